// Round 1
// baseline (1361.477 us; speedup 1.0000x reference)
//
#include <hip/hip_runtime.h>

// ---------------------------------------------------------------------------
// TeacherModel: small U-Net + pose heads. B=8, H=W=384, fp32 NCHW.
// Round 14: T14 async-STAGE split on the two dominant kernels (u2seg, u1).
//  Staging is split into {issue global loads -> regs, one chunk ahead} and
//  {vmcnt-wait + cvt + ds_write} so HBM latency (~600-900cy) hides under the
//  previous chunk's MFMA phase. LDS single-buffered, occupancy unchanged.
//  Numerics untouched (same loads / conversion / accumulation order).
// R13: p2 stride-2 MFMA w/ parity-split swizzle; hm/paf 1x1 MFMA GEMM.
// Engine validated across 5 kernels, absmax bit-stable 0.0078125 since R8.
// ---------------------------------------------------------------------------

#define BS 256

typedef _Float16 half8 __attribute__((ext_vector_type(8)));
typedef float floatx4 __attribute__((ext_vector_type(4)));

#define LDSDW 20    // dwords per x position
#define PL4 8160    // 6*68*LDSDW dwords per plane (4-row kernels)

// ===========================================================================
// Generic 3x3 weight pre-pack: [plane(hi/lo)][chunk][tap(9)][nt][lane][8]
// ci = chunk*32 + (lane>>4)*8 + j ; co = nt*16 + (lane&15)
// ===========================================================================
__global__ __launch_bounds__(BS) void packw_gen_kernel(
    const float* __restrict__ w, _Float16* __restrict__ bp, int Cin, int Cout)
{
    int total = (Cin >> 5) * 9 * (Cout >> 4) * 64;
    int tid = blockIdx.x * BS + threadIdx.x;
    if (tid >= total) return;
    int lane = tid & 63;
    int t = tid >> 6;
    int NTl = Cout >> 4;
    int nt = t % NTl; t /= NTl;
    int tap = t % 9;
    int chunk = t / 9;
    int q = lane >> 4, n = lane & 15;
    int co = nt * 16 + n;
    _Float16* ph = bp + (size_t)tid * 8;
    _Float16* pl = bp + (size_t)total * 8 + (size_t)tid * 8;
#pragma unroll
    for (int j = 0; j < 8; ++j) {
        int ci = chunk * 32 + q * 8 + j;
        float v = w[((size_t)co * Cin + ci) * 9 + tap];
        _Float16 h = (_Float16)v;
        ph[j] = h;
        pl[j] = (_Float16)(v - (float)h);
    }
}

// 1x1 weight pre-pack: [plane][chunk][nt][lane][8]; co >= Cout -> 0.
__global__ __launch_bounds__(BS) void packw_1x1_kernel(
    const float* __restrict__ w, _Float16* __restrict__ bp, int Cin, int NTl, int Cout)
{
    int total = (Cin >> 5) * NTl * 64;
    int tid = blockIdx.x * BS + threadIdx.x;
    if (tid >= total) return;
    int lane = tid & 63;
    int t = tid >> 6;
    int nt = t % NTl;
    int chunk = t / NTl;
    int q = lane >> 4, n = lane & 15;
    int co = nt * 16 + n;
    _Float16* ph = bp + (size_t)tid * 8;
    _Float16* pl = bp + (size_t)total * 8 + (size_t)tid * 8;
#pragma unroll
    for (int j = 0; j < 8; ++j) {
        int ci = chunk * 32 + q * 8 + j;
        float v = (co < Cout) ? w[(size_t)co * Cin + ci] : 0.f;
        _Float16 h = (_Float16)v;
        ph[j] = h;
        pl[j] = (_Float16)(v - (float)h);
    }
}

// ===========================================================================
// Generic stride-1 3x3 SAME conv via MFMA (R11): block = 2 rows x 32 px.
// ===========================================================================
template <int CHUNKS, int NT, int HH, int WW>
__global__ __launch_bounds__(BS) void conv3x3_mfma_kernel(
    const float* __restrict__ in_,
    const _Float16* __restrict__ bp,
    const float* __restrict__ bias,
    float* __restrict__ out)
{
    constexpr int PL = 4 * 34 * LDSDW;
    constexpr int EPI = 64 * NT * 16;
    constexpr int LDS_DW = (2 * PL > EPI) ? 2 * PL : EPI;
    __shared__ unsigned int lds[LDS_DW];

    int xblks = WW / 32;
    int b = blockIdx.x;
    int xb = b % xblks; b /= xblks;
    int yp = b % (HH / 2);
    int n  = b / (HH / 2);
    int y0 = yp * 2;
    int x0 = xb * 32;

    int tid = threadIdx.x;
    int lane = tid & 63, wv = tid >> 6;
    int m = lane & 15, q = lane >> 4;
    int lrow = wv >> 1;
    int lx   = (wv & 1) * 16;

    floatx4 acc[NT];
#pragma unroll
    for (int nt = 0; nt < NT; ++nt) acc[nt] = (floatx4){0.f, 0.f, 0.f, 0.f};

    const int planeW = CHUNKS * 9 * NT * 64 * 8;

    for (int chunk = 0; chunk < CHUNKS; ++chunk) {
        __syncthreads();
        for (int e = tid; e < 4 * 34 * 4; e += BS) {
            int xi = e % 34;
            int rest = e / 34;
            int oct = rest & 3;
            int row = rest >> 2;
            int iy = y0 - 1 + row, gx = x0 - 1 + xi;
            bool ok = (iy >= 0 && iy < HH && gx >= 0 && gx < WW);
            const float* gp = in_ +
                ((size_t)(n * (CHUNKS * 32) + chunk * 32 + oct * 8) * HH + iy) * WW + gx;
            half8 hv, lv;
#pragma unroll
            for (int j = 0; j < 8; ++j) {
                float v = ok ? gp[(size_t)j * HH * WW] : 0.f;
                _Float16 h = (_Float16)v;
                hv[j] = h;
                lv[j] = (_Float16)(v - (float)h);
            }
            int base = (row * 34 + xi) * LDSDW + oct * 4;
            *(half8*)((char*)lds + (size_t)base * 4) = hv;
            *(half8*)((char*)lds + ((size_t)PL + base) * 4) = lv;
        }
        __syncthreads();
#pragma unroll
        for (int ky = 0; ky < 3; ++ky) {
#pragma unroll
            for (int kx = 0; kx < 3; ++kx) {
                int row = lrow + ky;
                int xi  = lx + m + kx;
                int adw = (row * 34 + xi) * LDSDW + q * 4;
                half8 ah = *(const half8*)((const char*)lds + (size_t)adw * 4);
                half8 al = *(const half8*)((const char*)lds + ((size_t)PL + adw) * 4);
                int tap = ky * 3 + kx;
                const _Float16* bpp = bp + ((size_t)(chunk * 9 + tap) * NT) * 64 * 8;
#pragma unroll
                for (int nt = 0; nt < NT; ++nt) {
                    half8 bh = *(const half8*)(bpp + ((size_t)nt * 64 + lane) * 8);
                    half8 bl = *(const half8*)(bpp + planeW + ((size_t)nt * 64 + lane) * 8);
                    acc[nt] = __builtin_amdgcn_mfma_f32_16x16x32_f16(ah, bh, acc[nt], 0, 0, 0);
                    acc[nt] = __builtin_amdgcn_mfma_f32_16x16x32_f16(ah, bl, acc[nt], 0, 0, 0);
                    acc[nt] = __builtin_amdgcn_mfma_f32_16x16x32_f16(al, bh, acc[nt], 0, 0, 0);
                }
            }
        }
    }

    __syncthreads();
#pragma unroll
    for (int nt = 0; nt < NT; ++nt) {
#pragma unroll
        for (int r = 0; r < 4; ++r) {
            int co = nt * 16 + m;
            int pxl = wv * 16 + q * 4 + r;
            ((float*)lds)[co * 64 + pxl] = acc[nt][r];
        }
    }
    __syncthreads();
    {
        constexpr int thPerCo = 256 / (NT * 16);
        constexpr int pxPerTh = 64 / thPerCo;
        int co = tid / thPerCo;
        int sub = tid % thPerCo;
        int pxb = sub * pxPerTh;
        float bb = bias[co];
#pragma unroll
        for (int u = 0; u < pxPerTh; u += 4) {
            int p = pxb + u;
            int row = y0 + (p >> 5), xx = x0 + (p & 31);
            const float* lp = (const float*)lds + co * 64 + p;
            float4 vv = *(const float4*)lp;
            vv.x = fmaxf(vv.x + bb, 0.f);
            vv.y = fmaxf(vv.y + bb, 0.f);
            vv.z = fmaxf(vv.z + bb, 0.f);
            vv.w = fmaxf(vv.w + bb, 0.f);
            *(float4*)(out + ((size_t)(n * NT * 16 + co) * HH + row) * WW + xx) = vv;
        }
    }
}

// ===========================================================================
// Stride-2 3x3 conv (pad_lo=0, pad_hi=1) via MFMA: block = 2 out-rows x 32 px.
// Staging uses parity-split xi swizzle: pos = (xi&1)*34 + (xi>>1), so tap
// reads (ix = 2*ox + kx) are phase-contiguous -> LDS stride 20 (2-way, free).
// ===========================================================================
template <int CHUNKS, int NT, int WI>
__global__ __launch_bounds__(BS) void conv3x3s2_mfma_kernel(
    const float* __restrict__ in_,   // [8, CHUNKS*32, WI, WI]
    const _Float16* __restrict__ bp,
    const float* __restrict__ bias,  // [NT*16]
    float* __restrict__ out)         // [8, NT*16, WI/2, WI/2]
{
    constexpr int WO = WI / 2;
    constexpr int PLs = 5 * 68 * LDSDW;               // 6800 dw per plane
    constexpr int EPI = 64 * NT * 16;
    constexpr int LDS_DW = (2 * PLs > EPI) ? 2 * PLs : EPI;
    __shared__ unsigned int lds[LDS_DW];

    int xblks = WO / 32;
    int b = blockIdx.x;
    int xb = b % xblks; b /= xblks;
    int yp = b % (WO / 2);
    int n  = b / (WO / 2);
    int y0 = yp * 2;                                  // output rows y0, y0+1
    int x0 = xb * 32;

    int tid = threadIdx.x;
    int lane = tid & 63, wv = tid >> 6;
    int m = lane & 15, q = lane >> 4;
    int lrow = wv >> 1;
    int lx   = (wv & 1) * 16;

    floatx4 acc[NT];
#pragma unroll
    for (int nt = 0; nt < NT; ++nt) acc[nt] = (floatx4){0.f, 0.f, 0.f, 0.f};

    const int planeW = CHUNKS * 9 * NT * 64 * 8;

    for (int chunk = 0; chunk < CHUNKS; ++chunk) {
        __syncthreads();
        // stage 5 input rows x 65 xi (pad 68) x 4 octets; swizzled x position
        for (int e = tid; e < 5 * 68 * 4; e += BS) {
            int xi = e % 68;
            int rest = e / 68;
            int oct = rest & 3;
            int row = rest >> 2;                      // 0..4
            int iy = 2 * y0 + row, ix = 2 * x0 + xi;  // pad_lo = 0
            bool ok = (xi < 65 && iy < WI && ix < WI);
            const float* gp = in_ +
                ((size_t)(n * (CHUNKS * 32) + chunk * 32 + oct * 8) * WI + iy) * WI + ix;
            half8 hv, lv;
#pragma unroll
            for (int j = 0; j < 8; ++j) {
                float v = ok ? gp[(size_t)j * WI * WI] : 0.f;
                _Float16 h = (_Float16)v;
                hv[j] = h;
                lv[j] = (_Float16)(v - (float)h);
            }
            int pos = (xi & 1) * 34 + (xi >> 1);      // parity split
            int base = (row * 68 + pos) * LDSDW + oct * 4;
            *(half8*)((char*)lds + (size_t)base * 4) = hv;
            *(half8*)((char*)lds + ((size_t)PLs + base) * 4) = lv;
        }
        __syncthreads();
#pragma unroll
        for (int ky = 0; ky < 3; ++ky) {
#pragma unroll
            for (int kx = 0; kx < 3; ++kx) {
                int row = 2 * lrow + ky;              // 0..4
                int pos = (kx & 1) * 34 + (lx + m) + (kx >> 1);
                int adw = (row * 68 + pos) * LDSDW + q * 4;
                half8 ah = *(const half8*)((const char*)lds + (size_t)adw * 4);
                half8 al = *(const half8*)((const char*)lds + ((size_t)PLs + adw) * 4);
                int tap = ky * 3 + kx;
                const _Float16* bpp = bp + ((size_t)(chunk * 9 + tap) * NT) * 64 * 8;
#pragma unroll
                for (int nt = 0; nt < NT; ++nt) {
                    half8 bh = *(const half8*)(bpp + ((size_t)nt * 64 + lane) * 8);
                    half8 bl = *(const half8*)(bpp + planeW + ((size_t)nt * 64 + lane) * 8);
                    acc[nt] = __builtin_amdgcn_mfma_f32_16x16x32_f16(ah, bh, acc[nt], 0, 0, 0);
                    acc[nt] = __builtin_amdgcn_mfma_f32_16x16x32_f16(ah, bl, acc[nt], 0, 0, 0);
                    acc[nt] = __builtin_amdgcn_mfma_f32_16x16x32_f16(al, bh, acc[nt], 0, 0, 0);
                }
            }
        }
    }

    __syncthreads();
#pragma unroll
    for (int nt = 0; nt < NT; ++nt) {
#pragma unroll
        for (int r = 0; r < 4; ++r) {
            int co = nt * 16 + m;
            int pxl = wv * 16 + q * 4 + r;
            ((float*)lds)[co * 64 + pxl] = acc[nt][r];
        }
    }
    __syncthreads();
    {
        constexpr int thPerCo = 256 / (NT * 16);
        constexpr int pxPerTh = 64 / thPerCo;
        int co = tid / thPerCo;
        int sub = tid % thPerCo;
        int pxb = sub * pxPerTh;
        float bb = bias[co];
#pragma unroll
        for (int u = 0; u < pxPerTh; u += 4) {
            int p = pxb + u;
            int row = y0 + (p >> 5), xx = x0 + (p & 31);
            const float* lp = (const float*)lds + co * 64 + p;
            float4 vv = *(const float4*)lp;
            vv.x = fmaxf(vv.x + bb, 0.f);
            vv.y = fmaxf(vv.y + bb, 0.f);
            vv.z = fmaxf(vv.z + bb, 0.f);
            vv.w = fmaxf(vv.w + bb, 0.f);
            *(float4*)(out + ((size_t)(n * NT * 16 + co) * WO + row) * WO + xx) = vv;
        }
    }
}

// ===========================================================================
// 1x1 conv via MFMA GEMM: M = 64 px/block, N = NT*16 (store only co < Cout),
// K = CHUNKS*32. No relu (heads).
// ===========================================================================
template <int CHUNKS, int NT>
__global__ __launch_bounds__(BS) void conv1x1_mfma_kernel(
    const float* __restrict__ in_,   // [8, CHUNKS*32, HW]
    const _Float16* __restrict__ bp,
    const float* __restrict__ bias,  // [Cout]
    float* __restrict__ out,         // [8, Cout, HW]
    int Cout, int HW)
{
    constexpr int PL1 = 64 * LDSDW;                   // 1280 dw per plane
    constexpr int EPI = 64 * NT * 16;
    constexpr int LDS_DW = (2 * PL1 > EPI) ? 2 * PL1 : EPI;
    __shared__ unsigned int lds[LDS_DW];

    int pblks = HW / 64;
    int b = blockIdx.x;
    int pb = b % pblks;
    int n  = b / pblks;
    int sp0 = pb * 64;

    int tid = threadIdx.x;
    int lane = tid & 63, wv = tid >> 6;
    int m = lane & 15, q = lane >> 4;

    floatx4 acc[NT];
#pragma unroll
    for (int nt = 0; nt < NT; ++nt) acc[nt] = (floatx4){0.f, 0.f, 0.f, 0.f};

    const int planeW = CHUNKS * NT * 64 * 8;

    for (int chunk = 0; chunk < CHUNKS; ++chunk) {
        __syncthreads();
        // stage 64 px x 4 octets (one item per thread)
        {
            int px = tid & 63;
            int oct = tid >> 6;
            const float* gp = in_ +
                ((size_t)(n * (CHUNKS * 32) + chunk * 32 + oct * 8)) * HW + sp0 + px;
            half8 hv, lv;
#pragma unroll
            for (int j = 0; j < 8; ++j) {
                float v = gp[(size_t)j * HW];
                _Float16 h = (_Float16)v;
                hv[j] = h;
                lv[j] = (_Float16)(v - (float)h);
            }
            int base = px * LDSDW + oct * 4;
            *(half8*)((char*)lds + (size_t)base * 4) = hv;
            *(half8*)((char*)lds + ((size_t)PL1 + base) * 4) = lv;
        }
        __syncthreads();
        {
            int adw = (wv * 16 + m) * LDSDW + q * 4;
            half8 ah = *(const half8*)((const char*)lds + (size_t)adw * 4);
            half8 al = *(const half8*)((const char*)lds + ((size_t)PL1 + adw) * 4);
            const _Float16* bpp = bp + ((size_t)chunk * NT) * 64 * 8;
#pragma unroll
            for (int nt = 0; nt < NT; ++nt) {
                half8 bh = *(const half8*)(bpp + ((size_t)nt * 64 + lane) * 8);
                half8 bl = *(const half8*)(bpp + planeW + ((size_t)nt * 64 + lane) * 8);
                acc[nt] = __builtin_amdgcn_mfma_f32_16x16x32_f16(ah, bh, acc[nt], 0, 0, 0);
                acc[nt] = __builtin_amdgcn_mfma_f32_16x16x32_f16(ah, bl, acc[nt], 0, 0, 0);
                acc[nt] = __builtin_amdgcn_mfma_f32_16x16x32_f16(al, bh, acc[nt], 0, 0, 0);
            }
        }
    }

    __syncthreads();
#pragma unroll
    for (int nt = 0; nt < NT; ++nt) {
#pragma unroll
        for (int r = 0; r < 4; ++r) {
            ((float*)lds)[(nt * 16 + m) * 64 + wv * 16 + q * 4 + r] = acc[nt][r];
        }
    }
    __syncthreads();
    {
        constexpr int thPerCo = 256 / (NT * 16);      // NT=2 -> 8
        constexpr int pxPerTh = 64 / thPerCo;         // 8
        int co = tid / thPerCo;
        int g  = tid % thPerCo;
        if (co < Cout) {
            float bb = bias[co];
            const float* lp = (const float*)lds + co * 64 + g * pxPerTh;
            float* op = out + ((size_t)(n * Cout + co)) * HW + sp0 + g * pxPerTh;
#pragma unroll
            for (int u = 0; u < pxPerTh; u += 4) {
                float4 vv = *(const float4*)(lp + u);
                vv.x += bb; vv.y += bb; vv.z += bb; vv.w += bb;
                *(float4*)(op + u) = vv;
            }
        }
    }
}

// ===========================================================================
// u1 = relu(conv3x3(concat(up2(bn), d2))) via MFMA, 4 rows x 64 px @192.
// R14: async-STAGE split (T14) — chunk k+1 global loads issue before chunk
// k's MFMA phase; cvt + ds_write happen after the next barrier.
// ===========================================================================
__global__ __launch_bounds__(BS) void u1_mfma_kernel(
    const float* __restrict__ bn_,   // [8,128,96,96]
    const float* __restrict__ d2_,   // [8,64,192,192]
    const _Float16* __restrict__ bp,
    const float* __restrict__ b_u1,  // [64]
    float* __restrict__ out)         // [8,64,192,192]
{
    __shared__ unsigned int lds[2 * PL4];
    const int Ho = 192, Wo = 192;
    int b = blockIdx.x;
    int xb = b % 3; b /= 3;
    int yb = b % 48;
    int n  = b / 48;
    int y0 = yb * 4;
    int x0 = xb * 64;

    int tid = threadIdx.x;
    int lane = tid & 63, wv = tid >> 6;
    int m = lane & 15, q = lane >> 4;
    int yr = y0 + wv;

    floatx4 acc[4][4];
#pragma unroll
    for (int mt = 0; mt < 4; ++mt)
#pragma unroll
        for (int nt = 0; nt < 4; ++nt) acc[mt][nt] = (floatx4){0.f, 0.f, 0.f, 0.f};

    const int hh0 = (y0 - 1) >> 1;
    const int hx0 = (x0 - 1) >> 1;

    // Prefetch registers: chunk<4 (bn path) uses 3 items, else (d2) 7 items.
    float vr[7][8];

    auto u1_load = [&](int c) {
        if (c < 4) {
#pragma unroll
            for (int it = 0; it < 3; ++it) {
                int e = tid + it * BS;
                if (e < 4 * 34 * 4) {
                    int xi = e % 34;
                    int rest = e / 34;
                    int oct = rest & 3;
                    int row = rest >> 2;
                    int hy = hh0 + row, hx = hx0 + xi;
                    bool ok = (hy >= 0 && hy < 96 && hx >= 0 && hx < 96);
                    const float* gp = bn_ +
                        ((size_t)(n * 128 + c * 32 + oct * 8) * 96 + hy) * 96 + hx;
#pragma unroll
                    for (int j = 0; j < 8; ++j)
                        vr[it][j] = ok ? gp[(size_t)j * 96 * 96] : 0.f;
                }
            }
        } else {
#pragma unroll
            for (int it = 0; it < 7; ++it) {
                int e = tid + it * BS;
                if (e < 6 * 68 * 4) {
                    int xi = e % 68;
                    int rest = e / 68;
                    int oct = rest & 3;
                    int row = rest >> 2;
                    int iy = y0 - 1 + row, gx = x0 - 1 + xi;
                    bool ok = (xi < 67 && iy >= 0 && iy < Ho && gx >= 0 && gx < Wo);
                    const float* gp = d2_ +
                        ((size_t)(n * 64 + (c - 4) * 32 + oct * 8) * Ho + iy) * Wo + gx;
#pragma unroll
                    for (int j = 0; j < 8; ++j)
                        vr[it][j] = ok ? gp[(size_t)j * Ho * Wo] : 0.f;
                }
            }
        }
    };

    auto u1_store = [&](int c) {
        if (c < 4) {
#pragma unroll
            for (int it = 0; it < 3; ++it) {
                int e = tid + it * BS;
                if (e < 4 * 34 * 4) {
                    int xi = e % 34;
                    int rest = e / 34;
                    int oct = rest & 3;
                    int row = rest >> 2;
                    half8 hv, lv;
#pragma unroll
                    for (int j = 0; j < 8; ++j) {
                        float v = vr[it][j];
                        _Float16 h = (_Float16)v;
                        hv[j] = h;
                        lv[j] = (_Float16)(v - (float)h);
                    }
                    int base = (row * 68 + xi) * LDSDW + oct * 4;
                    *(half8*)((char*)lds + (size_t)base * 4) = hv;
                    *(half8*)((char*)lds + ((size_t)PL4 + base) * 4) = lv;
                }
            }
        } else {
#pragma unroll
            for (int it = 0; it < 7; ++it) {
                int e = tid + it * BS;
                if (e < 6 * 68 * 4) {
                    int xi = e % 68;
                    int rest = e / 68;
                    int oct = rest & 3;
                    int row = rest >> 2;
                    half8 hv, lv;
#pragma unroll
                    for (int j = 0; j < 8; ++j) {
                        float v = vr[it][j];
                        _Float16 h = (_Float16)v;
                        hv[j] = h;
                        lv[j] = (_Float16)(v - (float)h);
                    }
                    int base = (row * 68 + xi) * LDSDW + oct * 4;
                    *(half8*)((char*)lds + (size_t)base * 4) = hv;
                    *(half8*)((char*)lds + ((size_t)PL4 + base) * 4) = lv;
                }
            }
        }
    };

    u1_load(0);
    for (int chunk = 0; chunk < 6; ++chunk) {
        __syncthreads();               // previous chunk's LDS reads done
        u1_store(chunk);               // vmcnt-wait + cvt + ds_write
        __syncthreads();               // staging visible
        if (chunk < 5) u1_load(chunk + 1);  // issue next loads before MFMAs
#pragma unroll
        for (int ky = 0; ky < 3; ++ky) {
#pragma unroll
            for (int kx = 0; kx < 3; ++kx) {
                int tap = ky * 3 + kx;
                const _Float16* bpp = bp + ((size_t)(chunk * 9 + tap) * 4) * 64 * 8;
                half8 bh[4], bl[4];
#pragma unroll
                for (int nt = 0; nt < 4; ++nt) {
                    bh[nt] = *(const half8*)(bpp + ((size_t)nt * 64 + lane) * 8);
                    bl[nt] = *(const half8*)(bpp + 110592 + ((size_t)nt * 64 + lane) * 8);
                }
                int row;
                if (chunk < 4) row = ((yr + ky - 1) >> 1) - hh0;
                else           row = wv + ky;
#pragma unroll
                for (int mt = 0; mt < 4; ++mt) {
                    int px = 16 * mt + m;
                    int xi = (chunk < 4) ? (((x0 + px + kx - 1) >> 1) - hx0)
                                         : (px + kx);
                    int adw = (row * 68 + xi) * LDSDW + q * 4;
                    half8 ah = *(const half8*)((const char*)lds + (size_t)adw * 4);
                    half8 al = *(const half8*)((const char*)lds + ((size_t)PL4 + adw) * 4);
#pragma unroll
                    for (int nt = 0; nt < 4; ++nt) {
                        acc[mt][nt] = __builtin_amdgcn_mfma_f32_16x16x32_f16(ah, bh[nt], acc[mt][nt], 0, 0, 0);
                        acc[mt][nt] = __builtin_amdgcn_mfma_f32_16x16x32_f16(ah, bl[nt], acc[mt][nt], 0, 0, 0);
                        acc[mt][nt] = __builtin_amdgcn_mfma_f32_16x16x32_f16(al, bh[nt], acc[mt][nt], 0, 0, 0);
                    }
                }
            }
        }
    }

#pragma unroll
    for (int h = 0; h < 2; ++h) {
        __syncthreads();
#pragma unroll
        for (int ntl = 0; ntl < 2; ++ntl) {
#pragma unroll
            for (int mt = 0; mt < 4; ++mt) {
#pragma unroll
                for (int r = 0; r < 4; ++r) {
                    ((float*)lds)[(ntl * 16 + m) * 256 + wv * 64 + 16 * mt + q * 4 + r]
                        = acc[mt][h * 2 + ntl][r];
                }
            }
        }
        __syncthreads();
        {
            int col = tid >> 3;
            int g   = tid & 7;
            int row = g >> 1, xx = (g & 1) * 32;
            int co = h * 32 + col;
            float bb = b_u1[co];
            const float* lp = (const float*)lds + col * 256 + row * 64 + xx;
            float* op = out + ((size_t)(n * 64 + co) * Ho + y0 + row) * Wo + x0 + xx;
#pragma unroll
            for (int u = 0; u < 32; u += 4) {
                float4 vv = *(const float4*)(lp + u);
                vv.x = fmaxf(vv.x + bb, 0.f);
                vv.y = fmaxf(vv.y + bb, 0.f);
                vv.z = fmaxf(vv.z + bb, 0.f);
                vv.w = fmaxf(vv.w + bb, 0.f);
                *(float4*)(op + u) = vv;
            }
        }
    }
}

// ===========================================================================
// seg via fused MFMA u2+seg, 4 rows x 64 px @384; shfl_xor co-reduce.
// R14: async-STAGE split (T14), same structure as u1.
// ===========================================================================
__global__ __launch_bounds__(BS) void u2seg_mfma_kernel(
    const float* __restrict__ u1_,   // [8,64,192,192]
    const float* __restrict__ d1_,   // [8,32,384,384]
    const _Float16* __restrict__ bp,
    const float* __restrict__ b_u2,  // [32]
    const float* __restrict__ w_seg, // [32]
    const float* __restrict__ b_seg, // [1]
    float* __restrict__ seg)         // [8,1,384,384]
{
    __shared__ unsigned int lds[2 * PL4];
    const int Ho = 384, Wo = 384;
    int b = blockIdx.x;
    int xb = b % 6; b /= 6;
    int yb = b % 96;
    int n  = b / 96;
    int y0 = yb * 4;
    int x0 = xb * 64;

    int tid = threadIdx.x;
    int lane = tid & 63, wv = tid >> 6;
    int m = lane & 15, q = lane >> 4;
    int yr = y0 + wv;

    floatx4 acc[4][2];
#pragma unroll
    for (int mt = 0; mt < 4; ++mt) {
        acc[mt][0] = (floatx4){0.f, 0.f, 0.f, 0.f};
        acc[mt][1] = (floatx4){0.f, 0.f, 0.f, 0.f};
    }

    const int hh0 = (y0 - 1) >> 1;
    const int hx0 = (x0 - 1) >> 1;

    // Prefetch registers: chunk<2 (u1 path) uses 3 items, else (d1) 7 items.
    float vr[7][8];

    auto u2_load = [&](int c) {
        if (c < 2) {
#pragma unroll
            for (int it = 0; it < 3; ++it) {
                int e = tid + it * BS;
                if (e < 4 * 34 * 4) {
                    int xi = e % 34;
                    int rest = e / 34;
                    int oct = rest & 3;
                    int row = rest >> 2;
                    int hy = hh0 + row, hx = hx0 + xi;
                    bool ok = (hy >= 0 && hy < 192 && hx >= 0 && hx < 192);
                    const float* gp = u1_ +
                        ((size_t)(n * 64 + c * 32 + oct * 8) * 192 + hy) * 192 + hx;
#pragma unroll
                    for (int j = 0; j < 8; ++j)
                        vr[it][j] = ok ? gp[(size_t)j * 192 * 192] : 0.f;
                }
            }
        } else {
#pragma unroll
            for (int it = 0; it < 7; ++it) {
                int e = tid + it * BS;
                if (e < 6 * 68 * 4) {
                    int xi = e % 68;
                    int rest = e / 68;
                    int oct = rest & 3;
                    int row = rest >> 2;
                    int iy = y0 - 1 + row, gx = x0 - 1 + xi;
                    bool ok = (xi < 67 && iy >= 0 && iy < Ho && gx >= 0 && gx < Wo);
                    const float* gp = d1_ +
                        ((size_t)(n * 32 + oct * 8) * Ho + iy) * Wo + gx;
#pragma unroll
                    for (int j = 0; j < 8; ++j)
                        vr[it][j] = ok ? gp[(size_t)j * Ho * Wo] : 0.f;
                }
            }
        }
    };

    auto u2_store = [&](int c) {
        if (c < 2) {
#pragma unroll
            for (int it = 0; it < 3; ++it) {
                int e = tid + it * BS;
                if (e < 4 * 34 * 4) {
                    int xi = e % 34;
                    int rest = e / 34;
                    int oct = rest & 3;
                    int row = rest >> 2;
                    half8 hv, lv;
#pragma unroll
                    for (int j = 0; j < 8; ++j) {
                        float v = vr[it][j];
                        _Float16 h = (_Float16)v;
                        hv[j] = h;
                        lv[j] = (_Float16)(v - (float)h);
                    }
                    int base = (row * 68 + xi) * LDSDW + oct * 4;
                    *(half8*)((char*)lds + (size_t)base * 4) = hv;
                    *(half8*)((char*)lds + ((size_t)PL4 + base) * 4) = lv;
                }
            }
        } else {
#pragma unroll
            for (int it = 0; it < 7; ++it) {
                int e = tid + it * BS;
                if (e < 6 * 68 * 4) {
                    int xi = e % 68;
                    int rest = e / 68;
                    int oct = rest & 3;
                    int row = rest >> 2;
                    half8 hv, lv;
#pragma unroll
                    for (int j = 0; j < 8; ++j) {
                        float v = vr[it][j];
                        _Float16 h = (_Float16)v;
                        hv[j] = h;
                        lv[j] = (_Float16)(v - (float)h);
                    }
                    int base = (row * 68 + xi) * LDSDW + oct * 4;
                    *(half8*)((char*)lds + (size_t)base * 4) = hv;
                    *(half8*)((char*)lds + ((size_t)PL4 + base) * 4) = lv;
                }
            }
        }
    };

    u2_load(0);
    for (int chunk = 0; chunk < 3; ++chunk) {
        __syncthreads();               // previous chunk's LDS reads done
        u2_store(chunk);               // vmcnt-wait + cvt + ds_write
        __syncthreads();               // staging visible
        if (chunk < 2) u2_load(chunk + 1);  // issue next loads before MFMAs
#pragma unroll
        for (int ky = 0; ky < 3; ++ky) {
#pragma unroll
            for (int kx = 0; kx < 3; ++kx) {
                int tap = ky * 3 + kx;
                const _Float16* bpp = bp + ((size_t)(chunk * 9 + tap) * 2) * 64 * 8;
                half8 bh0 = *(const half8*)(bpp + (size_t)lane * 8);
                half8 bl0 = *(const half8*)(bpp + 27648 + (size_t)lane * 8);
                half8 bh1 = *(const half8*)(bpp + ((size_t)64 + lane) * 8);
                half8 bl1 = *(const half8*)(bpp + 27648 + ((size_t)64 + lane) * 8);
                int row;
                if (chunk < 2) row = ((yr + ky - 1) >> 1) - hh0;
                else           row = wv + ky;
#pragma unroll
                for (int mt = 0; mt < 4; ++mt) {
                    int px = 16 * mt + m;
                    int xi = (chunk < 2) ? (((x0 + px + kx - 1) >> 1) - hx0)
                                         : (px + kx);
                    int adw = (row * 68 + xi) * LDSDW + q * 4;
                    half8 ah = *(const half8*)((const char*)lds + (size_t)adw * 4);
                    half8 al = *(const half8*)((const char*)lds + ((size_t)PL4 + adw) * 4);
                    acc[mt][0] = __builtin_amdgcn_mfma_f32_16x16x32_f16(ah, bh0, acc[mt][0], 0, 0, 0);
                    acc[mt][0] = __builtin_amdgcn_mfma_f32_16x16x32_f16(ah, bl0, acc[mt][0], 0, 0, 0);
                    acc[mt][0] = __builtin_amdgcn_mfma_f32_16x16x32_f16(al, bh0, acc[mt][0], 0, 0, 0);
                    acc[mt][1] = __builtin_amdgcn_mfma_f32_16x16x32_f16(ah, bh1, acc[mt][1], 0, 0, 0);
                    acc[mt][1] = __builtin_amdgcn_mfma_f32_16x16x32_f16(ah, bl1, acc[mt][1], 0, 0, 0);
                    acc[mt][1] = __builtin_amdgcn_mfma_f32_16x16x32_f16(al, bh1, acc[mt][1], 0, 0, 0);
                }
            }
        }
    }

    float bb0 = b_u2[m], bb1 = b_u2[16 + m];
    float ws0 = w_seg[m], ws1 = w_seg[16 + m];
    float bseg = b_seg[0];
#pragma unroll
    for (int mt = 0; mt < 4; ++mt) {
        float sr[4];
#pragma unroll
        for (int r = 0; r < 4; ++r) {
            float p = ws0 * fmaxf(acc[mt][0][r] + bb0, 0.f)
                    + ws1 * fmaxf(acc[mt][1][r] + bb1, 0.f);
            p += __shfl_xor(p, 1);
            p += __shfl_xor(p, 2);
            p += __shfl_xor(p, 4);
            p += __shfl_xor(p, 8);
            sr[r] = p + bseg;
        }
        if (m == 0) {
            float4 o; o.x = sr[0]; o.y = sr[1]; o.z = sr[2]; o.w = sr[3];
            *(float4*)(seg + ((size_t)n * Ho + yr) * Wo + x0 + 16 * mt + q * 4) = o;
        }
    }
}

// ===========================================================================
// Vector kernels, unchanged.
// ===========================================================================

template <int UPA, int TCO>
__global__ __launch_bounds__(BS, 2) void conv3x3_x8_kernel(
    const float* __restrict__ inA, int Ca,
    const float* __restrict__ inB, int Cb,
    const float* __restrict__ w, const float* __restrict__ b,
    float* __restrict__ out,
    int N, int H, int W, int Cout, int do_relu)
{
    const int W8 = W >> 3;
    int idx = blockIdx.x * BS + threadIdx.x;
    int total = N * H * W8;
    if (idx >= total) return;
    int x8 = idx % W8;
    int t  = idx / W8;
    int y  = t % H;
    int n  = t / H;
    int x0 = x8 << 3;
    const int co0 = blockIdx.y * TCO;
    const bool left_ok  = (x0 > 0);
    const bool right_ok = (x0 + 8 < W);
    const int Cin = Ca + Cb;

    float acc[TCO][8];
#pragma unroll
    for (int j = 0; j < TCO; ++j) {
        float bv = b[co0 + j];
#pragma unroll
        for (int p = 0; p < 8; ++p) acc[j][p] = bv;
    }

    for (int ci = 0; ci < Cin; ++ci) {
        float v[3][10];
#pragma unroll
        for (int ky = 0; ky < 3; ++ky) {
            int iy = y + ky - 1;
            if (iy < 0 || iy >= H) {
#pragma unroll
                for (int p = 0; p < 10; ++p) v[ky][p] = 0.f;
                continue;
            }
            if (UPA == 2 && ci < Ca) {
                const float* r = inA + ((size_t)(n * Ca + ci) * (H >> 1) + (iy >> 1)) * (W >> 1);
                int xh = x0 >> 1;
                float sm = left_ok  ? r[xh - 1] : 0.f;
                float4 qq = *(const float4*)(r + xh);
                float s4 = right_ok ? r[xh + 4] : 0.f;
                v[ky][0] = sm;
                v[ky][1] = qq.x; v[ky][2] = qq.x;
                v[ky][3] = qq.y; v[ky][4] = qq.y;
                v[ky][5] = qq.z; v[ky][6] = qq.z;
                v[ky][7] = qq.w; v[ky][8] = qq.w;
                v[ky][9] = s4;
            } else {
                const float* r = (ci < Ca)
                    ? inA + ((size_t)(n * Ca + ci) * H + iy) * W
                    : inB + ((size_t)(n * Cb + (ci - Ca)) * H + iy) * W;
                v[ky][0] = left_ok ? r[x0 - 1] : 0.f;
                float4 q0 = *(const float4*)(r + x0);
                float4 q1 = *(const float4*)(r + x0 + 4);
                v[ky][1] = q0.x; v[ky][2] = q0.y; v[ky][3] = q0.z; v[ky][4] = q0.w;
                v[ky][5] = q1.x; v[ky][6] = q1.y; v[ky][7] = q1.z; v[ky][8] = q1.w;
                v[ky][9] = right_ok ? r[x0 + 8] : 0.f;
            }
        }
#pragma unroll
        for (int j = 0; j < TCO; ++j) {
            const float* wp = w + ((size_t)(co0 + j) * Cin + ci) * 9;
#pragma unroll
            for (int ky = 0; ky < 3; ++ky) {
                float w0 = wp[ky * 3 + 0], w1 = wp[ky * 3 + 1], w2 = wp[ky * 3 + 2];
#pragma unroll
                for (int p = 0; p < 8; ++p)
                    acc[j][p] += w0 * v[ky][p] + w1 * v[ky][p + 1] + w2 * v[ky][p + 2];
            }
        }
    }

#pragma unroll
    for (int j = 0; j < TCO; ++j) {
#pragma unroll
        for (int p = 0; p < 8; ++p)
            if (do_relu) acc[j][p] = fmaxf(acc[j][p], 0.f);
        float* o = out + ((size_t)(n * Cout + co0 + j) * H + y) * W + x0;
        float4 q0; q0.x = acc[j][0]; q0.y = acc[j][1]; q0.z = acc[j][2]; q0.w = acc[j][3];
        float4 q1; q1.x = acc[j][4]; q1.y = acc[j][5]; q1.z = acc[j][6]; q1.w = acc[j][7];
        *(float4*)o = q0;
        *(float4*)(o + 4) = q1;
    }
}

template <int TCO>
__global__ __launch_bounds__(BS) void conv3x3_s2_co_kernel(
    const float* __restrict__ inA, int Ca,
    const float* __restrict__ inB, int Cb,
    const float* __restrict__ w, const float* __restrict__ b,
    float* __restrict__ out,
    int N, int Hi, int Wi, int Cout, int do_relu)
{
    const int Ho = Hi >> 1, Wo = Wi >> 1, Woq = Wo >> 2;
    int idx = blockIdx.x * BS + threadIdx.x;
    int total = N * Ho * Woq;
    if (idx >= total) return;
    int q  = idx % Woq;
    int t  = idx / Woq;
    int oy = t % Ho;
    int n  = t / Ho;
    int ox0 = q << 2;
    int ix0 = ox0 << 1;
    const int co0 = blockIdx.y * TCO;
    const bool right_ok = (ix0 + 8 < Wi);
    const int Cin = Ca + Cb;

    float acc[TCO][4];
#pragma unroll
    for (int j = 0; j < TCO; ++j) {
        float bv = b[co0 + j];
        acc[j][0] = bv; acc[j][1] = bv; acc[j][2] = bv; acc[j][3] = bv;
    }

    for (int ci = 0; ci < Cin; ++ci) {
        const float* base = (ci < Ca)
            ? inA + (size_t)(n * Ca + ci) * Hi * Wi
            : inB + (size_t)(n * Cb + (ci - Ca)) * Hi * Wi;
        float v[3][9];
#pragma unroll
        for (int ky = 0; ky < 3; ++ky) {
            int iy = 2 * oy + ky;
            if (iy >= Hi) {
#pragma unroll
                for (int p = 0; p < 9; ++p) v[ky][p] = 0.f;
                continue;
            }
            const float* r = base + (size_t)iy * Wi + ix0;
            float4 a = *(const float4*)r;
            float4 c = *(const float4*)(r + 4);
            v[ky][0] = a.x; v[ky][1] = a.y; v[ky][2] = a.z; v[ky][3] = a.w;
            v[ky][4] = c.x; v[ky][5] = c.y; v[ky][6] = c.z; v[ky][7] = c.w;
            v[ky][8] = right_ok ? r[8] : 0.f;
        }
#pragma unroll
        for (int j = 0; j < TCO; ++j) {
            const float* wp = w + ((size_t)(co0 + j) * Cin + ci) * 9;
#pragma unroll
            for (int ky = 0; ky < 3; ++ky) {
                float w0 = wp[ky * 3 + 0], w1 = wp[ky * 3 + 1], w2 = wp[ky * 3 + 2];
#pragma unroll
                for (int p = 0; p < 4; ++p)
                    acc[j][p] += w0 * v[ky][2 * p] + w1 * v[ky][2 * p + 1] + w2 * v[ky][2 * p + 2];
            }
        }
    }

#pragma unroll
    for (int j = 0; j < TCO; ++j) {
        float4 o;
        o.x = acc[j][0]; o.y = acc[j][1]; o.z = acc[j][2]; o.w = acc[j][3];
        if (do_relu) {
            o.x = fmaxf(o.x, 0.f); o.y = fmaxf(o.y, 0.f);
            o.z = fmaxf(o.z, 0.f); o.w = fmaxf(o.w, 0.f);
        }
        *(float4*)(out + ((size_t)(n * Cout + co0 + j) * Ho + oy) * Wo + ox0) = o;
    }
}

__global__ __launch_bounds__(BS) void maxpool2_kernel(
    const float* __restrict__ in, float* __restrict__ out, int NC, int H, int W)
{
    int Ho = H >> 1, Wo = W >> 1, Woq = Wo >> 2;
    int idx = blockIdx.x * BS + threadIdx.x;
    int total = NC * Ho * Woq;
    if (idx >= total) return;
    int x4 = idx % Woq;
    int t  = idx / Woq;
    int y  = t % Ho;
    int c  = t / Ho;
    const float* r0 = in + ((size_t)c * H + 2 * y) * W + 8 * x4;
    const float* r1 = r0 + W;
    float4 a0 = *(const float4*)r0;
    float4 a1 = *(const float4*)(r0 + 4);
    float4 b0 = *(const float4*)r1;
    float4 b1 = *(const float4*)(r1 + 4);
    float4 o;
    o.x = fmaxf(fmaxf(a0.x, a0.y), fmaxf(b0.x, b0.y));
    o.y = fmaxf(fmaxf(a0.z, a0.w), fmaxf(b0.z, b0.w));
    o.z = fmaxf(fmaxf(a1.x, a1.y), fmaxf(b1.x, b1.y));
    o.w = fmaxf(fmaxf(a1.z, a1.w), fmaxf(b1.z, b1.w));
    *(float4*)(out + ((size_t)c * Ho + y) * Wo + 4 * x4) = o;
}

__global__ __launch_bounds__(BS) void peaks_kernel(
    const float* __restrict__ hm, float* __restrict__ out,
    int NC, int H, int W, float thresh)
{
    int idx = blockIdx.x * BS + threadIdx.x;
    int total = NC * H * W;
    if (idx >= total) return;
    int x = idx % W;
    int t = idx / W;
    int y = t % H;
    int c = t / H;
    float r = 0.f;
    if (x >= 1 && x < W - 1 && y >= 1 && y < H - 1) {
        const float* base = hm + (size_t)c * H * W;
        float cv = base[y * W + x];
        if (cv > thresh &&
            cv >= base[(y - 1) * W + x] &&
            cv >= base[(y + 1) * W + x] &&
            cv >= base[y * W + (x - 1)] &&
            cv >= base[y * W + (x + 1)])
            r = 1.f;
    }
    out[idx] = r;
}

static inline int nblk(long n) { return (int)((n + BS - 1) / BS); }

extern "C" void kernel_launch(void* const* d_in, const int* in_sizes, int n_in,
                              void* d_out, int out_size, void* d_ws, size_t ws_size,
                              hipStream_t stream)
{
    const float* x     = (const float*)d_in[0];
    const float* w_d1  = (const float*)d_in[1];  const float* b_d1  = (const float*)d_in[2];
    const float* w_d2  = (const float*)d_in[3];  const float* b_d2  = (const float*)d_in[4];
    const float* w_bn  = (const float*)d_in[5];  const float* b_bn  = (const float*)d_in[6];
    const float* w_u1  = (const float*)d_in[7];  const float* b_u1  = (const float*)d_in[8];
    const float* w_u2  = (const float*)d_in[9];  const float* b_u2  = (const float*)d_in[10];
    const float* w_seg = (const float*)d_in[11]; const float* b_seg = (const float*)d_in[12];
    const float* w_p1  = (const float*)d_in[13]; const float* b_p1  = (const float*)d_in[14];
    const float* w_p2  = (const float*)d_in[15]; const float* b_p2  = (const float*)d_in[16];
    const float* w_hm  = (const float*)d_in[17]; const float* b_hm  = (const float*)d_in[18];
    const float* w_paf = (const float*)d_in[19]; const float* b_paf = (const float*)d_in[20];

    const int N = 8, H = 384, W = 384;
    const int H2 = 192, W2 = 192, H4 = 96, W4 = 96;

    float* ws = (float*)d_ws;
    // Workspace extent = 56,623,104 floats = 216 MiB (R2 lifetime map).
    float* u1  = ws;                   // 8*64*192*192 = 18874368
    float* d1  = ws + 18874368;        // 8*32*384*384 = 37748736
    float* d2  = ws + 18874368;        // 8*64*192*192 = 18874368
    float* bn  = ws + 37748736;        // 8*128*96*96  = 9437184
    float* pd1 = ws;                   // 8*32*192*192 = 9437184
    float* pd2 = ws + 47185920;        // 8*64*96*96   = 4718592
    float* p1  = ws;                   // 8*64*192*192 = 18874368
    float* p2  = ws + 18874368;        // 8*128*96*96  = 9437184

    float* out_seg   = (float*)d_out;                 // 1179648
    float* out_hm    = out_seg + 1179648;             // 1253376
    float* out_paf   = out_hm + 1253376;              // 2359296
    float* out_peaks = out_paf + 2359296;             // 1253376
    // packed weights in the peaks region [4792320, 6045696), all consumed
    // before step 13 overwrites them. 16B-aligned.
    _Float16* bp_u1  = (_Float16*)(out_seg + 4792320); // 110592 fl
    _Float16* bp_u2  = (_Float16*)(out_seg + 4902912); // 27648 fl
    _Float16* bp_d2  = (_Float16*)(out_seg + 4930560); // 18432 fl
    _Float16* bp_bn  = (_Float16*)(out_seg + 4948992); // 73728 fl
    _Float16* bp_p2  = (_Float16*)(out_seg + 5022720); // 73728 fl
    _Float16* bp_hm  = (_Float16*)(out_seg + 5096448); // 4096 fl
    _Float16* bp_paf = (_Float16*)(out_seg + 5100544); // 4096 fl -> ends 5104640

    // 0. pack weights
    packw_gen_kernel<<<nblk(13824), BS, 0, stream>>>(w_u1, bp_u1, 192, 64);
    packw_gen_kernel<<<nblk(3456),  BS, 0, stream>>>(w_u2, bp_u2, 96, 32);
    packw_gen_kernel<<<nblk(2304),  BS, 0, stream>>>(w_d2, bp_d2, 32, 64);
    packw_gen_kernel<<<nblk(9216),  BS, 0, stream>>>(w_bn, bp_bn, 64, 128);
    packw_gen_kernel<<<nblk(9216),  BS, 0, stream>>>(w_p2, bp_p2, 64, 128);
    packw_1x1_kernel<<<nblk(512),   BS, 0, stream>>>(w_hm, bp_hm, 128, 2, 17);
    packw_1x1_kernel<<<nblk(512),   BS, 0, stream>>>(w_paf, bp_paf, 128, 2, 32);
    // 1. d1 = relu(conv3x3(x; 3->32)) @384
    {
        dim3 g(nblk((long)N * H * (W / 8)), 32 / 8);
        conv3x3_x8_kernel<1, 8><<<g, BS, 0, stream>>>(
            x, 3, nullptr, 0, w_d1, b_d1, d1, N, H, W, 32, 1);
    }
    // 2. pd1 = maxpool(d1) @192
    maxpool2_kernel<<<nblk((long)N * 32 * H2 * (W2 / 4)), BS, 0, stream>>>(d1, pd1, N * 32, H, W);
    // 3. d2 = relu(conv3x3(pd1; 32->64)) @192  [MFMA]
    conv3x3_mfma_kernel<1, 4, 192, 192><<<8 * 96 * 6, BS, 0, stream>>>(
        pd1, bp_d2, b_d2, d2);
    // 4. pd2 = maxpool(d2) @96
    maxpool2_kernel<<<nblk((long)N * 64 * H4 * (W4 / 4)), BS, 0, stream>>>(d2, pd2, N * 64, H2, W2);
    // 5. bn = relu(conv3x3(pd2; 64->128)) @96  [MFMA]
    conv3x3_mfma_kernel<2, 8, 96, 96><<<8 * 48 * 3, BS, 0, stream>>>(
        pd2, bp_bn, b_bn, bn);
    // 6. u1 = relu(conv3x3(concat(up2(bn), d2); 192->64)) @192  [MFMA 4-row, T14]
    u1_mfma_kernel<<<8 * 48 * 3, BS, 0, stream>>>(bn, d2, bp_u1, b_u1, u1);
    // 7. d1' = relu(conv3x3(x; 3->32)) @384  (recompute)
    {
        dim3 g(nblk((long)N * H * (W / 8)), 32 / 8);
        conv3x3_x8_kernel<1, 8><<<g, BS, 0, stream>>>(
            x, 3, nullptr, 0, w_d1, b_d1, d1, N, H, W, 32, 1);
    }
    // 8. seg via fused MFMA u2+seg @384  [MFMA 4-row, T14]
    u2seg_mfma_kernel<<<8 * 96 * 6, BS, 0, stream>>>(
        u1, d1, bp_u2, b_u2, w_seg, b_seg, out_seg);
    // 9. p1 = relu(conv3x3_s2(concat(x, seg); 4->64)) @384->192  [vector]
    {
        dim3 g(nblk((long)N * H2 * (W2 / 4)), 64 / 8);
        conv3x3_s2_co_kernel<8><<<g, BS, 0, stream>>>(
            x, 3, out_seg, 1, w_p1, b_p1, p1, N, H, W, 64, 1);
    }
    // 10. p2 = relu(conv3x3_s2(p1; 64->128)) @192->96  [MFMA s2]
    conv3x3s2_mfma_kernel<2, 8, 192><<<8 * 48 * 3, BS, 0, stream>>>(
        p1, bp_p2, b_p2, p2);
    // 11. hm = conv1x1(p2; 128->17) @96  [MFMA 1x1]
    conv1x1_mfma_kernel<4, 2><<<8 * 144, BS, 0, stream>>>(
        p2, bp_hm, b_hm, out_hm, 17, H4 * W4);
    // 12. paf = conv1x1(p2; 128->32) @96  [MFMA 1x1]
    conv1x1_mfma_kernel<4, 2><<<8 * 144, BS, 0, stream>>>(
        p2, bp_paf, b_paf, out_paf, 32, H4 * W4);
    // 13. peaks @96  (overwrites packed-weight region - already consumed)
    peaks_kernel<<<nblk((long)N * 17 * H4 * W4), BS, 0, stream>>>(
        out_hm, out_peaks, N * 17, H4, W4, 0.1f);
}

// Round 2
// 1013.088 us; speedup vs baseline: 1.3439x; 1.3439x over previous
//
#include <hip/hip_runtime.h>

// ---------------------------------------------------------------------------
// TeacherModel: small U-Net + pose heads. B=8, H=W=384, fp32 NCHW.
// Round 15: revert R14 reg-prefetch (VGPR 192 killed occupancy). New lever:
//  4-row kernels (u1, u2seg) retiled 4x64 -> 4x48 px. Staged LDS drops
//  65,280 -> 48,000 B => 3 blocks/CU (was 2), +50% TLP to overlap the
//  stage/MFMA phase serialization. Halo overhead ratio unchanged (1.5625 vs
//  1.547); per-output arithmetic bit-identical (same chunk/tap/hi-lo order).
// R13: p2 stride-2 MFMA w/ parity-split swizzle; hm/paf 1x1 MFMA GEMM.
// Engine validated across 5 kernels, absmax bit-stable 0.0078125 since R8.
// ---------------------------------------------------------------------------

#define BS 256

typedef _Float16 half8 __attribute__((ext_vector_type(8)));
typedef float floatx4 __attribute__((ext_vector_type(4)));

#define LDSDW 20    // dwords per x position
#define PLT 6000    // 6*50*LDSDW dwords per plane (4-row x 48-px kernels)

// ===========================================================================
// Generic 3x3 weight pre-pack: [plane(hi/lo)][chunk][tap(9)][nt][lane][8]
// ci = chunk*32 + (lane>>4)*8 + j ; co = nt*16 + (lane&15)
// ===========================================================================
__global__ __launch_bounds__(BS) void packw_gen_kernel(
    const float* __restrict__ w, _Float16* __restrict__ bp, int Cin, int Cout)
{
    int total = (Cin >> 5) * 9 * (Cout >> 4) * 64;
    int tid = blockIdx.x * BS + threadIdx.x;
    if (tid >= total) return;
    int lane = tid & 63;
    int t = tid >> 6;
    int NTl = Cout >> 4;
    int nt = t % NTl; t /= NTl;
    int tap = t % 9;
    int chunk = t / 9;
    int q = lane >> 4, n = lane & 15;
    int co = nt * 16 + n;
    _Float16* ph = bp + (size_t)tid * 8;
    _Float16* pl = bp + (size_t)total * 8 + (size_t)tid * 8;
#pragma unroll
    for (int j = 0; j < 8; ++j) {
        int ci = chunk * 32 + q * 8 + j;
        float v = w[((size_t)co * Cin + ci) * 9 + tap];
        _Float16 h = (_Float16)v;
        ph[j] = h;
        pl[j] = (_Float16)(v - (float)h);
    }
}

// 1x1 weight pre-pack: [plane][chunk][nt][lane][8]; co >= Cout -> 0.
__global__ __launch_bounds__(BS) void packw_1x1_kernel(
    const float* __restrict__ w, _Float16* __restrict__ bp, int Cin, int NTl, int Cout)
{
    int total = (Cin >> 5) * NTl * 64;
    int tid = blockIdx.x * BS + threadIdx.x;
    if (tid >= total) return;
    int lane = tid & 63;
    int t = tid >> 6;
    int nt = t % NTl;
    int chunk = t / NTl;
    int q = lane >> 4, n = lane & 15;
    int co = nt * 16 + n;
    _Float16* ph = bp + (size_t)tid * 8;
    _Float16* pl = bp + (size_t)total * 8 + (size_t)tid * 8;
#pragma unroll
    for (int j = 0; j < 8; ++j) {
        int ci = chunk * 32 + q * 8 + j;
        float v = (co < Cout) ? w[(size_t)co * Cin + ci] : 0.f;
        _Float16 h = (_Float16)v;
        ph[j] = h;
        pl[j] = (_Float16)(v - (float)h);
    }
}

// ===========================================================================
// Generic stride-1 3x3 SAME conv via MFMA (R11): block = 2 rows x 32 px.
// ===========================================================================
template <int CHUNKS, int NT, int HH, int WW>
__global__ __launch_bounds__(BS) void conv3x3_mfma_kernel(
    const float* __restrict__ in_,
    const _Float16* __restrict__ bp,
    const float* __restrict__ bias,
    float* __restrict__ out)
{
    constexpr int PL = 4 * 34 * LDSDW;
    constexpr int EPI = 64 * NT * 16;
    constexpr int LDS_DW = (2 * PL > EPI) ? 2 * PL : EPI;
    __shared__ unsigned int lds[LDS_DW];

    int xblks = WW / 32;
    int b = blockIdx.x;
    int xb = b % xblks; b /= xblks;
    int yp = b % (HH / 2);
    int n  = b / (HH / 2);
    int y0 = yp * 2;
    int x0 = xb * 32;

    int tid = threadIdx.x;
    int lane = tid & 63, wv = tid >> 6;
    int m = lane & 15, q = lane >> 4;
    int lrow = wv >> 1;
    int lx   = (wv & 1) * 16;

    floatx4 acc[NT];
#pragma unroll
    for (int nt = 0; nt < NT; ++nt) acc[nt] = (floatx4){0.f, 0.f, 0.f, 0.f};

    const int planeW = CHUNKS * 9 * NT * 64 * 8;

    for (int chunk = 0; chunk < CHUNKS; ++chunk) {
        __syncthreads();
        for (int e = tid; e < 4 * 34 * 4; e += BS) {
            int xi = e % 34;
            int rest = e / 34;
            int oct = rest & 3;
            int row = rest >> 2;
            int iy = y0 - 1 + row, gx = x0 - 1 + xi;
            bool ok = (iy >= 0 && iy < HH && gx >= 0 && gx < WW);
            const float* gp = in_ +
                ((size_t)(n * (CHUNKS * 32) + chunk * 32 + oct * 8) * HH + iy) * WW + gx;
            half8 hv, lv;
#pragma unroll
            for (int j = 0; j < 8; ++j) {
                float v = ok ? gp[(size_t)j * HH * WW] : 0.f;
                _Float16 h = (_Float16)v;
                hv[j] = h;
                lv[j] = (_Float16)(v - (float)h);
            }
            int base = (row * 34 + xi) * LDSDW + oct * 4;
            *(half8*)((char*)lds + (size_t)base * 4) = hv;
            *(half8*)((char*)lds + ((size_t)PL + base) * 4) = lv;
        }
        __syncthreads();
#pragma unroll
        for (int ky = 0; ky < 3; ++ky) {
#pragma unroll
            for (int kx = 0; kx < 3; ++kx) {
                int row = lrow + ky;
                int xi  = lx + m + kx;
                int adw = (row * 34 + xi) * LDSDW + q * 4;
                half8 ah = *(const half8*)((const char*)lds + (size_t)adw * 4);
                half8 al = *(const half8*)((const char*)lds + ((size_t)PL + adw) * 4);
                int tap = ky * 3 + kx;
                const _Float16* bpp = bp + ((size_t)(chunk * 9 + tap) * NT) * 64 * 8;
#pragma unroll
                for (int nt = 0; nt < NT; ++nt) {
                    half8 bh = *(const half8*)(bpp + ((size_t)nt * 64 + lane) * 8);
                    half8 bl = *(const half8*)(bpp + planeW + ((size_t)nt * 64 + lane) * 8);
                    acc[nt] = __builtin_amdgcn_mfma_f32_16x16x32_f16(ah, bh, acc[nt], 0, 0, 0);
                    acc[nt] = __builtin_amdgcn_mfma_f32_16x16x32_f16(ah, bl, acc[nt], 0, 0, 0);
                    acc[nt] = __builtin_amdgcn_mfma_f32_16x16x32_f16(al, bh, acc[nt], 0, 0, 0);
                }
            }
        }
    }

    __syncthreads();
#pragma unroll
    for (int nt = 0; nt < NT; ++nt) {
#pragma unroll
        for (int r = 0; r < 4; ++r) {
            int co = nt * 16 + m;
            int pxl = wv * 16 + q * 4 + r;
            ((float*)lds)[co * 64 + pxl] = acc[nt][r];
        }
    }
    __syncthreads();
    {
        constexpr int thPerCo = 256 / (NT * 16);
        constexpr int pxPerTh = 64 / thPerCo;
        int co = tid / thPerCo;
        int sub = tid % thPerCo;
        int pxb = sub * pxPerTh;
        float bb = bias[co];
#pragma unroll
        for (int u = 0; u < pxPerTh; u += 4) {
            int p = pxb + u;
            int row = y0 + (p >> 5), xx = x0 + (p & 31);
            const float* lp = (const float*)lds + co * 64 + p;
            float4 vv = *(const float4*)lp;
            vv.x = fmaxf(vv.x + bb, 0.f);
            vv.y = fmaxf(vv.y + bb, 0.f);
            vv.z = fmaxf(vv.z + bb, 0.f);
            vv.w = fmaxf(vv.w + bb, 0.f);
            *(float4*)(out + ((size_t)(n * NT * 16 + co) * HH + row) * WW + xx) = vv;
        }
    }
}

// ===========================================================================
// Stride-2 3x3 conv (pad_lo=0, pad_hi=1) via MFMA: block = 2 out-rows x 32 px.
// Staging uses parity-split xi swizzle: pos = (xi&1)*34 + (xi>>1), so tap
// reads (ix = 2*ox + kx) are phase-contiguous -> LDS stride 20 (2-way, free).
// ===========================================================================
template <int CHUNKS, int NT, int WI>
__global__ __launch_bounds__(BS) void conv3x3s2_mfma_kernel(
    const float* __restrict__ in_,   // [8, CHUNKS*32, WI, WI]
    const _Float16* __restrict__ bp,
    const float* __restrict__ bias,  // [NT*16]
    float* __restrict__ out)         // [8, NT*16, WI/2, WI/2]
{
    constexpr int WO = WI / 2;
    constexpr int PLs = 5 * 68 * LDSDW;               // 6800 dw per plane
    constexpr int EPI = 64 * NT * 16;
    constexpr int LDS_DW = (2 * PLs > EPI) ? 2 * PLs : EPI;
    __shared__ unsigned int lds[LDS_DW];

    int xblks = WO / 32;
    int b = blockIdx.x;
    int xb = b % xblks; b /= xblks;
    int yp = b % (WO / 2);
    int n  = b / (WO / 2);
    int y0 = yp * 2;                                  // output rows y0, y0+1
    int x0 = xb * 32;

    int tid = threadIdx.x;
    int lane = tid & 63, wv = tid >> 6;
    int m = lane & 15, q = lane >> 4;
    int lrow = wv >> 1;
    int lx   = (wv & 1) * 16;

    floatx4 acc[NT];
#pragma unroll
    for (int nt = 0; nt < NT; ++nt) acc[nt] = (floatx4){0.f, 0.f, 0.f, 0.f};

    const int planeW = CHUNKS * 9 * NT * 64 * 8;

    for (int chunk = 0; chunk < CHUNKS; ++chunk) {
        __syncthreads();
        // stage 5 input rows x 65 xi (pad 68) x 4 octets; swizzled x position
        for (int e = tid; e < 5 * 68 * 4; e += BS) {
            int xi = e % 68;
            int rest = e / 68;
            int oct = rest & 3;
            int row = rest >> 2;                      // 0..4
            int iy = 2 * y0 + row, ix = 2 * x0 + xi;  // pad_lo = 0
            bool ok = (xi < 65 && iy < WI && ix < WI);
            const float* gp = in_ +
                ((size_t)(n * (CHUNKS * 32) + chunk * 32 + oct * 8) * WI + iy) * WI + ix;
            half8 hv, lv;
#pragma unroll
            for (int j = 0; j < 8; ++j) {
                float v = ok ? gp[(size_t)j * WI * WI] : 0.f;
                _Float16 h = (_Float16)v;
                hv[j] = h;
                lv[j] = (_Float16)(v - (float)h);
            }
            int pos = (xi & 1) * 34 + (xi >> 1);      // parity split
            int base = (row * 68 + pos) * LDSDW + oct * 4;
            *(half8*)((char*)lds + (size_t)base * 4) = hv;
            *(half8*)((char*)lds + ((size_t)PLs + base) * 4) = lv;
        }
        __syncthreads();
#pragma unroll
        for (int ky = 0; ky < 3; ++ky) {
#pragma unroll
            for (int kx = 0; kx < 3; ++kx) {
                int row = 2 * lrow + ky;              // 0..4
                int pos = (kx & 1) * 34 + (lx + m) + (kx >> 1);
                int adw = (row * 68 + pos) * LDSDW + q * 4;
                half8 ah = *(const half8*)((const char*)lds + (size_t)adw * 4);
                half8 al = *(const half8*)((const char*)lds + ((size_t)PLs + adw) * 4);
                int tap = ky * 3 + kx;
                const _Float16* bpp = bp + ((size_t)(chunk * 9 + tap) * NT) * 64 * 8;
#pragma unroll
                for (int nt = 0; nt < NT; ++nt) {
                    half8 bh = *(const half8*)(bpp + ((size_t)nt * 64 + lane) * 8);
                    half8 bl = *(const half8*)(bpp + planeW + ((size_t)nt * 64 + lane) * 8);
                    acc[nt] = __builtin_amdgcn_mfma_f32_16x16x32_f16(ah, bh, acc[nt], 0, 0, 0);
                    acc[nt] = __builtin_amdgcn_mfma_f32_16x16x32_f16(ah, bl, acc[nt], 0, 0, 0);
                    acc[nt] = __builtin_amdgcn_mfma_f32_16x16x32_f16(al, bh, acc[nt], 0, 0, 0);
                }
            }
        }
    }

    __syncthreads();
#pragma unroll
    for (int nt = 0; nt < NT; ++nt) {
#pragma unroll
        for (int r = 0; r < 4; ++r) {
            int co = nt * 16 + m;
            int pxl = wv * 16 + q * 4 + r;
            ((float*)lds)[co * 64 + pxl] = acc[nt][r];
        }
    }
    __syncthreads();
    {
        constexpr int thPerCo = 256 / (NT * 16);
        constexpr int pxPerTh = 64 / thPerCo;
        int co = tid / thPerCo;
        int sub = tid % thPerCo;
        int pxb = sub * pxPerTh;
        float bb = bias[co];
#pragma unroll
        for (int u = 0; u < pxPerTh; u += 4) {
            int p = pxb + u;
            int row = y0 + (p >> 5), xx = x0 + (p & 31);
            const float* lp = (const float*)lds + co * 64 + p;
            float4 vv = *(const float4*)lp;
            vv.x = fmaxf(vv.x + bb, 0.f);
            vv.y = fmaxf(vv.y + bb, 0.f);
            vv.z = fmaxf(vv.z + bb, 0.f);
            vv.w = fmaxf(vv.w + bb, 0.f);
            *(float4*)(out + ((size_t)(n * NT * 16 + co) * WO + row) * WO + xx) = vv;
        }
    }
}

// ===========================================================================
// 1x1 conv via MFMA GEMM: M = 64 px/block, N = NT*16 (store only co < Cout),
// K = CHUNKS*32. No relu (heads).
// ===========================================================================
template <int CHUNKS, int NT>
__global__ __launch_bounds__(BS) void conv1x1_mfma_kernel(
    const float* __restrict__ in_,   // [8, CHUNKS*32, HW]
    const _Float16* __restrict__ bp,
    const float* __restrict__ bias,  // [Cout]
    float* __restrict__ out,         // [8, Cout, HW]
    int Cout, int HW)
{
    constexpr int PL1 = 64 * LDSDW;                   // 1280 dw per plane
    constexpr int EPI = 64 * NT * 16;
    constexpr int LDS_DW = (2 * PL1 > EPI) ? 2 * PL1 : EPI;
    __shared__ unsigned int lds[LDS_DW];

    int pblks = HW / 64;
    int b = blockIdx.x;
    int pb = b % pblks;
    int n  = b / pblks;
    int sp0 = pb * 64;

    int tid = threadIdx.x;
    int lane = tid & 63, wv = tid >> 6;
    int m = lane & 15, q = lane >> 4;

    floatx4 acc[NT];
#pragma unroll
    for (int nt = 0; nt < NT; ++nt) acc[nt] = (floatx4){0.f, 0.f, 0.f, 0.f};

    const int planeW = CHUNKS * NT * 64 * 8;

    for (int chunk = 0; chunk < CHUNKS; ++chunk) {
        __syncthreads();
        // stage 64 px x 4 octets (one item per thread)
        {
            int px = tid & 63;
            int oct = tid >> 6;
            const float* gp = in_ +
                ((size_t)(n * (CHUNKS * 32) + chunk * 32 + oct * 8)) * HW + sp0 + px;
            half8 hv, lv;
#pragma unroll
            for (int j = 0; j < 8; ++j) {
                float v = gp[(size_t)j * HW];
                _Float16 h = (_Float16)v;
                hv[j] = h;
                lv[j] = (_Float16)(v - (float)h);
            }
            int base = px * LDSDW + oct * 4;
            *(half8*)((char*)lds + (size_t)base * 4) = hv;
            *(half8*)((char*)lds + ((size_t)PL1 + base) * 4) = lv;
        }
        __syncthreads();
        {
            int adw = (wv * 16 + m) * LDSDW + q * 4;
            half8 ah = *(const half8*)((const char*)lds + (size_t)adw * 4);
            half8 al = *(const half8*)((const char*)lds + ((size_t)PL1 + adw) * 4);
            const _Float16* bpp = bp + ((size_t)chunk * NT) * 64 * 8;
#pragma unroll
            for (int nt = 0; nt < NT; ++nt) {
                half8 bh = *(const half8*)(bpp + ((size_t)nt * 64 + lane) * 8);
                half8 bl = *(const half8*)(bpp + planeW + ((size_t)nt * 64 + lane) * 8);
                acc[nt] = __builtin_amdgcn_mfma_f32_16x16x32_f16(ah, bh, acc[nt], 0, 0, 0);
                acc[nt] = __builtin_amdgcn_mfma_f32_16x16x32_f16(ah, bl, acc[nt], 0, 0, 0);
                acc[nt] = __builtin_amdgcn_mfma_f32_16x16x32_f16(al, bh, acc[nt], 0, 0, 0);
            }
        }
    }

    __syncthreads();
#pragma unroll
    for (int nt = 0; nt < NT; ++nt) {
#pragma unroll
        for (int r = 0; r < 4; ++r) {
            ((float*)lds)[(nt * 16 + m) * 64 + wv * 16 + q * 4 + r] = acc[nt][r];
        }
    }
    __syncthreads();
    {
        constexpr int thPerCo = 256 / (NT * 16);      // NT=2 -> 8
        constexpr int pxPerTh = 64 / thPerCo;         // 8
        int co = tid / thPerCo;
        int g  = tid % thPerCo;
        if (co < Cout) {
            float bb = bias[co];
            const float* lp = (const float*)lds + co * 64 + g * pxPerTh;
            float* op = out + ((size_t)(n * Cout + co)) * HW + sp0 + g * pxPerTh;
#pragma unroll
            for (int u = 0; u < pxPerTh; u += 4) {
                float4 vv = *(const float4*)(lp + u);
                vv.x += bb; vv.y += bb; vv.z += bb; vv.w += bb;
                *(float4*)(op + u) = vv;
            }
        }
    }
}

// ===========================================================================
// u1 = relu(conv3x3(concat(up2(bn), d2))) via MFMA, 4 rows x 48 px @192.
// R15: 48-px tile -> LDS 48,000 B -> 3 blocks/CU.
// ===========================================================================
__global__ __launch_bounds__(BS) void u1_mfma_kernel(
    const float* __restrict__ bn_,   // [8,128,96,96]
    const float* __restrict__ d2_,   // [8,64,192,192]
    const _Float16* __restrict__ bp,
    const float* __restrict__ b_u1,  // [64]
    float* __restrict__ out)         // [8,64,192,192]
{
    __shared__ unsigned int lds[2 * PLT];
    const int Ho = 192, Wo = 192;
    int b = blockIdx.x;
    int xb = b % 4; b /= 4;                           // 192/48 = 4 x-tiles
    int yb = b % 48;
    int n  = b / 48;
    int y0 = yb * 4;
    int x0 = xb * 48;

    int tid = threadIdx.x;
    int lane = tid & 63, wv = tid >> 6;
    int m = lane & 15, q = lane >> 4;
    int yr = y0 + wv;

    floatx4 acc[3][4];
#pragma unroll
    for (int mt = 0; mt < 3; ++mt)
#pragma unroll
        for (int nt = 0; nt < 4; ++nt) acc[mt][nt] = (floatx4){0.f, 0.f, 0.f, 0.f};

    const int hh0 = (y0 - 1) >> 1;
    const int hx0 = (x0 - 1) >> 1;

    for (int chunk = 0; chunk < 6; ++chunk) {
        __syncthreads();
        if (chunk < 4) {
            // bn path (half-res): 4 rows x 26 xi x 4 octets
            for (int e = tid; e < 4 * 26 * 4; e += BS) {
                int xi = e % 26;
                int rest = e / 26;
                int oct = rest & 3;
                int row = rest >> 2;
                int hy = hh0 + row, hx = hx0 + xi;
                bool ok = (hy >= 0 && hy < 96 && hx >= 0 && hx < 96);
                const float* gp = bn_ +
                    ((size_t)(n * 128 + chunk * 32 + oct * 8) * 96 + hy) * 96 + hx;
                half8 hv, lv;
#pragma unroll
                for (int j = 0; j < 8; ++j) {
                    float v = ok ? gp[(size_t)j * 96 * 96] : 0.f;
                    _Float16 h = (_Float16)v;
                    hv[j] = h;
                    lv[j] = (_Float16)(v - (float)h);
                }
                int base = (row * 50 + xi) * LDSDW + oct * 4;
                *(half8*)((char*)lds + (size_t)base * 4) = hv;
                *(half8*)((char*)lds + ((size_t)PLT + base) * 4) = lv;
            }
        } else {
            // d2 path (full-res): 6 rows x 50 xi x 4 octets
            for (int e = tid; e < 6 * 50 * 4; e += BS) {
                int xi = e % 50;
                int rest = e / 50;
                int oct = rest & 3;
                int row = rest >> 2;
                int iy = y0 - 1 + row, gx = x0 - 1 + xi;
                bool ok = (iy >= 0 && iy < Ho && gx >= 0 && gx < Wo);
                const float* gp = d2_ +
                    ((size_t)(n * 64 + (chunk - 4) * 32 + oct * 8) * Ho + iy) * Wo + gx;
                half8 hv, lv;
#pragma unroll
                for (int j = 0; j < 8; ++j) {
                    float v = ok ? gp[(size_t)j * Ho * Wo] : 0.f;
                    _Float16 h = (_Float16)v;
                    hv[j] = h;
                    lv[j] = (_Float16)(v - (float)h);
                }
                int base = (row * 50 + xi) * LDSDW + oct * 4;
                *(half8*)((char*)lds + (size_t)base * 4) = hv;
                *(half8*)((char*)lds + ((size_t)PLT + base) * 4) = lv;
            }
        }
        __syncthreads();
#pragma unroll
        for (int ky = 0; ky < 3; ++ky) {
#pragma unroll
            for (int kx = 0; kx < 3; ++kx) {
                int tap = ky * 3 + kx;
                const _Float16* bpp = bp + ((size_t)(chunk * 9 + tap) * 4) * 64 * 8;
                half8 bh[4], bl[4];
#pragma unroll
                for (int nt = 0; nt < 4; ++nt) {
                    bh[nt] = *(const half8*)(bpp + ((size_t)nt * 64 + lane) * 8);
                    bl[nt] = *(const half8*)(bpp + 110592 + ((size_t)nt * 64 + lane) * 8);
                }
                int row;
                if (chunk < 4) row = ((yr + ky - 1) >> 1) - hh0;
                else           row = wv + ky;
#pragma unroll
                for (int mt = 0; mt < 3; ++mt) {
                    int px = 16 * mt + m;
                    int xi = (chunk < 4) ? (((x0 + px + kx - 1) >> 1) - hx0)
                                         : (px + kx);
                    int adw = (row * 50 + xi) * LDSDW + q * 4;
                    half8 ah = *(const half8*)((const char*)lds + (size_t)adw * 4);
                    half8 al = *(const half8*)((const char*)lds + ((size_t)PLT + adw) * 4);
#pragma unroll
                    for (int nt = 0; nt < 4; ++nt) {
                        acc[mt][nt] = __builtin_amdgcn_mfma_f32_16x16x32_f16(ah, bh[nt], acc[mt][nt], 0, 0, 0);
                        acc[mt][nt] = __builtin_amdgcn_mfma_f32_16x16x32_f16(ah, bl[nt], acc[mt][nt], 0, 0, 0);
                        acc[mt][nt] = __builtin_amdgcn_mfma_f32_16x16x32_f16(al, bh[nt], acc[mt][nt], 0, 0, 0);
                    }
                }
            }
        }
    }

    // epilogue: 2 halves of 32 co; buffer [32 co][192 px]
#pragma unroll
    for (int h = 0; h < 2; ++h) {
        __syncthreads();
#pragma unroll
        for (int ntl = 0; ntl < 2; ++ntl) {
#pragma unroll
            for (int mt = 0; mt < 3; ++mt) {
#pragma unroll
                for (int r = 0; r < 4; ++r) {
                    ((float*)lds)[(ntl * 16 + m) * 192 + wv * 48 + 16 * mt + q * 4 + r]
                        = acc[mt][h * 2 + ntl][r];
                }
            }
        }
        __syncthreads();
        {
            int col = tid >> 3;            // 32 cols
            int g   = tid & 7;             // 8 threads/col, 24 px each
            int row = g >> 1, xx = (g & 1) * 24;
            int co = h * 32 + col;
            float bb = b_u1[co];
            const float* lp = (const float*)lds + col * 192 + g * 24;
            float* op = out + ((size_t)(n * 64 + co) * Ho + y0 + row) * Wo + x0 + xx;
#pragma unroll
            for (int u = 0; u < 24; u += 4) {
                float4 vv = *(const float4*)(lp + u);
                vv.x = fmaxf(vv.x + bb, 0.f);
                vv.y = fmaxf(vv.y + bb, 0.f);
                vv.z = fmaxf(vv.z + bb, 0.f);
                vv.w = fmaxf(vv.w + bb, 0.f);
                *(float4*)(op + u) = vv;
            }
        }
    }
}

// ===========================================================================
// seg via fused MFMA u2+seg, 4 rows x 48 px @384; shfl_xor co-reduce.
// R15: 48-px tile -> LDS 48,000 B -> 3 blocks/CU.
// ===========================================================================
__global__ __launch_bounds__(BS) void u2seg_mfma_kernel(
    const float* __restrict__ u1_,   // [8,64,192,192]
    const float* __restrict__ d1_,   // [8,32,384,384]
    const _Float16* __restrict__ bp,
    const float* __restrict__ b_u2,  // [32]
    const float* __restrict__ w_seg, // [32]
    const float* __restrict__ b_seg, // [1]
    float* __restrict__ seg)         // [8,1,384,384]
{
    __shared__ unsigned int lds[2 * PLT];
    const int Ho = 384, Wo = 384;
    int b = blockIdx.x;
    int xb = b % 8; b /= 8;                           // 384/48 = 8 x-tiles
    int yb = b % 96;
    int n  = b / 96;
    int y0 = yb * 4;
    int x0 = xb * 48;

    int tid = threadIdx.x;
    int lane = tid & 63, wv = tid >> 6;
    int m = lane & 15, q = lane >> 4;
    int yr = y0 + wv;

    floatx4 acc[3][2];
#pragma unroll
    for (int mt = 0; mt < 3; ++mt) {
        acc[mt][0] = (floatx4){0.f, 0.f, 0.f, 0.f};
        acc[mt][1] = (floatx4){0.f, 0.f, 0.f, 0.f};
    }

    const int hh0 = (y0 - 1) >> 1;
    const int hx0 = (x0 - 1) >> 1;

    for (int chunk = 0; chunk < 3; ++chunk) {
        __syncthreads();
        if (chunk < 2) {
            // u1 path (half-res): 4 rows x 26 xi x 4 octets
            for (int e = tid; e < 4 * 26 * 4; e += BS) {
                int xi = e % 26;
                int rest = e / 26;
                int oct = rest & 3;
                int row = rest >> 2;
                int hy = hh0 + row, hx = hx0 + xi;
                bool ok = (hy >= 0 && hy < 192 && hx >= 0 && hx < 192);
                const float* gp = u1_ +
                    ((size_t)(n * 64 + chunk * 32 + oct * 8) * 192 + hy) * 192 + hx;
                half8 hv, lv;
#pragma unroll
                for (int j = 0; j < 8; ++j) {
                    float v = ok ? gp[(size_t)j * 192 * 192] : 0.f;
                    _Float16 h = (_Float16)v;
                    hv[j] = h;
                    lv[j] = (_Float16)(v - (float)h);
                }
                int base = (row * 50 + xi) * LDSDW + oct * 4;
                *(half8*)((char*)lds + (size_t)base * 4) = hv;
                *(half8*)((char*)lds + ((size_t)PLT + base) * 4) = lv;
            }
        } else {
            // d1 path (full-res): 6 rows x 50 xi x 4 octets
            for (int e = tid; e < 6 * 50 * 4; e += BS) {
                int xi = e % 50;
                int rest = e / 50;
                int oct = rest & 3;
                int row = rest >> 2;
                int iy = y0 - 1 + row, gx = x0 - 1 + xi;
                bool ok = (iy >= 0 && iy < Ho && gx >= 0 && gx < Wo);
                const float* gp = d1_ +
                    ((size_t)(n * 32 + oct * 8) * Ho + iy) * Wo + gx;
                half8 hv, lv;
#pragma unroll
                for (int j = 0; j < 8; ++j) {
                    float v = ok ? gp[(size_t)j * Ho * Wo] : 0.f;
                    _Float16 h = (_Float16)v;
                    hv[j] = h;
                    lv[j] = (_Float16)(v - (float)h);
                }
                int base = (row * 50 + xi) * LDSDW + oct * 4;
                *(half8*)((char*)lds + (size_t)base * 4) = hv;
                *(half8*)((char*)lds + ((size_t)PLT + base) * 4) = lv;
            }
        }
        __syncthreads();
#pragma unroll
        for (int ky = 0; ky < 3; ++ky) {
#pragma unroll
            for (int kx = 0; kx < 3; ++kx) {
                int tap = ky * 3 + kx;
                const _Float16* bpp = bp + ((size_t)(chunk * 9 + tap) * 2) * 64 * 8;
                half8 bh0 = *(const half8*)(bpp + (size_t)lane * 8);
                half8 bl0 = *(const half8*)(bpp + 27648 + (size_t)lane * 8);
                half8 bh1 = *(const half8*)(bpp + ((size_t)64 + lane) * 8);
                half8 bl1 = *(const half8*)(bpp + 27648 + ((size_t)64 + lane) * 8);
                int row;
                if (chunk < 2) row = ((yr + ky - 1) >> 1) - hh0;
                else           row = wv + ky;
#pragma unroll
                for (int mt = 0; mt < 3; ++mt) {
                    int px = 16 * mt + m;
                    int xi = (chunk < 2) ? (((x0 + px + kx - 1) >> 1) - hx0)
                                         : (px + kx);
                    int adw = (row * 50 + xi) * LDSDW + q * 4;
                    half8 ah = *(const half8*)((const char*)lds + (size_t)adw * 4);
                    half8 al = *(const half8*)((const char*)lds + ((size_t)PLT + adw) * 4);
                    acc[mt][0] = __builtin_amdgcn_mfma_f32_16x16x32_f16(ah, bh0, acc[mt][0], 0, 0, 0);
                    acc[mt][0] = __builtin_amdgcn_mfma_f32_16x16x32_f16(ah, bl0, acc[mt][0], 0, 0, 0);
                    acc[mt][0] = __builtin_amdgcn_mfma_f32_16x16x32_f16(al, bh0, acc[mt][0], 0, 0, 0);
                    acc[mt][1] = __builtin_amdgcn_mfma_f32_16x16x32_f16(ah, bh1, acc[mt][1], 0, 0, 0);
                    acc[mt][1] = __builtin_amdgcn_mfma_f32_16x16x32_f16(ah, bl1, acc[mt][1], 0, 0, 0);
                    acc[mt][1] = __builtin_amdgcn_mfma_f32_16x16x32_f16(al, bh1, acc[mt][1], 0, 0, 0);
                }
            }
        }
    }

    float bb0 = b_u2[m], bb1 = b_u2[16 + m];
    float ws0 = w_seg[m], ws1 = w_seg[16 + m];
    float bseg = b_seg[0];
#pragma unroll
    for (int mt = 0; mt < 3; ++mt) {
        float sr[4];
#pragma unroll
        for (int r = 0; r < 4; ++r) {
            float p = ws0 * fmaxf(acc[mt][0][r] + bb0, 0.f)
                    + ws1 * fmaxf(acc[mt][1][r] + bb1, 0.f);
            p += __shfl_xor(p, 1);
            p += __shfl_xor(p, 2);
            p += __shfl_xor(p, 4);
            p += __shfl_xor(p, 8);
            sr[r] = p + bseg;
        }
        if (m == 0) {
            float4 o; o.x = sr[0]; o.y = sr[1]; o.z = sr[2]; o.w = sr[3];
            *(float4*)(seg + ((size_t)n * Ho + yr) * Wo + x0 + 16 * mt + q * 4) = o;
        }
    }
}

// ===========================================================================
// Vector kernels, unchanged.
// ===========================================================================

template <int UPA, int TCO>
__global__ __launch_bounds__(BS, 2) void conv3x3_x8_kernel(
    const float* __restrict__ inA, int Ca,
    const float* __restrict__ inB, int Cb,
    const float* __restrict__ w, const float* __restrict__ b,
    float* __restrict__ out,
    int N, int H, int W, int Cout, int do_relu)
{
    const int W8 = W >> 3;
    int idx = blockIdx.x * BS + threadIdx.x;
    int total = N * H * W8;
    if (idx >= total) return;
    int x8 = idx % W8;
    int t  = idx / W8;
    int y  = t % H;
    int n  = t / H;
    int x0 = x8 << 3;
    const int co0 = blockIdx.y * TCO;
    const bool left_ok  = (x0 > 0);
    const bool right_ok = (x0 + 8 < W);
    const int Cin = Ca + Cb;

    float acc[TCO][8];
#pragma unroll
    for (int j = 0; j < TCO; ++j) {
        float bv = b[co0 + j];
#pragma unroll
        for (int p = 0; p < 8; ++p) acc[j][p] = bv;
    }

    for (int ci = 0; ci < Cin; ++ci) {
        float v[3][10];
#pragma unroll
        for (int ky = 0; ky < 3; ++ky) {
            int iy = y + ky - 1;
            if (iy < 0 || iy >= H) {
#pragma unroll
                for (int p = 0; p < 10; ++p) v[ky][p] = 0.f;
                continue;
            }
            if (UPA == 2 && ci < Ca) {
                const float* r = inA + ((size_t)(n * Ca + ci) * (H >> 1) + (iy >> 1)) * (W >> 1);
                int xh = x0 >> 1;
                float sm = left_ok  ? r[xh - 1] : 0.f;
                float4 qq = *(const float4*)(r + xh);
                float s4 = right_ok ? r[xh + 4] : 0.f;
                v[ky][0] = sm;
                v[ky][1] = qq.x; v[ky][2] = qq.x;
                v[ky][3] = qq.y; v[ky][4] = qq.y;
                v[ky][5] = qq.z; v[ky][6] = qq.z;
                v[ky][7] = qq.w; v[ky][8] = qq.w;
                v[ky][9] = s4;
            } else {
                const float* r = (ci < Ca)
                    ? inA + ((size_t)(n * Ca + ci) * H + iy) * W
                    : inB + ((size_t)(n * Cb + (ci - Ca)) * H + iy) * W;
                v[ky][0] = left_ok ? r[x0 - 1] : 0.f;
                float4 q0 = *(const float4*)(r + x0);
                float4 q1 = *(const float4*)(r + x0 + 4);
                v[ky][1] = q0.x; v[ky][2] = q0.y; v[ky][3] = q0.z; v[ky][4] = q0.w;
                v[ky][5] = q1.x; v[ky][6] = q1.y; v[ky][7] = q1.z; v[ky][8] = q1.w;
                v[ky][9] = right_ok ? r[x0 + 8] : 0.f;
            }
        }
#pragma unroll
        for (int j = 0; j < TCO; ++j) {
            const float* wp = w + ((size_t)(co0 + j) * Cin + ci) * 9;
#pragma unroll
            for (int ky = 0; ky < 3; ++ky) {
                float w0 = wp[ky * 3 + 0], w1 = wp[ky * 3 + 1], w2 = wp[ky * 3 + 2];
#pragma unroll
                for (int p = 0; p < 8; ++p)
                    acc[j][p] += w0 * v[ky][p] + w1 * v[ky][p + 1] + w2 * v[ky][p + 2];
            }
        }
    }

#pragma unroll
    for (int j = 0; j < TCO; ++j) {
#pragma unroll
        for (int p = 0; p < 8; ++p)
            if (do_relu) acc[j][p] = fmaxf(acc[j][p], 0.f);
        float* o = out + ((size_t)(n * Cout + co0 + j) * H + y) * W + x0;
        float4 q0; q0.x = acc[j][0]; q0.y = acc[j][1]; q0.z = acc[j][2]; q0.w = acc[j][3];
        float4 q1; q1.x = acc[j][4]; q1.y = acc[j][5]; q1.z = acc[j][6]; q1.w = acc[j][7];
        *(float4*)o = q0;
        *(float4*)(o + 4) = q1;
    }
}

template <int TCO>
__global__ __launch_bounds__(BS) void conv3x3_s2_co_kernel(
    const float* __restrict__ inA, int Ca,
    const float* __restrict__ inB, int Cb,
    const float* __restrict__ w, const float* __restrict__ b,
    float* __restrict__ out,
    int N, int Hi, int Wi, int Cout, int do_relu)
{
    const int Ho = Hi >> 1, Wo = Wi >> 1, Woq = Wo >> 2;
    int idx = blockIdx.x * BS + threadIdx.x;
    int total = N * Ho * Woq;
    if (idx >= total) return;
    int q  = idx % Woq;
    int t  = idx / Woq;
    int oy = t % Ho;
    int n  = t / Ho;
    int ox0 = q << 2;
    int ix0 = ox0 << 1;
    const int co0 = blockIdx.y * TCO;
    const bool right_ok = (ix0 + 8 < Wi);
    const int Cin = Ca + Cb;

    float acc[TCO][4];
#pragma unroll
    for (int j = 0; j < TCO; ++j) {
        float bv = b[co0 + j];
        acc[j][0] = bv; acc[j][1] = bv; acc[j][2] = bv; acc[j][3] = bv;
    }

    for (int ci = 0; ci < Cin; ++ci) {
        const float* base = (ci < Ca)
            ? inA + (size_t)(n * Ca + ci) * Hi * Wi
            : inB + (size_t)(n * Cb + (ci - Ca)) * Hi * Wi;
        float v[3][9];
#pragma unroll
        for (int ky = 0; ky < 3; ++ky) {
            int iy = 2 * oy + ky;
            if (iy >= Hi) {
#pragma unroll
                for (int p = 0; p < 9; ++p) v[ky][p] = 0.f;
                continue;
            }
            const float* r = base + (size_t)iy * Wi + ix0;
            float4 a = *(const float4*)r;
            float4 c = *(const float4*)(r + 4);
            v[ky][0] = a.x; v[ky][1] = a.y; v[ky][2] = a.z; v[ky][3] = a.w;
            v[ky][4] = c.x; v[ky][5] = c.y; v[ky][6] = c.z; v[ky][7] = c.w;
            v[ky][8] = right_ok ? r[8] : 0.f;
        }
#pragma unroll
        for (int j = 0; j < TCO; ++j) {
            const float* wp = w + ((size_t)(co0 + j) * Cin + ci) * 9;
#pragma unroll
            for (int ky = 0; ky < 3; ++ky) {
                float w0 = wp[ky * 3 + 0], w1 = wp[ky * 3 + 1], w2 = wp[ky * 3 + 2];
#pragma unroll
                for (int p = 0; p < 4; ++p)
                    acc[j][p] += w0 * v[ky][2 * p] + w1 * v[ky][2 * p + 1] + w2 * v[ky][2 * p + 2];
            }
        }
    }

#pragma unroll
    for (int j = 0; j < TCO; ++j) {
        float4 o;
        o.x = acc[j][0]; o.y = acc[j][1]; o.z = acc[j][2]; o.w = acc[j][3];
        if (do_relu) {
            o.x = fmaxf(o.x, 0.f); o.y = fmaxf(o.y, 0.f);
            o.z = fmaxf(o.z, 0.f); o.w = fmaxf(o.w, 0.f);
        }
        *(float4*)(out + ((size_t)(n * Cout + co0 + j) * Ho + oy) * Wo + ox0) = o;
    }
}

__global__ __launch_bounds__(BS) void maxpool2_kernel(
    const float* __restrict__ in, float* __restrict__ out, int NC, int H, int W)
{
    int Ho = H >> 1, Wo = W >> 1, Woq = Wo >> 2;
    int idx = blockIdx.x * BS + threadIdx.x;
    int total = NC * Ho * Woq;
    if (idx >= total) return;
    int x4 = idx % Woq;
    int t  = idx / Woq;
    int y  = t % Ho;
    int c  = t / Ho;
    const float* r0 = in + ((size_t)c * H + 2 * y) * W + 8 * x4;
    const float* r1 = r0 + W;
    float4 a0 = *(const float4*)r0;
    float4 a1 = *(const float4*)(r0 + 4);
    float4 b0 = *(const float4*)r1;
    float4 b1 = *(const float4*)(r1 + 4);
    float4 o;
    o.x = fmaxf(fmaxf(a0.x, a0.y), fmaxf(b0.x, b0.y));
    o.y = fmaxf(fmaxf(a0.z, a0.w), fmaxf(b0.z, b0.w));
    o.z = fmaxf(fmaxf(a1.x, a1.y), fmaxf(b1.x, b1.y));
    o.w = fmaxf(fmaxf(a1.z, a1.w), fmaxf(b1.z, b1.w));
    *(float4*)(out + ((size_t)c * Ho + y) * Wo + 4 * x4) = o;
}

__global__ __launch_bounds__(BS) void peaks_kernel(
    const float* __restrict__ hm, float* __restrict__ out,
    int NC, int H, int W, float thresh)
{
    int idx = blockIdx.x * BS + threadIdx.x;
    int total = NC * H * W;
    if (idx >= total) return;
    int x = idx % W;
    int t = idx / W;
    int y = t % H;
    int c = t / H;
    float r = 0.f;
    if (x >= 1 && x < W - 1 && y >= 1 && y < H - 1) {
        const float* base = hm + (size_t)c * H * W;
        float cv = base[y * W + x];
        if (cv > thresh &&
            cv >= base[(y - 1) * W + x] &&
            cv >= base[(y + 1) * W + x] &&
            cv >= base[y * W + (x - 1)] &&
            cv >= base[y * W + (x + 1)])
            r = 1.f;
    }
    out[idx] = r;
}

static inline int nblk(long n) { return (int)((n + BS - 1) / BS); }

extern "C" void kernel_launch(void* const* d_in, const int* in_sizes, int n_in,
                              void* d_out, int out_size, void* d_ws, size_t ws_size,
                              hipStream_t stream)
{
    const float* x     = (const float*)d_in[0];
    const float* w_d1  = (const float*)d_in[1];  const float* b_d1  = (const float*)d_in[2];
    const float* w_d2  = (const float*)d_in[3];  const float* b_d2  = (const float*)d_in[4];
    const float* w_bn  = (const float*)d_in[5];  const float* b_bn  = (const float*)d_in[6];
    const float* w_u1  = (const float*)d_in[7];  const float* b_u1  = (const float*)d_in[8];
    const float* w_u2  = (const float*)d_in[9];  const float* b_u2  = (const float*)d_in[10];
    const float* w_seg = (const float*)d_in[11]; const float* b_seg = (const float*)d_in[12];
    const float* w_p1  = (const float*)d_in[13]; const float* b_p1  = (const float*)d_in[14];
    const float* w_p2  = (const float*)d_in[15]; const float* b_p2  = (const float*)d_in[16];
    const float* w_hm  = (const float*)d_in[17]; const float* b_hm  = (const float*)d_in[18];
    const float* w_paf = (const float*)d_in[19]; const float* b_paf = (const float*)d_in[20];

    const int N = 8, H = 384, W = 384;
    const int H2 = 192, W2 = 192, H4 = 96, W4 = 96;

    float* ws = (float*)d_ws;
    // Workspace extent = 56,623,104 floats = 216 MiB (R2 lifetime map).
    float* u1  = ws;                   // 8*64*192*192 = 18874368
    float* d1  = ws + 18874368;        // 8*32*384*384 = 37748736
    float* d2  = ws + 18874368;        // 8*64*192*192 = 18874368
    float* bn  = ws + 37748736;        // 8*128*96*96  = 9437184
    float* pd1 = ws;                   // 8*32*192*192 = 9437184
    float* pd2 = ws + 47185920;        // 8*64*96*96   = 4718592
    float* p1  = ws;                   // 8*64*192*192 = 18874368
    float* p2  = ws + 18874368;        // 8*128*96*96  = 9437184

    float* out_seg   = (float*)d_out;                 // 1179648
    float* out_hm    = out_seg + 1179648;             // 1253376
    float* out_paf   = out_hm + 1253376;              // 2359296
    float* out_peaks = out_paf + 2359296;             // 1253376
    // packed weights in the peaks region [4792320, 6045696), all consumed
    // before step 13 overwrites them. 16B-aligned.
    _Float16* bp_u1  = (_Float16*)(out_seg + 4792320); // 110592 fl
    _Float16* bp_u2  = (_Float16*)(out_seg + 4902912); // 27648 fl
    _Float16* bp_d2  = (_Float16*)(out_seg + 4930560); // 18432 fl
    _Float16* bp_bn  = (_Float16*)(out_seg + 4948992); // 73728 fl
    _Float16* bp_p2  = (_Float16*)(out_seg + 5022720); // 73728 fl
    _Float16* bp_hm  = (_Float16*)(out_seg + 5096448); // 4096 fl
    _Float16* bp_paf = (_Float16*)(out_seg + 5100544); // 4096 fl -> ends 5104640

    // 0. pack weights
    packw_gen_kernel<<<nblk(13824), BS, 0, stream>>>(w_u1, bp_u1, 192, 64);
    packw_gen_kernel<<<nblk(3456),  BS, 0, stream>>>(w_u2, bp_u2, 96, 32);
    packw_gen_kernel<<<nblk(2304),  BS, 0, stream>>>(w_d2, bp_d2, 32, 64);
    packw_gen_kernel<<<nblk(9216),  BS, 0, stream>>>(w_bn, bp_bn, 64, 128);
    packw_gen_kernel<<<nblk(9216),  BS, 0, stream>>>(w_p2, bp_p2, 64, 128);
    packw_1x1_kernel<<<nblk(512),   BS, 0, stream>>>(w_hm, bp_hm, 128, 2, 17);
    packw_1x1_kernel<<<nblk(512),   BS, 0, stream>>>(w_paf, bp_paf, 128, 2, 32);
    // 1. d1 = relu(conv3x3(x; 3->32)) @384
    {
        dim3 g(nblk((long)N * H * (W / 8)), 32 / 8);
        conv3x3_x8_kernel<1, 8><<<g, BS, 0, stream>>>(
            x, 3, nullptr, 0, w_d1, b_d1, d1, N, H, W, 32, 1);
    }
    // 2. pd1 = maxpool(d1) @192
    maxpool2_kernel<<<nblk((long)N * 32 * H2 * (W2 / 4)), BS, 0, stream>>>(d1, pd1, N * 32, H, W);
    // 3. d2 = relu(conv3x3(pd1; 32->64)) @192  [MFMA]
    conv3x3_mfma_kernel<1, 4, 192, 192><<<8 * 96 * 6, BS, 0, stream>>>(
        pd1, bp_d2, b_d2, d2);
    // 4. pd2 = maxpool(d2) @96
    maxpool2_kernel<<<nblk((long)N * 64 * H4 * (W4 / 4)), BS, 0, stream>>>(d2, pd2, N * 64, H2, W2);
    // 5. bn = relu(conv3x3(pd2; 64->128)) @96  [MFMA]
    conv3x3_mfma_kernel<2, 8, 96, 96><<<8 * 48 * 3, BS, 0, stream>>>(
        pd2, bp_bn, b_bn, bn);
    // 6. u1 = relu(conv3x3(concat(up2(bn), d2); 192->64)) @192  [MFMA 4x48, 3 blk/CU]
    u1_mfma_kernel<<<8 * 48 * 4, BS, 0, stream>>>(bn, d2, bp_u1, b_u1, u1);
    // 7. d1' = relu(conv3x3(x; 3->32)) @384  (recompute)
    {
        dim3 g(nblk((long)N * H * (W / 8)), 32 / 8);
        conv3x3_x8_kernel<1, 8><<<g, BS, 0, stream>>>(
            x, 3, nullptr, 0, w_d1, b_d1, d1, N, H, W, 32, 1);
    }
    // 8. seg via fused MFMA u2+seg @384  [MFMA 4x48, 3 blk/CU]
    u2seg_mfma_kernel<<<8 * 96 * 8, BS, 0, stream>>>(
        u1, d1, bp_u2, b_u2, w_seg, b_seg, out_seg);
    // 9. p1 = relu(conv3x3_s2(concat(x, seg); 4->64)) @384->192  [vector]
    {
        dim3 g(nblk((long)N * H2 * (W2 / 4)), 64 / 8);
        conv3x3_s2_co_kernel<8><<<g, BS, 0, stream>>>(
            x, 3, out_seg, 1, w_p1, b_p1, p1, N, H, W, 64, 1);
    }
    // 10. p2 = relu(conv3x3_s2(p1; 64->128)) @192->96  [MFMA s2]
    conv3x3s2_mfma_kernel<2, 8, 192><<<8 * 48 * 3, BS, 0, stream>>>(
        p1, bp_p2, b_p2, p2);
    // 11. hm = conv1x1(p2; 128->17) @96  [MFMA 1x1]
    conv1x1_mfma_kernel<4, 2><<<8 * 144, BS, 0, stream>>>(
        p2, bp_hm, b_hm, out_hm, 17, H4 * W4);
    // 12. paf = conv1x1(p2; 128->32) @96  [MFMA 1x1]
    conv1x1_mfma_kernel<4, 2><<<8 * 144, BS, 0, stream>>>(
        p2, bp_paf, b_paf, out_paf, 32, H4 * W4);
    // 13. peaks @96  (overwrites packed-weight region - already consumed)
    peaks_kernel<<<nblk((long)N * 17 * H4 * W4), BS, 0, stream>>>(
        out_hm, out_peaks, N * 17, H4, W4, 0.1f);
}

// Round 3
// 982.764 us; speedup vs baseline: 1.3854x; 1.0309x over previous
//
#include <hip/hip_runtime.h>

// ---------------------------------------------------------------------------
// TeacherModel: small U-Net + pose heads. B=8, H=W=384, fp32 NCHW.
// Round 16: producer-side f16 hi/lo split. Feature maps feeding the MFMA
//  4-row kernels (bn, d2, u1, d1') are emitted in [C/8][H][W][8] hi/lo f16
//  planes by their producers; u1/u2seg staging becomes 2x16B coalesced loads
//  + 2 ds_writes (no per-item cvt VALU, half the staged fetch bytes).
//  Bit-identical: hi=f16(v), lo=f16(v-hi) computed from the same fp32 v.
// R15: 4-row kernels at 4x48 px tile -> 48KB LDS -> 3 blocks/CU.
// Workspace lifetime map (floats, 56,623,104 total):
//  d1 fp32   [18.9M..56.6M) live s1->s2
//  pd1       [0..9.4M)      live s2->s3
//  d2 fp32   [9.4M..28.3M)  live s3->s4
//  d2sp h/l  [28.3M..47.2M) live s3->s6
//  pd2       [47.2M..51.9M) live s4->s5
//  bnsp h/l  [18.9M..28.3M) live s5->s6
//  u1sp h/l  [0..18.9M)     live s6->s8
//  d1sp h/l  [18.9M..56.6M) live s7->s8
//  p1        [0..18.9M)     live s9->s10
//  p2        [18.9M..28.3M) live s10->s12
// ---------------------------------------------------------------------------

#define BS 256

typedef _Float16 half8 __attribute__((ext_vector_type(8)));
typedef float floatx4 __attribute__((ext_vector_type(4)));

#define LDSDW 20    // dwords per x position
#define PLT 6000    // 6*50*LDSDW dwords per plane (4-row x 48-px kernels)

// ===========================================================================
// Generic 3x3 weight pre-pack: [plane(hi/lo)][chunk][tap(9)][nt][lane][8]
// ===========================================================================
__global__ __launch_bounds__(BS) void packw_gen_kernel(
    const float* __restrict__ w, _Float16* __restrict__ bp, int Cin, int Cout)
{
    int total = (Cin >> 5) * 9 * (Cout >> 4) * 64;
    int tid = blockIdx.x * BS + threadIdx.x;
    if (tid >= total) return;
    int lane = tid & 63;
    int t = tid >> 6;
    int NTl = Cout >> 4;
    int nt = t % NTl; t /= NTl;
    int tap = t % 9;
    int chunk = t / 9;
    int q = lane >> 4, n = lane & 15;
    int co = nt * 16 + n;
    _Float16* ph = bp + (size_t)tid * 8;
    _Float16* pl = bp + (size_t)total * 8 + (size_t)tid * 8;
#pragma unroll
    for (int j = 0; j < 8; ++j) {
        int ci = chunk * 32 + q * 8 + j;
        float v = w[((size_t)co * Cin + ci) * 9 + tap];
        _Float16 h = (_Float16)v;
        ph[j] = h;
        pl[j] = (_Float16)(v - (float)h);
    }
}

// 1x1 weight pre-pack: [plane][chunk][nt][lane][8]; co >= Cout -> 0.
__global__ __launch_bounds__(BS) void packw_1x1_kernel(
    const float* __restrict__ w, _Float16* __restrict__ bp, int Cin, int NTl, int Cout)
{
    int total = (Cin >> 5) * NTl * 64;
    int tid = blockIdx.x * BS + threadIdx.x;
    if (tid >= total) return;
    int lane = tid & 63;
    int t = tid >> 6;
    int nt = t % NTl;
    int chunk = t / NTl;
    int q = lane >> 4, n = lane & 15;
    int co = nt * 16 + n;
    _Float16* ph = bp + (size_t)tid * 8;
    _Float16* pl = bp + (size_t)total * 8 + (size_t)tid * 8;
#pragma unroll
    for (int j = 0; j < 8; ++j) {
        int ci = chunk * 32 + q * 8 + j;
        float v = (co < Cout) ? w[(size_t)co * Cin + ci] : 0.f;
        _Float16 h = (_Float16)v;
        ph[j] = h;
        pl[j] = (_Float16)(v - (float)h);
    }
}

// ===========================================================================
// Generic stride-1 3x3 SAME conv via MFMA: block = 2 rows x 32 px.
// OUTMODE: 0 = fp32 only, 1 = split only, 2 = both.
// Split layout: [C/8][H][W][8] per plane (hi, lo), relu applied.
// ===========================================================================
template <int CHUNKS, int NT, int HH, int WW, int OUTMODE>
__global__ __launch_bounds__(BS) void conv3x3_mfma_kernel(
    const float* __restrict__ in_,
    const _Float16* __restrict__ bp,
    const float* __restrict__ bias,
    float* __restrict__ out,
    _Float16* __restrict__ osph,
    _Float16* __restrict__ ospl)
{
    constexpr int PL = 4 * 34 * LDSDW;
    constexpr int EPI = 64 * NT * 16;
    constexpr int LDS_DW = (2 * PL > EPI) ? 2 * PL : EPI;
    __shared__ unsigned int lds[LDS_DW];

    int xblks = WW / 32;
    int b = blockIdx.x;
    int xb = b % xblks; b /= xblks;
    int yp = b % (HH / 2);
    int n  = b / (HH / 2);
    int y0 = yp * 2;
    int x0 = xb * 32;

    int tid = threadIdx.x;
    int lane = tid & 63, wv = tid >> 6;
    int m = lane & 15, q = lane >> 4;
    int lrow = wv >> 1;
    int lx   = (wv & 1) * 16;

    floatx4 acc[NT];
#pragma unroll
    for (int nt = 0; nt < NT; ++nt) acc[nt] = (floatx4){0.f, 0.f, 0.f, 0.f};

    const int planeW = CHUNKS * 9 * NT * 64 * 8;

    for (int chunk = 0; chunk < CHUNKS; ++chunk) {
        __syncthreads();
        for (int e = tid; e < 4 * 34 * 4; e += BS) {
            int xi = e % 34;
            int rest = e / 34;
            int oct = rest & 3;
            int row = rest >> 2;
            int iy = y0 - 1 + row, gx = x0 - 1 + xi;
            bool ok = (iy >= 0 && iy < HH && gx >= 0 && gx < WW);
            const float* gp = in_ +
                ((size_t)(n * (CHUNKS * 32) + chunk * 32 + oct * 8) * HH + iy) * WW + gx;
            half8 hv, lv;
#pragma unroll
            for (int j = 0; j < 8; ++j) {
                float v = ok ? gp[(size_t)j * HH * WW] : 0.f;
                _Float16 h = (_Float16)v;
                hv[j] = h;
                lv[j] = (_Float16)(v - (float)h);
            }
            int base = (row * 34 + xi) * LDSDW + oct * 4;
            *(half8*)((char*)lds + (size_t)base * 4) = hv;
            *(half8*)((char*)lds + ((size_t)PL + base) * 4) = lv;
        }
        __syncthreads();
#pragma unroll
        for (int ky = 0; ky < 3; ++ky) {
#pragma unroll
            for (int kx = 0; kx < 3; ++kx) {
                int row = lrow + ky;
                int xi  = lx + m + kx;
                int adw = (row * 34 + xi) * LDSDW + q * 4;
                half8 ah = *(const half8*)((const char*)lds + (size_t)adw * 4);
                half8 al = *(const half8*)((const char*)lds + ((size_t)PL + adw) * 4);
                int tap = ky * 3 + kx;
                const _Float16* bpp = bp + ((size_t)(chunk * 9 + tap) * NT) * 64 * 8;
#pragma unroll
                for (int nt = 0; nt < NT; ++nt) {
                    half8 bh = *(const half8*)(bpp + ((size_t)nt * 64 + lane) * 8);
                    half8 bl = *(const half8*)(bpp + planeW + ((size_t)nt * 64 + lane) * 8);
                    acc[nt] = __builtin_amdgcn_mfma_f32_16x16x32_f16(ah, bh, acc[nt], 0, 0, 0);
                    acc[nt] = __builtin_amdgcn_mfma_f32_16x16x32_f16(ah, bl, acc[nt], 0, 0, 0);
                    acc[nt] = __builtin_amdgcn_mfma_f32_16x16x32_f16(al, bh, acc[nt], 0, 0, 0);
                }
            }
        }
    }

    __syncthreads();
#pragma unroll
    for (int nt = 0; nt < NT; ++nt) {
#pragma unroll
        for (int r = 0; r < 4; ++r) {
            int co = nt * 16 + m;
            int pxl = wv * 16 + q * 4 + r;
            ((float*)lds)[co * 64 + pxl] = acc[nt][r];
        }
    }
    __syncthreads();
    if (OUTMODE != 1) {
        constexpr int thPerCo = 256 / (NT * 16);
        constexpr int pxPerTh = 64 / thPerCo;
        int co = tid / thPerCo;
        int sub = tid % thPerCo;
        int pxb = sub * pxPerTh;
        float bb = bias[co];
#pragma unroll
        for (int u = 0; u < pxPerTh; u += 4) {
            int p = pxb + u;
            int row = y0 + (p >> 5), xx = x0 + (p & 31);
            const float* lp = (const float*)lds + co * 64 + p;
            float4 vv = *(const float4*)lp;
            vv.x = fmaxf(vv.x + bb, 0.f);
            vv.y = fmaxf(vv.y + bb, 0.f);
            vv.z = fmaxf(vv.z + bb, 0.f);
            vv.w = fmaxf(vv.w + bb, 0.f);
            *(float4*)(out + ((size_t)(n * NT * 16 + co) * HH + row) * WW + xx) = vv;
        }
    }
    if (OUTMODE >= 1) {
        constexpr int OCTS = NT * 2;
        for (int it = tid; it < OCTS * 64; it += BS) {
            int px = it & 63;
            int oct = it >> 6;
            int row = y0 + (px >> 5), xx = x0 + (px & 31);
            half8 hv, lv;
#pragma unroll
            for (int j = 0; j < 8; ++j) {
                float v = fmaxf(((float*)lds)[(oct * 8 + j) * 64 + px] + bias[oct * 8 + j], 0.f);
                _Float16 hh = (_Float16)v;
                hv[j] = hh;
                lv[j] = (_Float16)(v - (float)hh);
            }
            size_t oaddr = ((size_t)((n * OCTS + oct) * HH + row) * WW + xx) * 8;
            *(half8*)(osph + oaddr) = hv;
            *(half8*)(ospl + oaddr) = lv;
        }
    }
}

// ===========================================================================
// Stride-2 3x3 conv (pad_lo=0, pad_hi=1) via MFMA: block = 2 out-rows x 32 px.
// ===========================================================================
template <int CHUNKS, int NT, int WI>
__global__ __launch_bounds__(BS) void conv3x3s2_mfma_kernel(
    const float* __restrict__ in_,   // [8, CHUNKS*32, WI, WI]
    const _Float16* __restrict__ bp,
    const float* __restrict__ bias,  // [NT*16]
    float* __restrict__ out)         // [8, NT*16, WI/2, WI/2]
{
    constexpr int WO = WI / 2;
    constexpr int PLs = 5 * 68 * LDSDW;               // 6800 dw per plane
    constexpr int EPI = 64 * NT * 16;
    constexpr int LDS_DW = (2 * PLs > EPI) ? 2 * PLs : EPI;
    __shared__ unsigned int lds[LDS_DW];

    int xblks = WO / 32;
    int b = blockIdx.x;
    int xb = b % xblks; b /= xblks;
    int yp = b % (WO / 2);
    int n  = b / (WO / 2);
    int y0 = yp * 2;                                  // output rows y0, y0+1
    int x0 = xb * 32;

    int tid = threadIdx.x;
    int lane = tid & 63, wv = tid >> 6;
    int m = lane & 15, q = lane >> 4;
    int lrow = wv >> 1;
    int lx   = (wv & 1) * 16;

    floatx4 acc[NT];
#pragma unroll
    for (int nt = 0; nt < NT; ++nt) acc[nt] = (floatx4){0.f, 0.f, 0.f, 0.f};

    const int planeW = CHUNKS * 9 * NT * 64 * 8;

    for (int chunk = 0; chunk < CHUNKS; ++chunk) {
        __syncthreads();
        // stage 5 input rows x 65 xi (pad 68) x 4 octets; swizzled x position
        for (int e = tid; e < 5 * 68 * 4; e += BS) {
            int xi = e % 68;
            int rest = e / 68;
            int oct = rest & 3;
            int row = rest >> 2;                      // 0..4
            int iy = 2 * y0 + row, ix = 2 * x0 + xi;  // pad_lo = 0
            bool ok = (xi < 65 && iy < WI && ix < WI);
            const float* gp = in_ +
                ((size_t)(n * (CHUNKS * 32) + chunk * 32 + oct * 8) * WI + iy) * WI + ix;
            half8 hv, lv;
#pragma unroll
            for (int j = 0; j < 8; ++j) {
                float v = ok ? gp[(size_t)j * WI * WI] : 0.f;
                _Float16 h = (_Float16)v;
                hv[j] = h;
                lv[j] = (_Float16)(v - (float)h);
            }
            int pos = (xi & 1) * 34 + (xi >> 1);      // parity split
            int base = (row * 68 + pos) * LDSDW + oct * 4;
            *(half8*)((char*)lds + (size_t)base * 4) = hv;
            *(half8*)((char*)lds + ((size_t)PLs + base) * 4) = lv;
        }
        __syncthreads();
#pragma unroll
        for (int ky = 0; ky < 3; ++ky) {
#pragma unroll
            for (int kx = 0; kx < 3; ++kx) {
                int row = 2 * lrow + ky;              // 0..4
                int pos = (kx & 1) * 34 + (lx + m) + (kx >> 1);
                int adw = (row * 68 + pos) * LDSDW + q * 4;
                half8 ah = *(const half8*)((const char*)lds + (size_t)adw * 4);
                half8 al = *(const half8*)((const char*)lds + ((size_t)PLs + adw) * 4);
                int tap = ky * 3 + kx;
                const _Float16* bpp = bp + ((size_t)(chunk * 9 + tap) * NT) * 64 * 8;
#pragma unroll
                for (int nt = 0; nt < NT; ++nt) {
                    half8 bh = *(const half8*)(bpp + ((size_t)nt * 64 + lane) * 8);
                    half8 bl = *(const half8*)(bpp + planeW + ((size_t)nt * 64 + lane) * 8);
                    acc[nt] = __builtin_amdgcn_mfma_f32_16x16x32_f16(ah, bh, acc[nt], 0, 0, 0);
                    acc[nt] = __builtin_amdgcn_mfma_f32_16x16x32_f16(ah, bl, acc[nt], 0, 0, 0);
                    acc[nt] = __builtin_amdgcn_mfma_f32_16x16x32_f16(al, bh, acc[nt], 0, 0, 0);
                }
            }
        }
    }

    __syncthreads();
#pragma unroll
    for (int nt = 0; nt < NT; ++nt) {
#pragma unroll
        for (int r = 0; r < 4; ++r) {
            int co = nt * 16 + m;
            int pxl = wv * 16 + q * 4 + r;
            ((float*)lds)[co * 64 + pxl] = acc[nt][r];
        }
    }
    __syncthreads();
    {
        constexpr int thPerCo = 256 / (NT * 16);
        constexpr int pxPerTh = 64 / thPerCo;
        int co = tid / thPerCo;
        int sub = tid % thPerCo;
        int pxb = sub * pxPerTh;
        float bb = bias[co];
#pragma unroll
        for (int u = 0; u < pxPerTh; u += 4) {
            int p = pxb + u;
            int row = y0 + (p >> 5), xx = x0 + (p & 31);
            const float* lp = (const float*)lds + co * 64 + p;
            float4 vv = *(const float4*)lp;
            vv.x = fmaxf(vv.x + bb, 0.f);
            vv.y = fmaxf(vv.y + bb, 0.f);
            vv.z = fmaxf(vv.z + bb, 0.f);
            vv.w = fmaxf(vv.w + bb, 0.f);
            *(float4*)(out + ((size_t)(n * NT * 16 + co) * WO + row) * WO + xx) = vv;
        }
    }
}

// ===========================================================================
// 1x1 conv via MFMA GEMM: M = 64 px/block, N = NT*16 (store only co < Cout),
// K = CHUNKS*32. No relu (heads).
// ===========================================================================
template <int CHUNKS, int NT>
__global__ __launch_bounds__(BS) void conv1x1_mfma_kernel(
    const float* __restrict__ in_,   // [8, CHUNKS*32, HW]
    const _Float16* __restrict__ bp,
    const float* __restrict__ bias,  // [Cout]
    float* __restrict__ out,         // [8, Cout, HW]
    int Cout, int HW)
{
    constexpr int PL1 = 64 * LDSDW;                   // 1280 dw per plane
    constexpr int EPI = 64 * NT * 16;
    constexpr int LDS_DW = (2 * PL1 > EPI) ? 2 * PL1 : EPI;
    __shared__ unsigned int lds[LDS_DW];

    int pblks = HW / 64;
    int b = blockIdx.x;
    int pb = b % pblks;
    int n  = b / pblks;
    int sp0 = pb * 64;

    int tid = threadIdx.x;
    int lane = tid & 63, wv = tid >> 6;
    int m = lane & 15, q = lane >> 4;

    floatx4 acc[NT];
#pragma unroll
    for (int nt = 0; nt < NT; ++nt) acc[nt] = (floatx4){0.f, 0.f, 0.f, 0.f};

    const int planeW = CHUNKS * NT * 64 * 8;

    for (int chunk = 0; chunk < CHUNKS; ++chunk) {
        __syncthreads();
        // stage 64 px x 4 octets (one item per thread)
        {
            int px = tid & 63;
            int oct = tid >> 6;
            const float* gp = in_ +
                ((size_t)(n * (CHUNKS * 32) + chunk * 32 + oct * 8)) * HW + sp0 + px;
            half8 hv, lv;
#pragma unroll
            for (int j = 0; j < 8; ++j) {
                float v = gp[(size_t)j * HW];
                _Float16 h = (_Float16)v;
                hv[j] = h;
                lv[j] = (_Float16)(v - (float)h);
            }
            int base = px * LDSDW + oct * 4;
            *(half8*)((char*)lds + (size_t)base * 4) = hv;
            *(half8*)((char*)lds + ((size_t)PL1 + base) * 4) = lv;
        }
        __syncthreads();
        {
            int adw = (wv * 16 + m) * LDSDW + q * 4;
            half8 ah = *(const half8*)((const char*)lds + (size_t)adw * 4);
            half8 al = *(const half8*)((const char*)lds + ((size_t)PL1 + adw) * 4);
            const _Float16* bpp = bp + ((size_t)chunk * NT) * 64 * 8;
#pragma unroll
            for (int nt = 0; nt < NT; ++nt) {
                half8 bh = *(const half8*)(bpp + ((size_t)nt * 64 + lane) * 8);
                half8 bl = *(const half8*)(bpp + planeW + ((size_t)nt * 64 + lane) * 8);
                acc[nt] = __builtin_amdgcn_mfma_f32_16x16x32_f16(ah, bh, acc[nt], 0, 0, 0);
                acc[nt] = __builtin_amdgcn_mfma_f32_16x16x32_f16(ah, bl, acc[nt], 0, 0, 0);
                acc[nt] = __builtin_amdgcn_mfma_f32_16x16x32_f16(al, bh, acc[nt], 0, 0, 0);
            }
        }
    }

    __syncthreads();
#pragma unroll
    for (int nt = 0; nt < NT; ++nt) {
#pragma unroll
        for (int r = 0; r < 4; ++r) {
            ((float*)lds)[(nt * 16 + m) * 64 + wv * 16 + q * 4 + r] = acc[nt][r];
        }
    }
    __syncthreads();
    {
        constexpr int thPerCo = 256 / (NT * 16);      // NT=2 -> 8
        constexpr int pxPerTh = 64 / thPerCo;         // 8
        int co = tid / thPerCo;
        int g  = tid % thPerCo;
        if (co < Cout) {
            float bb = bias[co];
            const float* lp = (const float*)lds + co * 64 + g * pxPerTh;
            float* op = out + ((size_t)(n * Cout + co)) * HW + sp0 + g * pxPerTh;
#pragma unroll
            for (int u = 0; u < pxPerTh; u += 4) {
                float4 vv = *(const float4*)(lp + u);
                vv.x += bb; vv.y += bb; vv.z += bb; vv.w += bb;
                *(float4*)(op + u) = vv;
            }
        }
    }
}

// ===========================================================================
// u1 = relu(conv3x3(concat(up2(bn), d2))) via MFMA, 4 rows x 48 px @192.
// R16: inputs are pre-split hi/lo f16 planes ([C/8][H][W][8]); staging is a
// pure copy. Output written split-only (feeds only u2seg).
// ===========================================================================
__global__ __launch_bounds__(BS) void u1_mfma_kernel(
    const _Float16* __restrict__ bnh, const _Float16* __restrict__ bnl,  // [8,16,96,96,8]
    const _Float16* __restrict__ d2h, const _Float16* __restrict__ d2l,  // [8,8,192,192,8]
    const _Float16* __restrict__ bp,
    const float* __restrict__ b_u1,  // [64]
    _Float16* __restrict__ oh, _Float16* __restrict__ ol_)               // [8,8,192,192,8]
{
    __shared__ unsigned int lds[2 * PLT];
    const int Ho = 192, Wo = 192;
    int b = blockIdx.x;
    int xb = b % 4; b /= 4;                           // 192/48 = 4 x-tiles
    int yb = b % 48;
    int n  = b / 48;
    int y0 = yb * 4;
    int x0 = xb * 48;

    int tid = threadIdx.x;
    int lane = tid & 63, wv = tid >> 6;
    int m = lane & 15, q = lane >> 4;
    int yr = y0 + wv;

    floatx4 acc[3][4];
#pragma unroll
    for (int mt = 0; mt < 3; ++mt)
#pragma unroll
        for (int nt = 0; nt < 4; ++nt) acc[mt][nt] = (floatx4){0.f, 0.f, 0.f, 0.f};

    const int hh0 = (y0 - 1) >> 1;
    const int hx0 = (x0 - 1) >> 1;

    for (int chunk = 0; chunk < 6; ++chunk) {
        __syncthreads();
        if (chunk < 4) {
            // bn path (half-res): 4 rows x 26 xi x 4 octets, copy from split planes
            for (int e = tid; e < 4 * 26 * 4; e += BS) {
                int xi = e % 26;
                int rest = e / 26;
                int oct = rest & 3;
                int row = rest >> 2;
                int hy = hh0 + row, hx = hx0 + xi;
                half8 hv = {}, lv = {};
                if (hy >= 0 && hy < 96 && hx >= 0 && hx < 96) {
                    size_t ga = ((size_t)((n * 16 + chunk * 4 + oct) * 96 + hy) * 96 + hx) * 8;
                    hv = *(const half8*)(bnh + ga);
                    lv = *(const half8*)(bnl + ga);
                }
                int base = (row * 50 + xi) * LDSDW + oct * 4;
                *(half8*)((char*)lds + (size_t)base * 4) = hv;
                *(half8*)((char*)lds + ((size_t)PLT + base) * 4) = lv;
            }
        } else {
            // d2 path (full-res): 6 rows x 50 xi x 4 octets
            for (int e = tid; e < 6 * 50 * 4; e += BS) {
                int xi = e % 50;
                int rest = e / 50;
                int oct = rest & 3;
                int row = rest >> 2;
                int iy = y0 - 1 + row, gx = x0 - 1 + xi;
                half8 hv = {}, lv = {};
                if (iy >= 0 && iy < Ho && gx >= 0 && gx < Wo) {
                    size_t ga = ((size_t)((n * 8 + (chunk - 4) * 4 + oct) * Ho + iy) * Wo + gx) * 8;
                    hv = *(const half8*)(d2h + ga);
                    lv = *(const half8*)(d2l + ga);
                }
                int base = (row * 50 + xi) * LDSDW + oct * 4;
                *(half8*)((char*)lds + (size_t)base * 4) = hv;
                *(half8*)((char*)lds + ((size_t)PLT + base) * 4) = lv;
            }
        }
        __syncthreads();
#pragma unroll
        for (int ky = 0; ky < 3; ++ky) {
#pragma unroll
            for (int kx = 0; kx < 3; ++kx) {
                int tap = ky * 3 + kx;
                const _Float16* bpp = bp + ((size_t)(chunk * 9 + tap) * 4) * 64 * 8;
                half8 bh[4], bl[4];
#pragma unroll
                for (int nt = 0; nt < 4; ++nt) {
                    bh[nt] = *(const half8*)(bpp + ((size_t)nt * 64 + lane) * 8);
                    bl[nt] = *(const half8*)(bpp + 110592 + ((size_t)nt * 64 + lane) * 8);
                }
                int row;
                if (chunk < 4) row = ((yr + ky - 1) >> 1) - hh0;
                else           row = wv + ky;
#pragma unroll
                for (int mt = 0; mt < 3; ++mt) {
                    int px = 16 * mt + m;
                    int xi = (chunk < 4) ? (((x0 + px + kx - 1) >> 1) - hx0)
                                         : (px + kx);
                    int adw = (row * 50 + xi) * LDSDW + q * 4;
                    half8 ah = *(const half8*)((const char*)lds + (size_t)adw * 4);
                    half8 al = *(const half8*)((const char*)lds + ((size_t)PLT + adw) * 4);
#pragma unroll
                    for (int nt = 0; nt < 4; ++nt) {
                        acc[mt][nt] = __builtin_amdgcn_mfma_f32_16x16x32_f16(ah, bh[nt], acc[mt][nt], 0, 0, 0);
                        acc[mt][nt] = __builtin_amdgcn_mfma_f32_16x16x32_f16(ah, bl[nt], acc[mt][nt], 0, 0, 0);
                        acc[mt][nt] = __builtin_amdgcn_mfma_f32_16x16x32_f16(al, bh[nt], acc[mt][nt], 0, 0, 0);
                    }
                }
            }
        }
    }

    // epilogue: 2 halves of 32 co; buffer [32 co][192 px]; split-only output
#pragma unroll
    for (int h = 0; h < 2; ++h) {
        __syncthreads();
#pragma unroll
        for (int ntl = 0; ntl < 2; ++ntl) {
#pragma unroll
            for (int mt = 0; mt < 3; ++mt) {
#pragma unroll
                for (int r = 0; r < 4; ++r) {
                    ((float*)lds)[(ntl * 16 + m) * 192 + wv * 48 + 16 * mt + q * 4 + r]
                        = acc[mt][h * 2 + ntl][r];
                }
            }
        }
        __syncthreads();
        for (int it = tid; it < 4 * 192; it += BS) {
            int px = it % 192;
            int ol = it / 192;                        // oct_local 0..3
            int row = y0 + px / 48, xx = x0 + px % 48;
            half8 hv, lv;
#pragma unroll
            for (int j = 0; j < 8; ++j) {
                int col = ol * 8 + j;
                float v = fmaxf(((float*)lds)[col * 192 + px] + b_u1[h * 32 + col], 0.f);
                _Float16 hh = (_Float16)v;
                hv[j] = hh;
                lv[j] = (_Float16)(v - (float)hh);
            }
            size_t oaddr = ((size_t)((n * 8 + h * 4 + ol) * Ho + row) * Wo + xx) * 8;
            *(half8*)(oh + oaddr) = hv;
            *(half8*)(ol_ + oaddr) = lv;
        }
    }
}

// ===========================================================================
// seg via fused MFMA u2+seg, 4 rows x 48 px @384; shfl_xor co-reduce.
// R16: inputs pre-split (u1sp, d1sp); staging is a pure copy.
// ===========================================================================
__global__ __launch_bounds__(BS) void u2seg_mfma_kernel(
    const _Float16* __restrict__ u1h, const _Float16* __restrict__ u1l,  // [8,8,192,192,8]
    const _Float16* __restrict__ d1h, const _Float16* __restrict__ d1l,  // [8,4,384,384,8]
    const _Float16* __restrict__ bp,
    const float* __restrict__ b_u2,  // [32]
    const float* __restrict__ w_seg, // [32]
    const float* __restrict__ b_seg, // [1]
    float* __restrict__ seg)         // [8,1,384,384]
{
    __shared__ unsigned int lds[2 * PLT];
    const int Ho = 384, Wo = 384;
    int b = blockIdx.x;
    int xb = b % 8; b /= 8;                           // 384/48 = 8 x-tiles
    int yb = b % 96;
    int n  = b / 96;
    int y0 = yb * 4;
    int x0 = xb * 48;

    int tid = threadIdx.x;
    int lane = tid & 63, wv = tid >> 6;
    int m = lane & 15, q = lane >> 4;
    int yr = y0 + wv;

    floatx4 acc[3][2];
#pragma unroll
    for (int mt = 0; mt < 3; ++mt) {
        acc[mt][0] = (floatx4){0.f, 0.f, 0.f, 0.f};
        acc[mt][1] = (floatx4){0.f, 0.f, 0.f, 0.f};
    }

    const int hh0 = (y0 - 1) >> 1;
    const int hx0 = (x0 - 1) >> 1;

    for (int chunk = 0; chunk < 3; ++chunk) {
        __syncthreads();
        if (chunk < 2) {
            // u1 path (half-res): 4 rows x 26 xi x 4 octets
            for (int e = tid; e < 4 * 26 * 4; e += BS) {
                int xi = e % 26;
                int rest = e / 26;
                int oct = rest & 3;
                int row = rest >> 2;
                int hy = hh0 + row, hx = hx0 + xi;
                half8 hv = {}, lv = {};
                if (hy >= 0 && hy < 192 && hx >= 0 && hx < 192) {
                    size_t ga = ((size_t)((n * 8 + chunk * 4 + oct) * 192 + hy) * 192 + hx) * 8;
                    hv = *(const half8*)(u1h + ga);
                    lv = *(const half8*)(u1l + ga);
                }
                int base = (row * 50 + xi) * LDSDW + oct * 4;
                *(half8*)((char*)lds + (size_t)base * 4) = hv;
                *(half8*)((char*)lds + ((size_t)PLT + base) * 4) = lv;
            }
        } else {
            // d1 path (full-res): 6 rows x 50 xi x 4 octets
            for (int e = tid; e < 6 * 50 * 4; e += BS) {
                int xi = e % 50;
                int rest = e / 50;
                int oct = rest & 3;
                int row = rest >> 2;
                int iy = y0 - 1 + row, gx = x0 - 1 + xi;
                half8 hv = {}, lv = {};
                if (iy >= 0 && iy < Ho && gx >= 0 && gx < Wo) {
                    size_t ga = ((size_t)((n * 4 + oct) * Ho + iy) * Wo + gx) * 8;
                    hv = *(const half8*)(d1h + ga);
                    lv = *(const half8*)(d1l + ga);
                }
                int base = (row * 50 + xi) * LDSDW + oct * 4;
                *(half8*)((char*)lds + (size_t)base * 4) = hv;
                *(half8*)((char*)lds + ((size_t)PLT + base) * 4) = lv;
            }
        }
        __syncthreads();
#pragma unroll
        for (int ky = 0; ky < 3; ++ky) {
#pragma unroll
            for (int kx = 0; kx < 3; ++kx) {
                int tap = ky * 3 + kx;
                const _Float16* bpp = bp + ((size_t)(chunk * 9 + tap) * 2) * 64 * 8;
                half8 bh0 = *(const half8*)(bpp + (size_t)lane * 8);
                half8 bl0 = *(const half8*)(bpp + 27648 + (size_t)lane * 8);
                half8 bh1 = *(const half8*)(bpp + ((size_t)64 + lane) * 8);
                half8 bl1 = *(const half8*)(bpp + 27648 + ((size_t)64 + lane) * 8);
                int row;
                if (chunk < 2) row = ((yr + ky - 1) >> 1) - hh0;
                else           row = wv + ky;
#pragma unroll
                for (int mt = 0; mt < 3; ++mt) {
                    int px = 16 * mt + m;
                    int xi = (chunk < 2) ? (((x0 + px + kx - 1) >> 1) - hx0)
                                         : (px + kx);
                    int adw = (row * 50 + xi) * LDSDW + q * 4;
                    half8 ah = *(const half8*)((const char*)lds + (size_t)adw * 4);
                    half8 al = *(const half8*)((const char*)lds + ((size_t)PLT + adw) * 4);
                    acc[mt][0] = __builtin_amdgcn_mfma_f32_16x16x32_f16(ah, bh0, acc[mt][0], 0, 0, 0);
                    acc[mt][0] = __builtin_amdgcn_mfma_f32_16x16x32_f16(ah, bl0, acc[mt][0], 0, 0, 0);
                    acc[mt][0] = __builtin_amdgcn_mfma_f32_16x16x32_f16(al, bh0, acc[mt][0], 0, 0, 0);
                    acc[mt][1] = __builtin_amdgcn_mfma_f32_16x16x32_f16(ah, bh1, acc[mt][1], 0, 0, 0);
                    acc[mt][1] = __builtin_amdgcn_mfma_f32_16x16x32_f16(ah, bl1, acc[mt][1], 0, 0, 0);
                    acc[mt][1] = __builtin_amdgcn_mfma_f32_16x16x32_f16(al, bh1, acc[mt][1], 0, 0, 0);
                }
            }
        }
    }

    float bb0 = b_u2[m], bb1 = b_u2[16 + m];
    float ws0 = w_seg[m], ws1 = w_seg[16 + m];
    float bseg = b_seg[0];
#pragma unroll
    for (int mt = 0; mt < 3; ++mt) {
        float sr[4];
#pragma unroll
        for (int r = 0; r < 4; ++r) {
            float p = ws0 * fmaxf(acc[mt][0][r] + bb0, 0.f)
                    + ws1 * fmaxf(acc[mt][1][r] + bb1, 0.f);
            p += __shfl_xor(p, 1);
            p += __shfl_xor(p, 2);
            p += __shfl_xor(p, 4);
            p += __shfl_xor(p, 8);
            sr[r] = p + bseg;
        }
        if (m == 0) {
            float4 o; o.x = sr[0]; o.y = sr[1]; o.z = sr[2]; o.w = sr[3];
            *(float4*)(seg + ((size_t)n * Ho + yr) * Wo + x0 + 16 * mt + q * 4) = o;
        }
    }
}

// ===========================================================================
// Vector kernels. conv3x3_x8 gains a SPLIT output mode (step 7: d1').
// ===========================================================================

template <int UPA, int TCO, int SPLIT>
__global__ __launch_bounds__(BS, 2) void conv3x3_x8_kernel(
    const float* __restrict__ inA, int Ca,
    const float* __restrict__ inB, int Cb,
    const float* __restrict__ w, const float* __restrict__ b,
    float* __restrict__ out,
    int N, int H, int W, int Cout, int do_relu,
    _Float16* __restrict__ osph, _Float16* __restrict__ ospl)
{
    const int W8 = W >> 3;
    int idx = blockIdx.x * BS + threadIdx.x;
    int total = N * H * W8;
    if (idx >= total) return;
    int x8 = idx % W8;
    int t  = idx / W8;
    int y  = t % H;
    int n  = t / H;
    int x0 = x8 << 3;
    const int co0 = blockIdx.y * TCO;
    const bool left_ok  = (x0 > 0);
    const bool right_ok = (x0 + 8 < W);
    const int Cin = Ca + Cb;

    float acc[TCO][8];
#pragma unroll
    for (int j = 0; j < TCO; ++j) {
        float bv = b[co0 + j];
#pragma unroll
        for (int p = 0; p < 8; ++p) acc[j][p] = bv;
    }

    for (int ci = 0; ci < Cin; ++ci) {
        float v[3][10];
#pragma unroll
        for (int ky = 0; ky < 3; ++ky) {
            int iy = y + ky - 1;
            if (iy < 0 || iy >= H) {
#pragma unroll
                for (int p = 0; p < 10; ++p) v[ky][p] = 0.f;
                continue;
            }
            if (UPA == 2 && ci < Ca) {
                const float* r = inA + ((size_t)(n * Ca + ci) * (H >> 1) + (iy >> 1)) * (W >> 1);
                int xh = x0 >> 1;
                float sm = left_ok  ? r[xh - 1] : 0.f;
                float4 qq = *(const float4*)(r + xh);
                float s4 = right_ok ? r[xh + 4] : 0.f;
                v[ky][0] = sm;
                v[ky][1] = qq.x; v[ky][2] = qq.x;
                v[ky][3] = qq.y; v[ky][4] = qq.y;
                v[ky][5] = qq.z; v[ky][6] = qq.z;
                v[ky][7] = qq.w; v[ky][8] = qq.w;
                v[ky][9] = s4;
            } else {
                const float* r = (ci < Ca)
                    ? inA + ((size_t)(n * Ca + ci) * H + iy) * W
                    : inB + ((size_t)(n * Cb + (ci - Ca)) * H + iy) * W;
                v[ky][0] = left_ok ? r[x0 - 1] : 0.f;
                float4 q0 = *(const float4*)(r + x0);
                float4 q1 = *(const float4*)(r + x0 + 4);
                v[ky][1] = q0.x; v[ky][2] = q0.y; v[ky][3] = q0.z; v[ky][4] = q0.w;
                v[ky][5] = q1.x; v[ky][6] = q1.y; v[ky][7] = q1.z; v[ky][8] = q1.w;
                v[ky][9] = right_ok ? r[x0 + 8] : 0.f;
            }
        }
#pragma unroll
        for (int j = 0; j < TCO; ++j) {
            const float* wp = w + ((size_t)(co0 + j) * Cin + ci) * 9;
#pragma unroll
            for (int ky = 0; ky < 3; ++ky) {
                float w0 = wp[ky * 3 + 0], w1 = wp[ky * 3 + 1], w2 = wp[ky * 3 + 2];
#pragma unroll
                for (int p = 0; p < 8; ++p)
                    acc[j][p] += w0 * v[ky][p] + w1 * v[ky][p + 1] + w2 * v[ky][p + 2];
            }
        }
    }

    if (SPLIT) {
        // TCO == 8, co0 % 8 == 0: thread owns one output octet for 8 px.
#pragma unroll
        for (int p = 0; p < 8; ++p) {
            half8 hv, lv;
#pragma unroll
            for (int j = 0; j < 8; ++j) {
                float v = acc[j][p];
                if (do_relu) v = fmaxf(v, 0.f);
                _Float16 hh = (_Float16)v;
                hv[j] = hh;
                lv[j] = (_Float16)(v - (float)hh);
            }
            size_t oaddr = ((size_t)((n * (Cout >> 3) + (co0 >> 3)) * H + y) * W + x0 + p) * 8;
            *(half8*)(osph + oaddr) = hv;
            *(half8*)(ospl + oaddr) = lv;
        }
    } else {
#pragma unroll
        for (int j = 0; j < TCO; ++j) {
#pragma unroll
            for (int p = 0; p < 8; ++p)
                if (do_relu) acc[j][p] = fmaxf(acc[j][p], 0.f);
            float* o = out + ((size_t)(n * Cout + co0 + j) * H + y) * W + x0;
            float4 q0; q0.x = acc[j][0]; q0.y = acc[j][1]; q0.z = acc[j][2]; q0.w = acc[j][3];
            float4 q1; q1.x = acc[j][4]; q1.y = acc[j][5]; q1.z = acc[j][6]; q1.w = acc[j][7];
            *(float4*)o = q0;
            *(float4*)(o + 4) = q1;
        }
    }
}

template <int TCO>
__global__ __launch_bounds__(BS) void conv3x3_s2_co_kernel(
    const float* __restrict__ inA, int Ca,
    const float* __restrict__ inB, int Cb,
    const float* __restrict__ w, const float* __restrict__ b,
    float* __restrict__ out,
    int N, int Hi, int Wi, int Cout, int do_relu)
{
    const int Ho = Hi >> 1, Wo = Wi >> 1, Woq = Wo >> 2;
    int idx = blockIdx.x * BS + threadIdx.x;
    int total = N * Ho * Woq;
    if (idx >= total) return;
    int q  = idx % Woq;
    int t  = idx / Woq;
    int oy = t % Ho;
    int n  = t / Ho;
    int ox0 = q << 2;
    int ix0 = ox0 << 1;
    const int co0 = blockIdx.y * TCO;
    const bool right_ok = (ix0 + 8 < Wi);
    const int Cin = Ca + Cb;

    float acc[TCO][4];
#pragma unroll
    for (int j = 0; j < TCO; ++j) {
        float bv = b[co0 + j];
        acc[j][0] = bv; acc[j][1] = bv; acc[j][2] = bv; acc[j][3] = bv;
    }

    for (int ci = 0; ci < Cin; ++ci) {
        const float* base = (ci < Ca)
            ? inA + (size_t)(n * Ca + ci) * Hi * Wi
            : inB + (size_t)(n * Cb + (ci - Ca)) * Hi * Wi;
        float v[3][9];
#pragma unroll
        for (int ky = 0; ky < 3; ++ky) {
            int iy = 2 * oy + ky;
            if (iy >= Hi) {
#pragma unroll
                for (int p = 0; p < 9; ++p) v[ky][p] = 0.f;
                continue;
            }
            const float* r = base + (size_t)iy * Wi + ix0;
            float4 a = *(const float4*)r;
            float4 c = *(const float4*)(r + 4);
            v[ky][0] = a.x; v[ky][1] = a.y; v[ky][2] = a.z; v[ky][3] = a.w;
            v[ky][4] = c.x; v[ky][5] = c.y; v[ky][6] = c.z; v[ky][7] = c.w;
            v[ky][8] = right_ok ? r[8] : 0.f;
        }
#pragma unroll
        for (int j = 0; j < TCO; ++j) {
            const float* wp = w + ((size_t)(co0 + j) * Cin + ci) * 9;
#pragma unroll
            for (int ky = 0; ky < 3; ++ky) {
                float w0 = wp[ky * 3 + 0], w1 = wp[ky * 3 + 1], w2 = wp[ky * 3 + 2];
#pragma unroll
                for (int p = 0; p < 4; ++p)
                    acc[j][p] += w0 * v[ky][2 * p] + w1 * v[ky][2 * p + 1] + w2 * v[ky][2 * p + 2];
            }
        }
    }

#pragma unroll
    for (int j = 0; j < TCO; ++j) {
        float4 o;
        o.x = acc[j][0]; o.y = acc[j][1]; o.z = acc[j][2]; o.w = acc[j][3];
        if (do_relu) {
            o.x = fmaxf(o.x, 0.f); o.y = fmaxf(o.y, 0.f);
            o.z = fmaxf(o.z, 0.f); o.w = fmaxf(o.w, 0.f);
        }
        *(float4*)(out + ((size_t)(n * Cout + co0 + j) * Ho + oy) * Wo + ox0) = o;
    }
}

__global__ __launch_bounds__(BS) void maxpool2_kernel(
    const float* __restrict__ in, float* __restrict__ out, int NC, int H, int W)
{
    int Ho = H >> 1, Wo = W >> 1, Woq = Wo >> 2;
    int idx = blockIdx.x * BS + threadIdx.x;
    int total = NC * Ho * Woq;
    if (idx >= total) return;
    int x4 = idx % Woq;
    int t  = idx / Woq;
    int y  = t % Ho;
    int c  = t / Ho;
    const float* r0 = in + ((size_t)c * H + 2 * y) * W + 8 * x4;
    const float* r1 = r0 + W;
    float4 a0 = *(const float4*)r0;
    float4 a1 = *(const float4*)(r0 + 4);
    float4 b0 = *(const float4*)r1;
    float4 b1 = *(const float4*)(r1 + 4);
    float4 o;
    o.x = fmaxf(fmaxf(a0.x, a0.y), fmaxf(b0.x, b0.y));
    o.y = fmaxf(fmaxf(a0.z, a0.w), fmaxf(b0.z, b0.w));
    o.z = fmaxf(fmaxf(a1.x, a1.y), fmaxf(b1.x, b1.y));
    o.w = fmaxf(fmaxf(a1.z, a1.w), fmaxf(b1.z, b1.w));
    *(float4*)(out + ((size_t)c * Ho + y) * Wo + 4 * x4) = o;
}

__global__ __launch_bounds__(BS) void peaks_kernel(
    const float* __restrict__ hm, float* __restrict__ out,
    int NC, int H, int W, float thresh)
{
    int idx = blockIdx.x * BS + threadIdx.x;
    int total = NC * H * W;
    if (idx >= total) return;
    int x = idx % W;
    int t = idx / W;
    int y = t % H;
    int c = t / H;
    float r = 0.f;
    if (x >= 1 && x < W - 1 && y >= 1 && y < H - 1) {
        const float* base = hm + (size_t)c * H * W;
        float cv = base[y * W + x];
        if (cv > thresh &&
            cv >= base[(y - 1) * W + x] &&
            cv >= base[(y + 1) * W + x] &&
            cv >= base[y * W + (x - 1)] &&
            cv >= base[y * W + (x + 1)])
            r = 1.f;
    }
    out[idx] = r;
}

static inline int nblk(long n) { return (int)((n + BS - 1) / BS); }

extern "C" void kernel_launch(void* const* d_in, const int* in_sizes, int n_in,
                              void* d_out, int out_size, void* d_ws, size_t ws_size,
                              hipStream_t stream)
{
    const float* x     = (const float*)d_in[0];
    const float* w_d1  = (const float*)d_in[1];  const float* b_d1  = (const float*)d_in[2];
    const float* w_d2  = (const float*)d_in[3];  const float* b_d2  = (const float*)d_in[4];
    const float* w_bn  = (const float*)d_in[5];  const float* b_bn  = (const float*)d_in[6];
    const float* w_u1  = (const float*)d_in[7];  const float* b_u1  = (const float*)d_in[8];
    const float* w_u2  = (const float*)d_in[9];  const float* b_u2  = (const float*)d_in[10];
    const float* w_seg = (const float*)d_in[11]; const float* b_seg = (const float*)d_in[12];
    const float* w_p1  = (const float*)d_in[13]; const float* b_p1  = (const float*)d_in[14];
    const float* w_p2  = (const float*)d_in[15]; const float* b_p2  = (const float*)d_in[16];
    const float* w_hm  = (const float*)d_in[17]; const float* b_hm  = (const float*)d_in[18];
    const float* w_paf = (const float*)d_in[19]; const float* b_paf = (const float*)d_in[20];

    const int N = 8, H = 384, W = 384;
    const int H2 = 192, W2 = 192, H4 = 96, W4 = 96;

    float* ws = (float*)d_ws;
    // Lifetime map in header comment. All offsets in floats.
    float* d1   = ws + 18874368;                       // fp32, s1->s2
    float* pd1  = ws;                                  // s2->s3
    float* d2f  = ws + 9437184;                        // fp32 for maxpool, s3->s4
    _Float16* d2sp_h = (_Float16*)(ws + 28311552);     // s3->s6
    _Float16* d2sp_l = (_Float16*)(ws + 37748736);
    float* pd2  = ws + 47185920;                       // s4->s5
    _Float16* bnsp_h = (_Float16*)(ws + 18874368);     // s5->s6
    _Float16* bnsp_l = (_Float16*)(ws + 23592960);
    _Float16* u1sp_h = (_Float16*)(ws);                // s6->s8
    _Float16* u1sp_l = (_Float16*)(ws + 9437184);
    _Float16* d1sp_h = (_Float16*)(ws + 18874368);     // s7->s8
    _Float16* d1sp_l = (_Float16*)(ws + 37748736);
    float* p1   = ws;                                  // s9->s10
    float* p2   = ws + 18874368;                       // s10->s12

    float* out_seg   = (float*)d_out;                 // 1179648
    float* out_hm    = out_seg + 1179648;             // 1253376
    float* out_paf   = out_hm + 1253376;              // 2359296
    float* out_peaks = out_paf + 2359296;             // 1253376
    // packed weights in the peaks region [4792320, 6045696), all consumed
    // before step 13 overwrites them. 16B-aligned.
    _Float16* bp_u1  = (_Float16*)(out_seg + 4792320); // 110592 fl
    _Float16* bp_u2  = (_Float16*)(out_seg + 4902912); // 27648 fl
    _Float16* bp_d2  = (_Float16*)(out_seg + 4930560); // 18432 fl
    _Float16* bp_bn  = (_Float16*)(out_seg + 4948992); // 73728 fl
    _Float16* bp_p2  = (_Float16*)(out_seg + 5022720); // 73728 fl
    _Float16* bp_hm  = (_Float16*)(out_seg + 5096448); // 4096 fl
    _Float16* bp_paf = (_Float16*)(out_seg + 5100544); // 4096 fl -> ends 5104640

    // 0. pack weights
    packw_gen_kernel<<<nblk(13824), BS, 0, stream>>>(w_u1, bp_u1, 192, 64);
    packw_gen_kernel<<<nblk(3456),  BS, 0, stream>>>(w_u2, bp_u2, 96, 32);
    packw_gen_kernel<<<nblk(2304),  BS, 0, stream>>>(w_d2, bp_d2, 32, 64);
    packw_gen_kernel<<<nblk(9216),  BS, 0, stream>>>(w_bn, bp_bn, 64, 128);
    packw_gen_kernel<<<nblk(9216),  BS, 0, stream>>>(w_p2, bp_p2, 64, 128);
    packw_1x1_kernel<<<nblk(512),   BS, 0, stream>>>(w_hm, bp_hm, 128, 2, 17);
    packw_1x1_kernel<<<nblk(512),   BS, 0, stream>>>(w_paf, bp_paf, 128, 2, 32);
    // 1. d1 = relu(conv3x3(x; 3->32)) @384  [fp32, feeds maxpool]
    {
        dim3 g(nblk((long)N * H * (W / 8)), 32 / 8);
        conv3x3_x8_kernel<1, 8, 0><<<g, BS, 0, stream>>>(
            x, 3, nullptr, 0, w_d1, b_d1, d1, N, H, W, 32, 1, nullptr, nullptr);
    }
    // 2. pd1 = maxpool(d1) @192
    maxpool2_kernel<<<nblk((long)N * 32 * H2 * (W2 / 4)), BS, 0, stream>>>(d1, pd1, N * 32, H, W);
    // 3. d2 = relu(conv3x3(pd1; 32->64)) @192  [MFMA; fp32 + split out]
    conv3x3_mfma_kernel<1, 4, 192, 192, 2><<<8 * 96 * 6, BS, 0, stream>>>(
        pd1, bp_d2, b_d2, d2f, d2sp_h, d2sp_l);
    // 4. pd2 = maxpool(d2) @96
    maxpool2_kernel<<<nblk((long)N * 64 * H4 * (W4 / 4)), BS, 0, stream>>>(d2f, pd2, N * 64, H2, W2);
    // 5. bn = relu(conv3x3(pd2; 64->128)) @96  [MFMA; split-only out]
    conv3x3_mfma_kernel<2, 8, 96, 96, 1><<<8 * 48 * 3, BS, 0, stream>>>(
        pd2, bp_bn, b_bn, nullptr, bnsp_h, bnsp_l);
    // 6. u1 = relu(conv3x3(concat(up2(bn), d2); 192->64)) @192  [MFMA 4x48, split I/O]
    u1_mfma_kernel<<<8 * 48 * 4, BS, 0, stream>>>(
        bnsp_h, bnsp_l, d2sp_h, d2sp_l, bp_u1, b_u1, u1sp_h, u1sp_l);
    // 7. d1' = relu(conv3x3(x; 3->32)) @384  (recompute, split-only out)
    {
        dim3 g(nblk((long)N * H * (W / 8)), 32 / 8);
        conv3x3_x8_kernel<1, 8, 1><<<g, BS, 0, stream>>>(
            x, 3, nullptr, 0, w_d1, b_d1, nullptr, N, H, W, 32, 1, d1sp_h, d1sp_l);
    }
    // 8. seg via fused MFMA u2+seg @384  [MFMA 4x48, split inputs]
    u2seg_mfma_kernel<<<8 * 96 * 8, BS, 0, stream>>>(
        u1sp_h, u1sp_l, d1sp_h, d1sp_l, bp_u2, b_u2, w_seg, b_seg, out_seg);
    // 9. p1 = relu(conv3x3_s2(concat(x, seg); 4->64)) @384->192  [vector]
    {
        dim3 g(nblk((long)N * H2 * (W2 / 4)), 64 / 8);
        conv3x3_s2_co_kernel<8><<<g, BS, 0, stream>>>(
            x, 3, out_seg, 1, w_p1, b_p1, p1, N, H, W, 64, 1);
    }
    // 10. p2 = relu(conv3x3_s2(p1; 64->128)) @192->96  [MFMA s2]
    conv3x3s2_mfma_kernel<2, 8, 192><<<8 * 48 * 3, BS, 0, stream>>>(
        p1, bp_p2, b_p2, p2);
    // 11. hm = conv1x1(p2; 128->17) @96  [MFMA 1x1]
    conv1x1_mfma_kernel<4, 2><<<8 * 144, BS, 0, stream>>>(
        p2, bp_hm, b_hm, out_hm, 17, H4 * W4);
    // 12. paf = conv1x1(p2; 128->32) @96  [MFMA 1x1]
    conv1x1_mfma_kernel<4, 2><<<8 * 144, BS, 0, stream>>>(
        p2, bp_paf, b_paf, out_paf, 32, H4 * W4);
    // 13. peaks @96  (overwrites packed-weight region - already consumed)
    peaks_kernel<<<nblk((long)N * 17 * H4 * W4), BS, 0, stream>>>(
        out_hm, out_peaks, N * 17, H4, W4, 0.1f);
}

// Round 4
// 965.018 us; speedup vs baseline: 1.4108x; 1.0184x over previous
//
#include <hip/hip_runtime.h>

// ---------------------------------------------------------------------------
// TeacherModel: small U-Net + pose heads. B=8, H=W=384, fp32 NCHW.
// Round 17: u1/u2seg retiled 4x48 -> 8 rows x 48 px (512-thread blocks).
//  Waves/CU 12 -> 16 (2 blocks x 8 waves, LDS 80,000 B x 2 = 160 KB/CU) and
//  halo ratio 1.5625 -> 1.302 (17% less staging). Epilogue buffer stride
//  384 -> 388 dw (16-way bank conflict fix). Arithmetic bit-identical.
// R16: producer-side f16 hi/lo split ([C/8][H][W][8] planes).
// Workspace lifetime map (floats, 56,623,104 total):
//  d1 fp32   [18.9M..56.6M) live s1->s2
//  pd1       [0..9.4M)      live s2->s3
//  d2 fp32   [9.4M..28.3M)  live s3->s4
//  d2sp h/l  [28.3M..47.2M) live s3->s6
//  pd2       [47.2M..51.9M) live s4->s5
//  bnsp h/l  [18.9M..28.3M) live s5->s6
//  u1sp h/l  [0..18.9M)     live s6->s8
//  d1sp h/l  [18.9M..56.6M) live s7->s8
//  p1        [0..18.9M)     live s9->s10
//  p2        [18.9M..28.3M) live s10->s12
// ---------------------------------------------------------------------------

#define BS 256
#define BSW 512     // 8-wave blocks for the 8-row kernels

typedef _Float16 half8 __attribute__((ext_vector_type(8)));
typedef float floatx4 __attribute__((ext_vector_type(4)));

#define LDSDW 20    // dwords per x position
#define PLT8 10000  // 10*50*LDSDW dwords per plane (8-row x 48-px kernels)
#define ESTR 388    // u1 epilogue buffer stride (dw): 384+4, breaks mod-32

// ===========================================================================
// Generic 3x3 weight pre-pack: [plane(hi/lo)][chunk][tap(9)][nt][lane][8]
// ===========================================================================
__global__ __launch_bounds__(BS) void packw_gen_kernel(
    const float* __restrict__ w, _Float16* __restrict__ bp, int Cin, int Cout)
{
    int total = (Cin >> 5) * 9 * (Cout >> 4) * 64;
    int tid = blockIdx.x * BS + threadIdx.x;
    if (tid >= total) return;
    int lane = tid & 63;
    int t = tid >> 6;
    int NTl = Cout >> 4;
    int nt = t % NTl; t /= NTl;
    int tap = t % 9;
    int chunk = t / 9;
    int q = lane >> 4, n = lane & 15;
    int co = nt * 16 + n;
    _Float16* ph = bp + (size_t)tid * 8;
    _Float16* pl = bp + (size_t)total * 8 + (size_t)tid * 8;
#pragma unroll
    for (int j = 0; j < 8; ++j) {
        int ci = chunk * 32 + q * 8 + j;
        float v = w[((size_t)co * Cin + ci) * 9 + tap];
        _Float16 h = (_Float16)v;
        ph[j] = h;
        pl[j] = (_Float16)(v - (float)h);
    }
}

// 1x1 weight pre-pack: [plane][chunk][nt][lane][8]; co >= Cout -> 0.
__global__ __launch_bounds__(BS) void packw_1x1_kernel(
    const float* __restrict__ w, _Float16* __restrict__ bp, int Cin, int NTl, int Cout)
{
    int total = (Cin >> 5) * NTl * 64;
    int tid = blockIdx.x * BS + threadIdx.x;
    if (tid >= total) return;
    int lane = tid & 63;
    int t = tid >> 6;
    int nt = t % NTl;
    int chunk = t / NTl;
    int q = lane >> 4, n = lane & 15;
    int co = nt * 16 + n;
    _Float16* ph = bp + (size_t)tid * 8;
    _Float16* pl = bp + (size_t)total * 8 + (size_t)tid * 8;
#pragma unroll
    for (int j = 0; j < 8; ++j) {
        int ci = chunk * 32 + q * 8 + j;
        float v = (co < Cout) ? w[(size_t)co * Cin + ci] : 0.f;
        _Float16 h = (_Float16)v;
        ph[j] = h;
        pl[j] = (_Float16)(v - (float)h);
    }
}

// ===========================================================================
// Generic stride-1 3x3 SAME conv via MFMA: block = 2 rows x 32 px.
// OUTMODE: 0 = fp32 only, 1 = split only, 2 = both.
// Split layout: [C/8][H][W][8] per plane (hi, lo), relu applied.
// ===========================================================================
template <int CHUNKS, int NT, int HH, int WW, int OUTMODE>
__global__ __launch_bounds__(BS) void conv3x3_mfma_kernel(
    const float* __restrict__ in_,
    const _Float16* __restrict__ bp,
    const float* __restrict__ bias,
    float* __restrict__ out,
    _Float16* __restrict__ osph,
    _Float16* __restrict__ ospl)
{
    constexpr int PL = 4 * 34 * LDSDW;
    constexpr int EPI = 64 * NT * 16;
    constexpr int LDS_DW = (2 * PL > EPI) ? 2 * PL : EPI;
    __shared__ unsigned int lds[LDS_DW];

    int xblks = WW / 32;
    int b = blockIdx.x;
    int xb = b % xblks; b /= xblks;
    int yp = b % (HH / 2);
    int n  = b / (HH / 2);
    int y0 = yp * 2;
    int x0 = xb * 32;

    int tid = threadIdx.x;
    int lane = tid & 63, wv = tid >> 6;
    int m = lane & 15, q = lane >> 4;
    int lrow = wv >> 1;
    int lx   = (wv & 1) * 16;

    floatx4 acc[NT];
#pragma unroll
    for (int nt = 0; nt < NT; ++nt) acc[nt] = (floatx4){0.f, 0.f, 0.f, 0.f};

    const int planeW = CHUNKS * 9 * NT * 64 * 8;

    for (int chunk = 0; chunk < CHUNKS; ++chunk) {
        __syncthreads();
        for (int e = tid; e < 4 * 34 * 4; e += BS) {
            int xi = e % 34;
            int rest = e / 34;
            int oct = rest & 3;
            int row = rest >> 2;
            int iy = y0 - 1 + row, gx = x0 - 1 + xi;
            bool ok = (iy >= 0 && iy < HH && gx >= 0 && gx < WW);
            const float* gp = in_ +
                ((size_t)(n * (CHUNKS * 32) + chunk * 32 + oct * 8) * HH + iy) * WW + gx;
            half8 hv, lv;
#pragma unroll
            for (int j = 0; j < 8; ++j) {
                float v = ok ? gp[(size_t)j * HH * WW] : 0.f;
                _Float16 h = (_Float16)v;
                hv[j] = h;
                lv[j] = (_Float16)(v - (float)h);
            }
            int base = (row * 34 + xi) * LDSDW + oct * 4;
            *(half8*)((char*)lds + (size_t)base * 4) = hv;
            *(half8*)((char*)lds + ((size_t)PL + base) * 4) = lv;
        }
        __syncthreads();
#pragma unroll
        for (int ky = 0; ky < 3; ++ky) {
#pragma unroll
            for (int kx = 0; kx < 3; ++kx) {
                int row = lrow + ky;
                int xi  = lx + m + kx;
                int adw = (row * 34 + xi) * LDSDW + q * 4;
                half8 ah = *(const half8*)((const char*)lds + (size_t)adw * 4);
                half8 al = *(const half8*)((const char*)lds + ((size_t)PL + adw) * 4);
                int tap = ky * 3 + kx;
                const _Float16* bpp = bp + ((size_t)(chunk * 9 + tap) * NT) * 64 * 8;
#pragma unroll
                for (int nt = 0; nt < NT; ++nt) {
                    half8 bh = *(const half8*)(bpp + ((size_t)nt * 64 + lane) * 8);
                    half8 bl = *(const half8*)(bpp + planeW + ((size_t)nt * 64 + lane) * 8);
                    acc[nt] = __builtin_amdgcn_mfma_f32_16x16x32_f16(ah, bh, acc[nt], 0, 0, 0);
                    acc[nt] = __builtin_amdgcn_mfma_f32_16x16x32_f16(ah, bl, acc[nt], 0, 0, 0);
                    acc[nt] = __builtin_amdgcn_mfma_f32_16x16x32_f16(al, bh, acc[nt], 0, 0, 0);
                }
            }
        }
    }

    __syncthreads();
#pragma unroll
    for (int nt = 0; nt < NT; ++nt) {
#pragma unroll
        for (int r = 0; r < 4; ++r) {
            int co = nt * 16 + m;
            int pxl = wv * 16 + q * 4 + r;
            ((float*)lds)[co * 64 + pxl] = acc[nt][r];
        }
    }
    __syncthreads();
    if (OUTMODE != 1) {
        constexpr int thPerCo = 256 / (NT * 16);
        constexpr int pxPerTh = 64 / thPerCo;
        int co = tid / thPerCo;
        int sub = tid % thPerCo;
        int pxb = sub * pxPerTh;
        float bb = bias[co];
#pragma unroll
        for (int u = 0; u < pxPerTh; u += 4) {
            int p = pxb + u;
            int row = y0 + (p >> 5), xx = x0 + (p & 31);
            const float* lp = (const float*)lds + co * 64 + p;
            float4 vv = *(const float4*)lp;
            vv.x = fmaxf(vv.x + bb, 0.f);
            vv.y = fmaxf(vv.y + bb, 0.f);
            vv.z = fmaxf(vv.z + bb, 0.f);
            vv.w = fmaxf(vv.w + bb, 0.f);
            *(float4*)(out + ((size_t)(n * NT * 16 + co) * HH + row) * WW + xx) = vv;
        }
    }
    if (OUTMODE >= 1) {
        constexpr int OCTS = NT * 2;
        for (int it = tid; it < OCTS * 64; it += BS) {
            int px = it & 63;
            int oct = it >> 6;
            int row = y0 + (px >> 5), xx = x0 + (px & 31);
            half8 hv, lv;
#pragma unroll
            for (int j = 0; j < 8; ++j) {
                float v = fmaxf(((float*)lds)[(oct * 8 + j) * 64 + px] + bias[oct * 8 + j], 0.f);
                _Float16 hh = (_Float16)v;
                hv[j] = hh;
                lv[j] = (_Float16)(v - (float)hh);
            }
            size_t oaddr = ((size_t)((n * OCTS + oct) * HH + row) * WW + xx) * 8;
            *(half8*)(osph + oaddr) = hv;
            *(half8*)(ospl + oaddr) = lv;
        }
    }
}

// ===========================================================================
// Stride-2 3x3 conv (pad_lo=0, pad_hi=1) via MFMA: block = 2 out-rows x 32 px.
// ===========================================================================
template <int CHUNKS, int NT, int WI>
__global__ __launch_bounds__(BS) void conv3x3s2_mfma_kernel(
    const float* __restrict__ in_,   // [8, CHUNKS*32, WI, WI]
    const _Float16* __restrict__ bp,
    const float* __restrict__ bias,  // [NT*16]
    float* __restrict__ out)         // [8, NT*16, WI/2, WI/2]
{
    constexpr int WO = WI / 2;
    constexpr int PLs = 5 * 68 * LDSDW;               // 6800 dw per plane
    constexpr int EPI = 64 * NT * 16;
    constexpr int LDS_DW = (2 * PLs > EPI) ? 2 * PLs : EPI;
    __shared__ unsigned int lds[LDS_DW];

    int xblks = WO / 32;
    int b = blockIdx.x;
    int xb = b % xblks; b /= xblks;
    int yp = b % (WO / 2);
    int n  = b / (WO / 2);
    int y0 = yp * 2;                                  // output rows y0, y0+1
    int x0 = xb * 32;

    int tid = threadIdx.x;
    int lane = tid & 63, wv = tid >> 6;
    int m = lane & 15, q = lane >> 4;
    int lrow = wv >> 1;
    int lx   = (wv & 1) * 16;

    floatx4 acc[NT];
#pragma unroll
    for (int nt = 0; nt < NT; ++nt) acc[nt] = (floatx4){0.f, 0.f, 0.f, 0.f};

    const int planeW = CHUNKS * 9 * NT * 64 * 8;

    for (int chunk = 0; chunk < CHUNKS; ++chunk) {
        __syncthreads();
        // stage 5 input rows x 65 xi (pad 68) x 4 octets; swizzled x position
        for (int e = tid; e < 5 * 68 * 4; e += BS) {
            int xi = e % 68;
            int rest = e / 68;
            int oct = rest & 3;
            int row = rest >> 2;                      // 0..4
            int iy = 2 * y0 + row, ix = 2 * x0 + xi;  // pad_lo = 0
            bool ok = (xi < 65 && iy < WI && ix < WI);
            const float* gp = in_ +
                ((size_t)(n * (CHUNKS * 32) + chunk * 32 + oct * 8) * WI + iy) * WI + ix;
            half8 hv, lv;
#pragma unroll
            for (int j = 0; j < 8; ++j) {
                float v = ok ? gp[(size_t)j * WI * WI] : 0.f;
                _Float16 h = (_Float16)v;
                hv[j] = h;
                lv[j] = (_Float16)(v - (float)h);
            }
            int pos = (xi & 1) * 34 + (xi >> 1);      // parity split
            int base = (row * 68 + pos) * LDSDW + oct * 4;
            *(half8*)((char*)lds + (size_t)base * 4) = hv;
            *(half8*)((char*)lds + ((size_t)PLs + base) * 4) = lv;
        }
        __syncthreads();
#pragma unroll
        for (int ky = 0; ky < 3; ++ky) {
#pragma unroll
            for (int kx = 0; kx < 3; ++kx) {
                int row = 2 * lrow + ky;              // 0..4
                int pos = (kx & 1) * 34 + (lx + m) + (kx >> 1);
                int adw = (row * 68 + pos) * LDSDW + q * 4;
                half8 ah = *(const half8*)((const char*)lds + (size_t)adw * 4);
                half8 al = *(const half8*)((const char*)lds + ((size_t)PLs + adw) * 4);
                int tap = ky * 3 + kx;
                const _Float16* bpp = bp + ((size_t)(chunk * 9 + tap) * NT) * 64 * 8;
#pragma unroll
                for (int nt = 0; nt < NT; ++nt) {
                    half8 bh = *(const half8*)(bpp + ((size_t)nt * 64 + lane) * 8);
                    half8 bl = *(const half8*)(bpp + planeW + ((size_t)nt * 64 + lane) * 8);
                    acc[nt] = __builtin_amdgcn_mfma_f32_16x16x32_f16(ah, bh, acc[nt], 0, 0, 0);
                    acc[nt] = __builtin_amdgcn_mfma_f32_16x16x32_f16(ah, bl, acc[nt], 0, 0, 0);
                    acc[nt] = __builtin_amdgcn_mfma_f32_16x16x32_f16(al, bh, acc[nt], 0, 0, 0);
                }
            }
        }
    }

    __syncthreads();
#pragma unroll
    for (int nt = 0; nt < NT; ++nt) {
#pragma unroll
        for (int r = 0; r < 4; ++r) {
            int co = nt * 16 + m;
            int pxl = wv * 16 + q * 4 + r;
            ((float*)lds)[co * 64 + pxl] = acc[nt][r];
        }
    }
    __syncthreads();
    {
        constexpr int thPerCo = 256 / (NT * 16);
        constexpr int pxPerTh = 64 / thPerCo;
        int co = tid / thPerCo;
        int sub = tid % thPerCo;
        int pxb = sub * pxPerTh;
        float bb = bias[co];
#pragma unroll
        for (int u = 0; u < pxPerTh; u += 4) {
            int p = pxb + u;
            int row = y0 + (p >> 5), xx = x0 + (p & 31);
            const float* lp = (const float*)lds + co * 64 + p;
            float4 vv = *(const float4*)lp;
            vv.x = fmaxf(vv.x + bb, 0.f);
            vv.y = fmaxf(vv.y + bb, 0.f);
            vv.z = fmaxf(vv.z + bb, 0.f);
            vv.w = fmaxf(vv.w + bb, 0.f);
            *(float4*)(out + ((size_t)(n * NT * 16 + co) * WO + row) * WO + xx) = vv;
        }
    }
}

// ===========================================================================
// 1x1 conv via MFMA GEMM: M = 64 px/block, N = NT*16 (store only co < Cout),
// K = CHUNKS*32. No relu (heads).
// ===========================================================================
template <int CHUNKS, int NT>
__global__ __launch_bounds__(BS) void conv1x1_mfma_kernel(
    const float* __restrict__ in_,   // [8, CHUNKS*32, HW]
    const _Float16* __restrict__ bp,
    const float* __restrict__ bias,  // [Cout]
    float* __restrict__ out,         // [8, Cout, HW]
    int Cout, int HW)
{
    constexpr int PL1 = 64 * LDSDW;                   // 1280 dw per plane
    constexpr int EPI = 64 * NT * 16;
    constexpr int LDS_DW = (2 * PL1 > EPI) ? 2 * PL1 : EPI;
    __shared__ unsigned int lds[LDS_DW];

    int pblks = HW / 64;
    int b = blockIdx.x;
    int pb = b % pblks;
    int n  = b / pblks;
    int sp0 = pb * 64;

    int tid = threadIdx.x;
    int lane = tid & 63, wv = tid >> 6;
    int m = lane & 15, q = lane >> 4;

    floatx4 acc[NT];
#pragma unroll
    for (int nt = 0; nt < NT; ++nt) acc[nt] = (floatx4){0.f, 0.f, 0.f, 0.f};

    const int planeW = CHUNKS * NT * 64 * 8;

    for (int chunk = 0; chunk < CHUNKS; ++chunk) {
        __syncthreads();
        // stage 64 px x 4 octets (one item per thread)
        {
            int px = tid & 63;
            int oct = tid >> 6;
            const float* gp = in_ +
                ((size_t)(n * (CHUNKS * 32) + chunk * 32 + oct * 8)) * HW + sp0 + px;
            half8 hv, lv;
#pragma unroll
            for (int j = 0; j < 8; ++j) {
                float v = gp[(size_t)j * HW];
                _Float16 h = (_Float16)v;
                hv[j] = h;
                lv[j] = (_Float16)(v - (float)h);
            }
            int base = px * LDSDW + oct * 4;
            *(half8*)((char*)lds + (size_t)base * 4) = hv;
            *(half8*)((char*)lds + ((size_t)PL1 + base) * 4) = lv;
        }
        __syncthreads();
        {
            int adw = (wv * 16 + m) * LDSDW + q * 4;
            half8 ah = *(const half8*)((const char*)lds + (size_t)adw * 4);
            half8 al = *(const half8*)((const char*)lds + ((size_t)PL1 + adw) * 4);
            const _Float16* bpp = bp + ((size_t)chunk * NT) * 64 * 8;
#pragma unroll
            for (int nt = 0; nt < NT; ++nt) {
                half8 bh = *(const half8*)(bpp + ((size_t)nt * 64 + lane) * 8);
                half8 bl = *(const half8*)(bpp + planeW + ((size_t)nt * 64 + lane) * 8);
                acc[nt] = __builtin_amdgcn_mfma_f32_16x16x32_f16(ah, bh, acc[nt], 0, 0, 0);
                acc[nt] = __builtin_amdgcn_mfma_f32_16x16x32_f16(ah, bl, acc[nt], 0, 0, 0);
                acc[nt] = __builtin_amdgcn_mfma_f32_16x16x32_f16(al, bh, acc[nt], 0, 0, 0);
            }
        }
    }

    __syncthreads();
#pragma unroll
    for (int nt = 0; nt < NT; ++nt) {
#pragma unroll
        for (int r = 0; r < 4; ++r) {
            ((float*)lds)[(nt * 16 + m) * 64 + wv * 16 + q * 4 + r] = acc[nt][r];
        }
    }
    __syncthreads();
    {
        constexpr int thPerCo = 256 / (NT * 16);      // NT=2 -> 8
        constexpr int pxPerTh = 64 / thPerCo;         // 8
        int co = tid / thPerCo;
        int g  = tid % thPerCo;
        if (co < Cout) {
            float bb = bias[co];
            const float* lp = (const float*)lds + co * 64 + g * pxPerTh;
            float* op = out + ((size_t)(n * Cout + co)) * HW + sp0 + g * pxPerTh;
#pragma unroll
            for (int u = 0; u < pxPerTh; u += 4) {
                float4 vv = *(const float4*)(lp + u);
                vv.x += bb; vv.y += bb; vv.z += bb; vv.w += bb;
                *(float4*)(op + u) = vv;
            }
        }
    }
}

// ===========================================================================
// u1 = relu(conv3x3(concat(up2(bn), d2))) via MFMA, 8 rows x 48 px @192.
// R17: 512-thread blocks, 80,000 B LDS -> 2 blocks x 8 waves = 16 waves/CU.
// Inputs pre-split; output split-only (feeds u2seg).
// ===========================================================================
__global__ __launch_bounds__(BSW) void u1_mfma_kernel(
    const _Float16* __restrict__ bnh, const _Float16* __restrict__ bnl,  // [8,16,96,96,8]
    const _Float16* __restrict__ d2h, const _Float16* __restrict__ d2l,  // [8,8,192,192,8]
    const _Float16* __restrict__ bp,
    const float* __restrict__ b_u1,  // [64]
    _Float16* __restrict__ oh, _Float16* __restrict__ ol_)               // [8,8,192,192,8]
{
    __shared__ unsigned int lds[2 * PLT8];
    const int Ho = 192, Wo = 192;
    int b = blockIdx.x;
    int xb = b % 4; b /= 4;                           // 192/48 = 4 x-tiles
    int yb = b % 24;                                  // 192/8 = 24 y-tiles
    int n  = b / 24;
    int y0 = yb * 8;
    int x0 = xb * 48;

    int tid = threadIdx.x;
    int lane = tid & 63, wv = tid >> 6;               // wv 0..7
    int m = lane & 15, q = lane >> 4;
    int yr = y0 + wv;

    floatx4 acc[3][4];
#pragma unroll
    for (int mt = 0; mt < 3; ++mt)
#pragma unroll
        for (int nt = 0; nt < 4; ++nt) acc[mt][nt] = (floatx4){0.f, 0.f, 0.f, 0.f};

    const int hh0 = (y0 - 1) >> 1;
    const int hx0 = (x0 - 1) >> 1;

    for (int chunk = 0; chunk < 6; ++chunk) {
        __syncthreads();
        if (chunk < 4) {
            // bn path (half-res): 6 rows x 26 xi x 4 octets
            for (int e = tid; e < 6 * 26 * 4; e += BSW) {
                int xi = e % 26;
                int rest = e / 26;
                int oct = rest & 3;
                int row = rest >> 2;
                int hy = hh0 + row, hx = hx0 + xi;
                half8 hv = {}, lv = {};
                if (hy >= 0 && hy < 96 && hx >= 0 && hx < 96) {
                    size_t ga = ((size_t)((n * 16 + chunk * 4 + oct) * 96 + hy) * 96 + hx) * 8;
                    hv = *(const half8*)(bnh + ga);
                    lv = *(const half8*)(bnl + ga);
                }
                int base = (row * 50 + xi) * LDSDW + oct * 4;
                *(half8*)((char*)lds + (size_t)base * 4) = hv;
                *(half8*)((char*)lds + ((size_t)PLT8 + base) * 4) = lv;
            }
        } else {
            // d2 path (full-res): 10 rows x 50 xi x 4 octets
            for (int e = tid; e < 10 * 50 * 4; e += BSW) {
                int xi = e % 50;
                int rest = e / 50;
                int oct = rest & 3;
                int row = rest >> 2;
                int iy = y0 - 1 + row, gx = x0 - 1 + xi;
                half8 hv = {}, lv = {};
                if (iy >= 0 && iy < Ho && gx >= 0 && gx < Wo) {
                    size_t ga = ((size_t)((n * 8 + (chunk - 4) * 4 + oct) * Ho + iy) * Wo + gx) * 8;
                    hv = *(const half8*)(d2h + ga);
                    lv = *(const half8*)(d2l + ga);
                }
                int base = (row * 50 + xi) * LDSDW + oct * 4;
                *(half8*)((char*)lds + (size_t)base * 4) = hv;
                *(half8*)((char*)lds + ((size_t)PLT8 + base) * 4) = lv;
            }
        }
        __syncthreads();
#pragma unroll
        for (int ky = 0; ky < 3; ++ky) {
#pragma unroll
            for (int kx = 0; kx < 3; ++kx) {
                int tap = ky * 3 + kx;
                const _Float16* bpp = bp + ((size_t)(chunk * 9 + tap) * 4) * 64 * 8;
                half8 bh[4], bl[4];
#pragma unroll
                for (int nt = 0; nt < 4; ++nt) {
                    bh[nt] = *(const half8*)(bpp + ((size_t)nt * 64 + lane) * 8);
                    bl[nt] = *(const half8*)(bpp + 110592 + ((size_t)nt * 64 + lane) * 8);
                }
                int row;
                if (chunk < 4) row = ((yr + ky - 1) >> 1) - hh0;
                else           row = wv + ky;
#pragma unroll
                for (int mt = 0; mt < 3; ++mt) {
                    int px = 16 * mt + m;
                    int xi = (chunk < 4) ? (((x0 + px + kx - 1) >> 1) - hx0)
                                         : (px + kx);
                    int adw = (row * 50 + xi) * LDSDW + q * 4;
                    half8 ah = *(const half8*)((const char*)lds + (size_t)adw * 4);
                    half8 al = *(const half8*)((const char*)lds + ((size_t)PLT8 + adw) * 4);
#pragma unroll
                    for (int nt = 0; nt < 4; ++nt) {
                        acc[mt][nt] = __builtin_amdgcn_mfma_f32_16x16x32_f16(ah, bh[nt], acc[mt][nt], 0, 0, 0);
                        acc[mt][nt] = __builtin_amdgcn_mfma_f32_16x16x32_f16(ah, bl[nt], acc[mt][nt], 0, 0, 0);
                        acc[mt][nt] = __builtin_amdgcn_mfma_f32_16x16x32_f16(al, bh[nt], acc[mt][nt], 0, 0, 0);
                    }
                }
            }
        }
    }

    // epilogue: 2 halves of 32 co; buffer [32 co][stride ESTR; 384 px used]
#pragma unroll
    for (int h = 0; h < 2; ++h) {
        __syncthreads();
#pragma unroll
        for (int ntl = 0; ntl < 2; ++ntl) {
#pragma unroll
            for (int mt = 0; mt < 3; ++mt) {
#pragma unroll
                for (int r = 0; r < 4; ++r) {
                    ((float*)lds)[(ntl * 16 + m) * ESTR + wv * 48 + 16 * mt + q * 4 + r]
                        = acc[mt][h * 2 + ntl][r];
                }
            }
        }
        __syncthreads();
        for (int it = tid; it < 4 * 384; it += BSW) {
            int px = it % 384;                        // wv*48 + local px
            int ol = it / 384;                        // oct_local 0..3
            int row = y0 + px / 48, xx = x0 + px % 48;
            half8 hv, lv;
#pragma unroll
            for (int j = 0; j < 8; ++j) {
                int col = ol * 8 + j;
                float v = fmaxf(((float*)lds)[col * ESTR + px] + b_u1[h * 32 + col], 0.f);
                _Float16 hh = (_Float16)v;
                hv[j] = hh;
                lv[j] = (_Float16)(v - (float)hh);
            }
            size_t oaddr = ((size_t)((n * 8 + h * 4 + ol) * Ho + row) * Wo + xx) * 8;
            *(half8*)(oh + oaddr) = hv;
            *(half8*)(ol_ + oaddr) = lv;
        }
    }
}

// ===========================================================================
// seg via fused MFMA u2+seg, 8 rows x 48 px @384; shfl_xor co-reduce.
// R17: 512-thread blocks, 80,000 B LDS -> 2 blocks x 8 waves = 16 waves/CU.
// ===========================================================================
__global__ __launch_bounds__(BSW) void u2seg_mfma_kernel(
    const _Float16* __restrict__ u1h, const _Float16* __restrict__ u1l,  // [8,8,192,192,8]
    const _Float16* __restrict__ d1h, const _Float16* __restrict__ d1l,  // [8,4,384,384,8]
    const _Float16* __restrict__ bp,
    const float* __restrict__ b_u2,  // [32]
    const float* __restrict__ w_seg, // [32]
    const float* __restrict__ b_seg, // [1]
    float* __restrict__ seg)         // [8,1,384,384]
{
    __shared__ unsigned int lds[2 * PLT8];
    const int Ho = 384, Wo = 384;
    int b = blockIdx.x;
    int xb = b % 8; b /= 8;                           // 384/48 = 8 x-tiles
    int yb = b % 48;                                  // 384/8 = 48 y-tiles
    int n  = b / 48;
    int y0 = yb * 8;
    int x0 = xb * 48;

    int tid = threadIdx.x;
    int lane = tid & 63, wv = tid >> 6;               // wv 0..7
    int m = lane & 15, q = lane >> 4;
    int yr = y0 + wv;

    floatx4 acc[3][2];
#pragma unroll
    for (int mt = 0; mt < 3; ++mt) {
        acc[mt][0] = (floatx4){0.f, 0.f, 0.f, 0.f};
        acc[mt][1] = (floatx4){0.f, 0.f, 0.f, 0.f};
    }

    const int hh0 = (y0 - 1) >> 1;
    const int hx0 = (x0 - 1) >> 1;

    for (int chunk = 0; chunk < 3; ++chunk) {
        __syncthreads();
        if (chunk < 2) {
            // u1 path (half-res): 6 rows x 26 xi x 4 octets
            for (int e = tid; e < 6 * 26 * 4; e += BSW) {
                int xi = e % 26;
                int rest = e / 26;
                int oct = rest & 3;
                int row = rest >> 2;
                int hy = hh0 + row, hx = hx0 + xi;
                half8 hv = {}, lv = {};
                if (hy >= 0 && hy < 192 && hx >= 0 && hx < 192) {
                    size_t ga = ((size_t)((n * 8 + chunk * 4 + oct) * 192 + hy) * 192 + hx) * 8;
                    hv = *(const half8*)(u1h + ga);
                    lv = *(const half8*)(u1l + ga);
                }
                int base = (row * 50 + xi) * LDSDW + oct * 4;
                *(half8*)((char*)lds + (size_t)base * 4) = hv;
                *(half8*)((char*)lds + ((size_t)PLT8 + base) * 4) = lv;
            }
        } else {
            // d1 path (full-res): 10 rows x 50 xi x 4 octets
            for (int e = tid; e < 10 * 50 * 4; e += BSW) {
                int xi = e % 50;
                int rest = e / 50;
                int oct = rest & 3;
                int row = rest >> 2;
                int iy = y0 - 1 + row, gx = x0 - 1 + xi;
                half8 hv = {}, lv = {};
                if (iy >= 0 && iy < Ho && gx >= 0 && gx < Wo) {
                    size_t ga = ((size_t)((n * 4 + oct) * Ho + iy) * Wo + gx) * 8;
                    hv = *(const half8*)(d1h + ga);
                    lv = *(const half8*)(d1l + ga);
                }
                int base = (row * 50 + xi) * LDSDW + oct * 4;
                *(half8*)((char*)lds + (size_t)base * 4) = hv;
                *(half8*)((char*)lds + ((size_t)PLT8 + base) * 4) = lv;
            }
        }
        __syncthreads();
#pragma unroll
        for (int ky = 0; ky < 3; ++ky) {
#pragma unroll
            for (int kx = 0; kx < 3; ++kx) {
                int tap = ky * 3 + kx;
                const _Float16* bpp = bp + ((size_t)(chunk * 9 + tap) * 2) * 64 * 8;
                half8 bh0 = *(const half8*)(bpp + (size_t)lane * 8);
                half8 bl0 = *(const half8*)(bpp + 27648 + (size_t)lane * 8);
                half8 bh1 = *(const half8*)(bpp + ((size_t)64 + lane) * 8);
                half8 bl1 = *(const half8*)(bpp + 27648 + ((size_t)64 + lane) * 8);
                int row;
                if (chunk < 2) row = ((yr + ky - 1) >> 1) - hh0;
                else           row = wv + ky;
#pragma unroll
                for (int mt = 0; mt < 3; ++mt) {
                    int px = 16 * mt + m;
                    int xi = (chunk < 2) ? (((x0 + px + kx - 1) >> 1) - hx0)
                                         : (px + kx);
                    int adw = (row * 50 + xi) * LDSDW + q * 4;
                    half8 ah = *(const half8*)((const char*)lds + (size_t)adw * 4);
                    half8 al = *(const half8*)((const char*)lds + ((size_t)PLT8 + adw) * 4);
                    acc[mt][0] = __builtin_amdgcn_mfma_f32_16x16x32_f16(ah, bh0, acc[mt][0], 0, 0, 0);
                    acc[mt][0] = __builtin_amdgcn_mfma_f32_16x16x32_f16(ah, bl0, acc[mt][0], 0, 0, 0);
                    acc[mt][0] = __builtin_amdgcn_mfma_f32_16x16x32_f16(al, bh0, acc[mt][0], 0, 0, 0);
                    acc[mt][1] = __builtin_amdgcn_mfma_f32_16x16x32_f16(ah, bh1, acc[mt][1], 0, 0, 0);
                    acc[mt][1] = __builtin_amdgcn_mfma_f32_16x16x32_f16(ah, bl1, acc[mt][1], 0, 0, 0);
                    acc[mt][1] = __builtin_amdgcn_mfma_f32_16x16x32_f16(al, bh1, acc[mt][1], 0, 0, 0);
                }
            }
        }
    }

    float bb0 = b_u2[m], bb1 = b_u2[16 + m];
    float ws0 = w_seg[m], ws1 = w_seg[16 + m];
    float bseg = b_seg[0];
#pragma unroll
    for (int mt = 0; mt < 3; ++mt) {
        float sr[4];
#pragma unroll
        for (int r = 0; r < 4; ++r) {
            float p = ws0 * fmaxf(acc[mt][0][r] + bb0, 0.f)
                    + ws1 * fmaxf(acc[mt][1][r] + bb1, 0.f);
            p += __shfl_xor(p, 1);
            p += __shfl_xor(p, 2);
            p += __shfl_xor(p, 4);
            p += __shfl_xor(p, 8);
            sr[r] = p + bseg;
        }
        if (m == 0) {
            float4 o; o.x = sr[0]; o.y = sr[1]; o.z = sr[2]; o.w = sr[3];
            *(float4*)(seg + ((size_t)n * Ho + yr) * Wo + x0 + 16 * mt + q * 4) = o;
        }
    }
}

// ===========================================================================
// Vector kernels. conv3x3_x8 has a SPLIT output mode (step 7: d1').
// ===========================================================================

template <int UPA, int TCO, int SPLIT>
__global__ __launch_bounds__(BS, 2) void conv3x3_x8_kernel(
    const float* __restrict__ inA, int Ca,
    const float* __restrict__ inB, int Cb,
    const float* __restrict__ w, const float* __restrict__ b,
    float* __restrict__ out,
    int N, int H, int W, int Cout, int do_relu,
    _Float16* __restrict__ osph, _Float16* __restrict__ ospl)
{
    const int W8 = W >> 3;
    int idx = blockIdx.x * BS + threadIdx.x;
    int total = N * H * W8;
    if (idx >= total) return;
    int x8 = idx % W8;
    int t  = idx / W8;
    int y  = t % H;
    int n  = t / H;
    int x0 = x8 << 3;
    const int co0 = blockIdx.y * TCO;
    const bool left_ok  = (x0 > 0);
    const bool right_ok = (x0 + 8 < W);
    const int Cin = Ca + Cb;

    float acc[TCO][8];
#pragma unroll
    for (int j = 0; j < TCO; ++j) {
        float bv = b[co0 + j];
#pragma unroll
        for (int p = 0; p < 8; ++p) acc[j][p] = bv;
    }

    for (int ci = 0; ci < Cin; ++ci) {
        float v[3][10];
#pragma unroll
        for (int ky = 0; ky < 3; ++ky) {
            int iy = y + ky - 1;
            if (iy < 0 || iy >= H) {
#pragma unroll
                for (int p = 0; p < 10; ++p) v[ky][p] = 0.f;
                continue;
            }
            if (UPA == 2 && ci < Ca) {
                const float* r = inA + ((size_t)(n * Ca + ci) * (H >> 1) + (iy >> 1)) * (W >> 1);
                int xh = x0 >> 1;
                float sm = left_ok  ? r[xh - 1] : 0.f;
                float4 qq = *(const float4*)(r + xh);
                float s4 = right_ok ? r[xh + 4] : 0.f;
                v[ky][0] = sm;
                v[ky][1] = qq.x; v[ky][2] = qq.x;
                v[ky][3] = qq.y; v[ky][4] = qq.y;
                v[ky][5] = qq.z; v[ky][6] = qq.z;
                v[ky][7] = qq.w; v[ky][8] = qq.w;
                v[ky][9] = s4;
            } else {
                const float* r = (ci < Ca)
                    ? inA + ((size_t)(n * Ca + ci) * H + iy) * W
                    : inB + ((size_t)(n * Cb + (ci - Ca)) * H + iy) * W;
                v[ky][0] = left_ok ? r[x0 - 1] : 0.f;
                float4 q0 = *(const float4*)(r + x0);
                float4 q1 = *(const float4*)(r + x0 + 4);
                v[ky][1] = q0.x; v[ky][2] = q0.y; v[ky][3] = q0.z; v[ky][4] = q0.w;
                v[ky][5] = q1.x; v[ky][6] = q1.y; v[ky][7] = q1.z; v[ky][8] = q1.w;
                v[ky][9] = right_ok ? r[x0 + 8] : 0.f;
            }
        }
#pragma unroll
        for (int j = 0; j < TCO; ++j) {
            const float* wp = w + ((size_t)(co0 + j) * Cin + ci) * 9;
#pragma unroll
            for (int ky = 0; ky < 3; ++ky) {
                float w0 = wp[ky * 3 + 0], w1 = wp[ky * 3 + 1], w2 = wp[ky * 3 + 2];
#pragma unroll
                for (int p = 0; p < 8; ++p)
                    acc[j][p] += w0 * v[ky][p] + w1 * v[ky][p + 1] + w2 * v[ky][p + 2];
            }
        }
    }

    if (SPLIT) {
        // TCO == 8, co0 % 8 == 0: thread owns one output octet for 8 px.
#pragma unroll
        for (int p = 0; p < 8; ++p) {
            half8 hv, lv;
#pragma unroll
            for (int j = 0; j < 8; ++j) {
                float v = acc[j][p];
                if (do_relu) v = fmaxf(v, 0.f);
                _Float16 hh = (_Float16)v;
                hv[j] = hh;
                lv[j] = (_Float16)(v - (float)hh);
            }
            size_t oaddr = ((size_t)((n * (Cout >> 3) + (co0 >> 3)) * H + y) * W + x0 + p) * 8;
            *(half8*)(osph + oaddr) = hv;
            *(half8*)(ospl + oaddr) = lv;
        }
    } else {
#pragma unroll
        for (int j = 0; j < TCO; ++j) {
#pragma unroll
            for (int p = 0; p < 8; ++p)
                if (do_relu) acc[j][p] = fmaxf(acc[j][p], 0.f);
            float* o = out + ((size_t)(n * Cout + co0 + j) * H + y) * W + x0;
            float4 q0; q0.x = acc[j][0]; q0.y = acc[j][1]; q0.z = acc[j][2]; q0.w = acc[j][3];
            float4 q1; q1.x = acc[j][4]; q1.y = acc[j][5]; q1.z = acc[j][6]; q1.w = acc[j][7];
            *(float4*)o = q0;
            *(float4*)(o + 4) = q1;
        }
    }
}

template <int TCO>
__global__ __launch_bounds__(BS) void conv3x3_s2_co_kernel(
    const float* __restrict__ inA, int Ca,
    const float* __restrict__ inB, int Cb,
    const float* __restrict__ w, const float* __restrict__ b,
    float* __restrict__ out,
    int N, int Hi, int Wi, int Cout, int do_relu)
{
    const int Ho = Hi >> 1, Wo = Wi >> 1, Woq = Wo >> 2;
    int idx = blockIdx.x * BS + threadIdx.x;
    int total = N * Ho * Woq;
    if (idx >= total) return;
    int q  = idx % Woq;
    int t  = idx / Woq;
    int oy = t % Ho;
    int n  = t / Ho;
    int ox0 = q << 2;
    int ix0 = ox0 << 1;
    const int co0 = blockIdx.y * TCO;
    const bool right_ok = (ix0 + 8 < Wi);
    const int Cin = Ca + Cb;

    float acc[TCO][4];
#pragma unroll
    for (int j = 0; j < TCO; ++j) {
        float bv = b[co0 + j];
        acc[j][0] = bv; acc[j][1] = bv; acc[j][2] = bv; acc[j][3] = bv;
    }

    for (int ci = 0; ci < Cin; ++ci) {
        const float* base = (ci < Ca)
            ? inA + (size_t)(n * Ca + ci) * Hi * Wi
            : inB + (size_t)(n * Cb + (ci - Ca)) * Hi * Wi;
        float v[3][9];
#pragma unroll
        for (int ky = 0; ky < 3; ++ky) {
            int iy = 2 * oy + ky;
            if (iy >= Hi) {
#pragma unroll
                for (int p = 0; p < 9; ++p) v[ky][p] = 0.f;
                continue;
            }
            const float* r = base + (size_t)iy * Wi + ix0;
            float4 a = *(const float4*)r;
            float4 c = *(const float4*)(r + 4);
            v[ky][0] = a.x; v[ky][1] = a.y; v[ky][2] = a.z; v[ky][3] = a.w;
            v[ky][4] = c.x; v[ky][5] = c.y; v[ky][6] = c.z; v[ky][7] = c.w;
            v[ky][8] = right_ok ? r[8] : 0.f;
        }
#pragma unroll
        for (int j = 0; j < TCO; ++j) {
            const float* wp = w + ((size_t)(co0 + j) * Cin + ci) * 9;
#pragma unroll
            for (int ky = 0; ky < 3; ++ky) {
                float w0 = wp[ky * 3 + 0], w1 = wp[ky * 3 + 1], w2 = wp[ky * 3 + 2];
#pragma unroll
                for (int p = 0; p < 4; ++p)
                    acc[j][p] += w0 * v[ky][2 * p] + w1 * v[ky][2 * p + 1] + w2 * v[ky][2 * p + 2];
            }
        }
    }

#pragma unroll
    for (int j = 0; j < TCO; ++j) {
        float4 o;
        o.x = acc[j][0]; o.y = acc[j][1]; o.z = acc[j][2]; o.w = acc[j][3];
        if (do_relu) {
            o.x = fmaxf(o.x, 0.f); o.y = fmaxf(o.y, 0.f);
            o.z = fmaxf(o.z, 0.f); o.w = fmaxf(o.w, 0.f);
        }
        *(float4*)(out + ((size_t)(n * Cout + co0 + j) * Ho + oy) * Wo + ox0) = o;
    }
}

__global__ __launch_bounds__(BS) void maxpool2_kernel(
    const float* __restrict__ in, float* __restrict__ out, int NC, int H, int W)
{
    int Ho = H >> 1, Wo = W >> 1, Woq = Wo >> 2;
    int idx = blockIdx.x * BS + threadIdx.x;
    int total = NC * Ho * Woq;
    if (idx >= total) return;
    int x4 = idx % Woq;
    int t  = idx / Woq;
    int y  = t % Ho;
    int c  = t / Ho;
    const float* r0 = in + ((size_t)c * H + 2 * y) * W + 8 * x4;
    const float* r1 = r0 + W;
    float4 a0 = *(const float4*)r0;
    float4 a1 = *(const float4*)(r0 + 4);
    float4 b0 = *(const float4*)r1;
    float4 b1 = *(const float4*)(r1 + 4);
    float4 o;
    o.x = fmaxf(fmaxf(a0.x, a0.y), fmaxf(b0.x, b0.y));
    o.y = fmaxf(fmaxf(a0.z, a0.w), fmaxf(b0.z, b0.w));
    o.z = fmaxf(fmaxf(a1.x, a1.y), fmaxf(b1.x, b1.y));
    o.w = fmaxf(fmaxf(a1.z, a1.w), fmaxf(b1.z, b1.w));
    *(float4*)(out + ((size_t)c * Ho + y) * Wo + 4 * x4) = o;
}

__global__ __launch_bounds__(BS) void peaks_kernel(
    const float* __restrict__ hm, float* __restrict__ out,
    int NC, int H, int W, float thresh)
{
    int idx = blockIdx.x * BS + threadIdx.x;
    int total = NC * H * W;
    if (idx >= total) return;
    int x = idx % W;
    int t = idx / W;
    int y = t % H;
    int c = t / H;
    float r = 0.f;
    if (x >= 1 && x < W - 1 && y >= 1 && y < H - 1) {
        const float* base = hm + (size_t)c * H * W;
        float cv = base[y * W + x];
        if (cv > thresh &&
            cv >= base[(y - 1) * W + x] &&
            cv >= base[(y + 1) * W + x] &&
            cv >= base[y * W + (x - 1)] &&
            cv >= base[y * W + (x + 1)])
            r = 1.f;
    }
    out[idx] = r;
}

static inline int nblk(long n) { return (int)((n + BS - 1) / BS); }

extern "C" void kernel_launch(void* const* d_in, const int* in_sizes, int n_in,
                              void* d_out, int out_size, void* d_ws, size_t ws_size,
                              hipStream_t stream)
{
    const float* x     = (const float*)d_in[0];
    const float* w_d1  = (const float*)d_in[1];  const float* b_d1  = (const float*)d_in[2];
    const float* w_d2  = (const float*)d_in[3];  const float* b_d2  = (const float*)d_in[4];
    const float* w_bn  = (const float*)d_in[5];  const float* b_bn  = (const float*)d_in[6];
    const float* w_u1  = (const float*)d_in[7];  const float* b_u1  = (const float*)d_in[8];
    const float* w_u2  = (const float*)d_in[9];  const float* b_u2  = (const float*)d_in[10];
    const float* w_seg = (const float*)d_in[11]; const float* b_seg = (const float*)d_in[12];
    const float* w_p1  = (const float*)d_in[13]; const float* b_p1  = (const float*)d_in[14];
    const float* w_p2  = (const float*)d_in[15]; const float* b_p2  = (const float*)d_in[16];
    const float* w_hm  = (const float*)d_in[17]; const float* b_hm  = (const float*)d_in[18];
    const float* w_paf = (const float*)d_in[19]; const float* b_paf = (const float*)d_in[20];

    const int N = 8, H = 384, W = 384;
    const int H2 = 192, W2 = 192, H4 = 96, W4 = 96;

    float* ws = (float*)d_ws;
    // Lifetime map in header comment. All offsets in floats.
    float* d1   = ws + 18874368;                       // fp32, s1->s2
    float* pd1  = ws;                                  // s2->s3
    float* d2f  = ws + 9437184;                        // fp32 for maxpool, s3->s4
    _Float16* d2sp_h = (_Float16*)(ws + 28311552);     // s3->s6
    _Float16* d2sp_l = (_Float16*)(ws + 37748736);
    float* pd2  = ws + 47185920;                       // s4->s5
    _Float16* bnsp_h = (_Float16*)(ws + 18874368);     // s5->s6
    _Float16* bnsp_l = (_Float16*)(ws + 23592960);
    _Float16* u1sp_h = (_Float16*)(ws);                // s6->s8
    _Float16* u1sp_l = (_Float16*)(ws + 9437184);
    _Float16* d1sp_h = (_Float16*)(ws + 18874368);     // s7->s8
    _Float16* d1sp_l = (_Float16*)(ws + 37748736);
    float* p1   = ws;                                  // s9->s10
    float* p2   = ws + 18874368;                       // s10->s12

    float* out_seg   = (float*)d_out;                 // 1179648
    float* out_hm    = out_seg + 1179648;             // 1253376
    float* out_paf   = out_hm + 1253376;              // 2359296
    float* out_peaks = out_paf + 2359296;             // 1253376
    // packed weights in the peaks region [4792320, 6045696), all consumed
    // before step 13 overwrites them. 16B-aligned.
    _Float16* bp_u1  = (_Float16*)(out_seg + 4792320); // 110592 fl
    _Float16* bp_u2  = (_Float16*)(out_seg + 4902912); // 27648 fl
    _Float16* bp_d2  = (_Float16*)(out_seg + 4930560); // 18432 fl
    _Float16* bp_bn  = (_Float16*)(out_seg + 4948992); // 73728 fl
    _Float16* bp_p2  = (_Float16*)(out_seg + 5022720); // 73728 fl
    _Float16* bp_hm  = (_Float16*)(out_seg + 5096448); // 4096 fl
    _Float16* bp_paf = (_Float16*)(out_seg + 5100544); // 4096 fl -> ends 5104640

    // 0. pack weights
    packw_gen_kernel<<<nblk(13824), BS, 0, stream>>>(w_u1, bp_u1, 192, 64);
    packw_gen_kernel<<<nblk(3456),  BS, 0, stream>>>(w_u2, bp_u2, 96, 32);
    packw_gen_kernel<<<nblk(2304),  BS, 0, stream>>>(w_d2, bp_d2, 32, 64);
    packw_gen_kernel<<<nblk(9216),  BS, 0, stream>>>(w_bn, bp_bn, 64, 128);
    packw_gen_kernel<<<nblk(9216),  BS, 0, stream>>>(w_p2, bp_p2, 64, 128);
    packw_1x1_kernel<<<nblk(512),   BS, 0, stream>>>(w_hm, bp_hm, 128, 2, 17);
    packw_1x1_kernel<<<nblk(512),   BS, 0, stream>>>(w_paf, bp_paf, 128, 2, 32);
    // 1. d1 = relu(conv3x3(x; 3->32)) @384  [fp32, feeds maxpool]
    {
        dim3 g(nblk((long)N * H * (W / 8)), 32 / 8);
        conv3x3_x8_kernel<1, 8, 0><<<g, BS, 0, stream>>>(
            x, 3, nullptr, 0, w_d1, b_d1, d1, N, H, W, 32, 1, nullptr, nullptr);
    }
    // 2. pd1 = maxpool(d1) @192
    maxpool2_kernel<<<nblk((long)N * 32 * H2 * (W2 / 4)), BS, 0, stream>>>(d1, pd1, N * 32, H, W);
    // 3. d2 = relu(conv3x3(pd1; 32->64)) @192  [MFMA; fp32 + split out]
    conv3x3_mfma_kernel<1, 4, 192, 192, 2><<<8 * 96 * 6, BS, 0, stream>>>(
        pd1, bp_d2, b_d2, d2f, d2sp_h, d2sp_l);
    // 4. pd2 = maxpool(d2) @96
    maxpool2_kernel<<<nblk((long)N * 64 * H4 * (W4 / 4)), BS, 0, stream>>>(d2f, pd2, N * 64, H2, W2);
    // 5. bn = relu(conv3x3(pd2; 64->128)) @96  [MFMA; split-only out]
    conv3x3_mfma_kernel<2, 8, 96, 96, 1><<<8 * 48 * 3, BS, 0, stream>>>(
        pd2, bp_bn, b_bn, nullptr, bnsp_h, bnsp_l);
    // 6. u1 = relu(conv3x3(concat(up2(bn), d2); 192->64)) @192  [MFMA 8x48, 512th]
    u1_mfma_kernel<<<8 * 24 * 4, BSW, 0, stream>>>(
        bnsp_h, bnsp_l, d2sp_h, d2sp_l, bp_u1, b_u1, u1sp_h, u1sp_l);
    // 7. d1' = relu(conv3x3(x; 3->32)) @384  (recompute, split-only out)
    {
        dim3 g(nblk((long)N * H * (W / 8)), 32 / 8);
        conv3x3_x8_kernel<1, 8, 1><<<g, BS, 0, stream>>>(
            x, 3, nullptr, 0, w_d1, b_d1, nullptr, N, H, W, 32, 1, d1sp_h, d1sp_l);
    }
    // 8. seg via fused MFMA u2+seg @384  [MFMA 8x48, 512th]
    u2seg_mfma_kernel<<<8 * 48 * 8, BSW, 0, stream>>>(
        u1sp_h, u1sp_l, d1sp_h, d1sp_l, bp_u2, b_u2, w_seg, b_seg, out_seg);
    // 9. p1 = relu(conv3x3_s2(concat(x, seg); 4->64)) @384->192  [vector]
    {
        dim3 g(nblk((long)N * H2 * (W2 / 4)), 64 / 8);
        conv3x3_s2_co_kernel<8><<<g, BS, 0, stream>>>(
            x, 3, out_seg, 1, w_p1, b_p1, p1, N, H, W, 64, 1);
    }
    // 10. p2 = relu(conv3x3_s2(p1; 64->128)) @192->96  [MFMA s2]
    conv3x3s2_mfma_kernel<2, 8, 192><<<8 * 48 * 3, BS, 0, stream>>>(
        p1, bp_p2, b_p2, p2);
    // 11. hm = conv1x1(p2; 128->17) @96  [MFMA 1x1]
    conv1x1_mfma_kernel<4, 2><<<8 * 144, BS, 0, stream>>>(
        p2, bp_hm, b_hm, out_hm, 17, H4 * W4);
    // 12. paf = conv1x1(p2; 128->32) @96  [MFMA 1x1]
    conv1x1_mfma_kernel<4, 2><<<8 * 144, BS, 0, stream>>>(
        p2, bp_paf, b_paf, out_paf, 32, H4 * W4);
    // 13. peaks @96  (overwrites packed-weight region - already consumed)
    peaks_kernel<<<nblk((long)N * 17 * H4 * W4), BS, 0, stream>>>(
        out_hm, out_peaks, N * 17, H4, W4, 0.1f);
}

// Round 5
// 962.948 us; speedup vs baseline: 1.4139x; 1.0021x over previous
//
#include <hip/hip_runtime.h>

// ---------------------------------------------------------------------------
// TeacherModel: small U-Net + pose heads. B=8, H=W=384, fp32 NCHW.
// Round 18: producer-side f16 hi/lo split rolled out to the whole pipeline.
//  maxpool emits split planes (pd1sp/pd2sp); p1 emits split; d2/bn/p2/hm/paf
//  consume split with pure-copy staging (no cvt VALU, half the fetch).
//  All splits computed from the identical fp32 values -> bit-identical.
// R17: u1/u2seg at 8 rows x 48 px (512-thread blocks).
// R16: split-plane layout [C/8][H][W][8] (hi, lo).
// Workspace lifetime map (floats, 56,623,104 total):
//  d1 fp32    [18.9M..56.6M) s1->s2
//  pd1sp h/l  [0..4.7M)+[4.7M..9.4M)       s2->s3
//  d2f fp32   [9.4M..28.3M)                s3->s4
//  d2sp h/l   [28.3M..37.7M)+[37.7M..47.2M) s3->s6
//  pd2sp h/l  [47.2M..49.5M)+[49.5M..51.9M) s4->s5
//  bnsp h/l   [18.9M..23.6M)+[23.6M..28.3M) s5->s6
//  u1sp h/l   [0..9.4M)+[9.4M..18.9M)      s6->s8
//  d1sp h/l   [18.9M..37.7M)+[37.7M..56.6M) s7->s8
//  p1sp h/l   [0..9.4M)+[9.4M..18.9M)      s9->s10
//  p2sp h/l   [18.9M..23.6M)+[23.6M..28.3M) s10->s12
// ---------------------------------------------------------------------------

#define BS 256
#define BSW 512     // 8-wave blocks for the 8-row kernels

typedef _Float16 half8 __attribute__((ext_vector_type(8)));
typedef float floatx4 __attribute__((ext_vector_type(4)));

#define LDSDW 20    // dwords per x position
#define PLT8 10000  // 10*50*LDSDW dwords per plane (8-row x 48-px kernels)
#define ESTR 388    // u1 epilogue buffer stride (dw)

// ===========================================================================
// Weight pre-pack kernels (unchanged).
// ===========================================================================
__global__ __launch_bounds__(BS) void packw_gen_kernel(
    const float* __restrict__ w, _Float16* __restrict__ bp, int Cin, int Cout)
{
    int total = (Cin >> 5) * 9 * (Cout >> 4) * 64;
    int tid = blockIdx.x * BS + threadIdx.x;
    if (tid >= total) return;
    int lane = tid & 63;
    int t = tid >> 6;
    int NTl = Cout >> 4;
    int nt = t % NTl; t /= NTl;
    int tap = t % 9;
    int chunk = t / 9;
    int q = lane >> 4, n = lane & 15;
    int co = nt * 16 + n;
    _Float16* ph = bp + (size_t)tid * 8;
    _Float16* pl = bp + (size_t)total * 8 + (size_t)tid * 8;
#pragma unroll
    for (int j = 0; j < 8; ++j) {
        int ci = chunk * 32 + q * 8 + j;
        float v = w[((size_t)co * Cin + ci) * 9 + tap];
        _Float16 h = (_Float16)v;
        ph[j] = h;
        pl[j] = (_Float16)(v - (float)h);
    }
}

__global__ __launch_bounds__(BS) void packw_1x1_kernel(
    const float* __restrict__ w, _Float16* __restrict__ bp, int Cin, int NTl, int Cout)
{
    int total = (Cin >> 5) * NTl * 64;
    int tid = blockIdx.x * BS + threadIdx.x;
    if (tid >= total) return;
    int lane = tid & 63;
    int t = tid >> 6;
    int nt = t % NTl;
    int chunk = t / NTl;
    int q = lane >> 4, n = lane & 15;
    int co = nt * 16 + n;
    _Float16* ph = bp + (size_t)tid * 8;
    _Float16* pl = bp + (size_t)total * 8 + (size_t)tid * 8;
#pragma unroll
    for (int j = 0; j < 8; ++j) {
        int ci = chunk * 32 + q * 8 + j;
        float v = (co < Cout) ? w[(size_t)co * Cin + ci] : 0.f;
        _Float16 h = (_Float16)v;
        ph[j] = h;
        pl[j] = (_Float16)(v - (float)h);
    }
}

// ===========================================================================
// maxpool 2x2 with split output: fp32 in [N*C][H][W] -> hi/lo [N][C/8][Ho][Wo][8]
// ===========================================================================
__global__ __launch_bounds__(BS) void maxpool2_split_kernel(
    const float* __restrict__ in, _Float16* __restrict__ oh, _Float16* __restrict__ ol,
    int N, int Coct, int H, int W)
{
    int Ho = H >> 1, Wo = W >> 1, Woq = Wo >> 2;
    int idx = blockIdx.x * BS + threadIdx.x;
    int total = N * Coct * Ho * Woq;
    if (idx >= total) return;
    int x4 = idx % Woq;
    int t  = idx / Woq;
    int y  = t % Ho; t /= Ho;
    int oct = t % Coct;
    int n  = t / Coct;
    int C = Coct * 8;
    float m[8][4];
#pragma unroll
    for (int j = 0; j < 8; ++j) {
        const float* r0 = in + ((size_t)((n * C + oct * 8 + j) * H + 2 * y)) * W + 8 * x4;
        const float* r1 = r0 + W;
        float4 a0 = *(const float4*)r0;
        float4 a1 = *(const float4*)(r0 + 4);
        float4 b0 = *(const float4*)r1;
        float4 b1 = *(const float4*)(r1 + 4);
        m[j][0] = fmaxf(fmaxf(a0.x, a0.y), fmaxf(b0.x, b0.y));
        m[j][1] = fmaxf(fmaxf(a0.z, a0.w), fmaxf(b0.z, b0.w));
        m[j][2] = fmaxf(fmaxf(a1.x, a1.y), fmaxf(b1.x, b1.y));
        m[j][3] = fmaxf(fmaxf(a1.z, a1.w), fmaxf(b1.z, b1.w));
    }
#pragma unroll
    for (int p = 0; p < 4; ++p) {
        half8 hv, lv;
#pragma unroll
        for (int j = 0; j < 8; ++j) {
            float v = m[j][p];
            _Float16 h = (_Float16)v;
            hv[j] = h;
            lv[j] = (_Float16)(v - (float)h);
        }
        size_t oa = ((size_t)((n * Coct + oct) * Ho + y) * Wo + 4 * x4 + p) * 8;
        *(half8*)(oh + oa) = hv;
        *(half8*)(ol + oa) = lv;
    }
}

// ===========================================================================
// Generic stride-1 3x3 SAME conv via MFMA, SPLIT input: block = 2 rows x 32 px.
// OUTMODE: 0 = fp32 only, 1 = split only, 2 = both.
// ===========================================================================
template <int CHUNKS, int NT, int HH, int WW, int OUTMODE>
__global__ __launch_bounds__(BS) void conv3x3s_mfma_kernel(
    const _Float16* __restrict__ inh, const _Float16* __restrict__ inl,
    const _Float16* __restrict__ bp,
    const float* __restrict__ bias,
    float* __restrict__ out,
    _Float16* __restrict__ osph,
    _Float16* __restrict__ ospl)
{
    constexpr int PL = 4 * 34 * LDSDW;
    constexpr int EPI = 64 * NT * 16;
    constexpr int LDS_DW = (2 * PL > EPI) ? 2 * PL : EPI;
    __shared__ unsigned int lds[LDS_DW];

    int xblks = WW / 32;
    int b = blockIdx.x;
    int xb = b % xblks; b /= xblks;
    int yp = b % (HH / 2);
    int n  = b / (HH / 2);
    int y0 = yp * 2;
    int x0 = xb * 32;

    int tid = threadIdx.x;
    int lane = tid & 63, wv = tid >> 6;
    int m = lane & 15, q = lane >> 4;
    int lrow = wv >> 1;
    int lx   = (wv & 1) * 16;

    floatx4 acc[NT];
#pragma unroll
    for (int nt = 0; nt < NT; ++nt) acc[nt] = (floatx4){0.f, 0.f, 0.f, 0.f};

    const int planeW = CHUNKS * 9 * NT * 64 * 8;

    for (int chunk = 0; chunk < CHUNKS; ++chunk) {
        __syncthreads();
        for (int e = tid; e < 4 * 34 * 4; e += BS) {
            int xi = e % 34;
            int rest = e / 34;
            int oct = rest & 3;
            int row = rest >> 2;
            int iy = y0 - 1 + row, gx = x0 - 1 + xi;
            half8 hv = {}, lv = {};
            if (iy >= 0 && iy < HH && gx >= 0 && gx < WW) {
                size_t ga = ((size_t)((n * (CHUNKS * 4) + chunk * 4 + oct) * HH + iy) * WW + gx) * 8;
                hv = *(const half8*)(inh + ga);
                lv = *(const half8*)(inl + ga);
            }
            int base = (row * 34 + xi) * LDSDW + oct * 4;
            *(half8*)((char*)lds + (size_t)base * 4) = hv;
            *(half8*)((char*)lds + ((size_t)PL + base) * 4) = lv;
        }
        __syncthreads();
#pragma unroll
        for (int ky = 0; ky < 3; ++ky) {
#pragma unroll
            for (int kx = 0; kx < 3; ++kx) {
                int row = lrow + ky;
                int xi  = lx + m + kx;
                int adw = (row * 34 + xi) * LDSDW + q * 4;
                half8 ah = *(const half8*)((const char*)lds + (size_t)adw * 4);
                half8 al = *(const half8*)((const char*)lds + ((size_t)PL + adw) * 4);
                int tap = ky * 3 + kx;
                const _Float16* bpp = bp + ((size_t)(chunk * 9 + tap) * NT) * 64 * 8;
#pragma unroll
                for (int nt = 0; nt < NT; ++nt) {
                    half8 bh = *(const half8*)(bpp + ((size_t)nt * 64 + lane) * 8);
                    half8 bl = *(const half8*)(bpp + planeW + ((size_t)nt * 64 + lane) * 8);
                    acc[nt] = __builtin_amdgcn_mfma_f32_16x16x32_f16(ah, bh, acc[nt], 0, 0, 0);
                    acc[nt] = __builtin_amdgcn_mfma_f32_16x16x32_f16(ah, bl, acc[nt], 0, 0, 0);
                    acc[nt] = __builtin_amdgcn_mfma_f32_16x16x32_f16(al, bh, acc[nt], 0, 0, 0);
                }
            }
        }
    }

    __syncthreads();
#pragma unroll
    for (int nt = 0; nt < NT; ++nt) {
#pragma unroll
        for (int r = 0; r < 4; ++r) {
            int co = nt * 16 + m;
            int pxl = wv * 16 + q * 4 + r;
            ((float*)lds)[co * 64 + pxl] = acc[nt][r];
        }
    }
    __syncthreads();
    if (OUTMODE != 1) {
        constexpr int thPerCo = 256 / (NT * 16);
        constexpr int pxPerTh = 64 / thPerCo;
        int co = tid / thPerCo;
        int sub = tid % thPerCo;
        int pxb = sub * pxPerTh;
        float bb = bias[co];
#pragma unroll
        for (int u = 0; u < pxPerTh; u += 4) {
            int p = pxb + u;
            int row = y0 + (p >> 5), xx = x0 + (p & 31);
            const float* lp = (const float*)lds + co * 64 + p;
            float4 vv = *(const float4*)lp;
            vv.x = fmaxf(vv.x + bb, 0.f);
            vv.y = fmaxf(vv.y + bb, 0.f);
            vv.z = fmaxf(vv.z + bb, 0.f);
            vv.w = fmaxf(vv.w + bb, 0.f);
            *(float4*)(out + ((size_t)(n * NT * 16 + co) * HH + row) * WW + xx) = vv;
        }
    }
    if (OUTMODE >= 1) {
        constexpr int OCTS = NT * 2;
        for (int it = tid; it < OCTS * 64; it += BS) {
            int px = it & 63;
            int oct = it >> 6;
            int row = y0 + (px >> 5), xx = x0 + (px & 31);
            half8 hv, lv;
#pragma unroll
            for (int j = 0; j < 8; ++j) {
                float v = fmaxf(((float*)lds)[(oct * 8 + j) * 64 + px] + bias[oct * 8 + j], 0.f);
                _Float16 hh = (_Float16)v;
                hv[j] = hh;
                lv[j] = (_Float16)(v - (float)hh);
            }
            size_t oaddr = ((size_t)((n * OCTS + oct) * HH + row) * WW + xx) * 8;
            *(half8*)(osph + oaddr) = hv;
            *(half8*)(ospl + oaddr) = lv;
        }
    }
}

// ===========================================================================
// Stride-2 3x3 conv (pad_lo=0, pad_hi=1) via MFMA, SPLIT input + SPLIT output.
// block = 2 out-rows x 32 px; parity-split xi swizzle.
// ===========================================================================
template <int CHUNKS, int NT, int WI>
__global__ __launch_bounds__(BS) void conv3x3s2s_mfma_kernel(
    const _Float16* __restrict__ inh, const _Float16* __restrict__ inl,
    const _Float16* __restrict__ bp,
    const float* __restrict__ bias,  // [NT*16]
    _Float16* __restrict__ oh, _Float16* __restrict__ ol_)  // [8, NT*2, WO, WO, 8]
{
    constexpr int WO = WI / 2;
    constexpr int PLs = 5 * 68 * LDSDW;               // 6800 dw per plane
    constexpr int EPI = 64 * NT * 16;
    constexpr int LDS_DW = (2 * PLs > EPI) ? 2 * PLs : EPI;
    __shared__ unsigned int lds[LDS_DW];

    int xblks = WO / 32;
    int b = blockIdx.x;
    int xb = b % xblks; b /= xblks;
    int yp = b % (WO / 2);
    int n  = b / (WO / 2);
    int y0 = yp * 2;
    int x0 = xb * 32;

    int tid = threadIdx.x;
    int lane = tid & 63, wv = tid >> 6;
    int m = lane & 15, q = lane >> 4;
    int lrow = wv >> 1;
    int lx   = (wv & 1) * 16;

    floatx4 acc[NT];
#pragma unroll
    for (int nt = 0; nt < NT; ++nt) acc[nt] = (floatx4){0.f, 0.f, 0.f, 0.f};

    const int planeW = CHUNKS * 9 * NT * 64 * 8;

    for (int chunk = 0; chunk < CHUNKS; ++chunk) {
        __syncthreads();
        for (int e = tid; e < 5 * 68 * 4; e += BS) {
            int xi = e % 68;
            int rest = e / 68;
            int oct = rest & 3;
            int row = rest >> 2;                      // 0..4
            int iy = 2 * y0 + row, ix = 2 * x0 + xi;  // pad_lo = 0
            half8 hv = {}, lv = {};
            if (xi < 65 && iy < WI && ix < WI) {
                size_t ga = ((size_t)((n * (CHUNKS * 4) + chunk * 4 + oct) * WI + iy) * WI + ix) * 8;
                hv = *(const half8*)(inh + ga);
                lv = *(const half8*)(inl + ga);
            }
            int pos = (xi & 1) * 34 + (xi >> 1);      // parity split
            int base = (row * 68 + pos) * LDSDW + oct * 4;
            *(half8*)((char*)lds + (size_t)base * 4) = hv;
            *(half8*)((char*)lds + ((size_t)PLs + base) * 4) = lv;
        }
        __syncthreads();
#pragma unroll
        for (int ky = 0; ky < 3; ++ky) {
#pragma unroll
            for (int kx = 0; kx < 3; ++kx) {
                int row = 2 * lrow + ky;              // 0..4
                int pos = (kx & 1) * 34 + (lx + m) + (kx >> 1);
                int adw = (row * 68 + pos) * LDSDW + q * 4;
                half8 ah = *(const half8*)((const char*)lds + (size_t)adw * 4);
                half8 al = *(const half8*)((const char*)lds + ((size_t)PLs + adw) * 4);
                int tap = ky * 3 + kx;
                const _Float16* bpp = bp + ((size_t)(chunk * 9 + tap) * NT) * 64 * 8;
#pragma unroll
                for (int nt = 0; nt < NT; ++nt) {
                    half8 bh = *(const half8*)(bpp + ((size_t)nt * 64 + lane) * 8);
                    half8 bl = *(const half8*)(bpp + planeW + ((size_t)nt * 64 + lane) * 8);
                    acc[nt] = __builtin_amdgcn_mfma_f32_16x16x32_f16(ah, bh, acc[nt], 0, 0, 0);
                    acc[nt] = __builtin_amdgcn_mfma_f32_16x16x32_f16(ah, bl, acc[nt], 0, 0, 0);
                    acc[nt] = __builtin_amdgcn_mfma_f32_16x16x32_f16(al, bh, acc[nt], 0, 0, 0);
                }
            }
        }
    }

    __syncthreads();
#pragma unroll
    for (int nt = 0; nt < NT; ++nt) {
#pragma unroll
        for (int r = 0; r < 4; ++r) {
            int co = nt * 16 + m;
            int pxl = wv * 16 + q * 4 + r;
            ((float*)lds)[co * 64 + pxl] = acc[nt][r];
        }
    }
    __syncthreads();
    {
        constexpr int OCTS = NT * 2;
        for (int it = tid; it < OCTS * 64; it += BS) {
            int px = it & 63;
            int oct = it >> 6;
            int row = y0 + (px >> 5), xx = x0 + (px & 31);
            half8 hv, lv;
#pragma unroll
            for (int j = 0; j < 8; ++j) {
                float v = fmaxf(((float*)lds)[(oct * 8 + j) * 64 + px] + bias[oct * 8 + j], 0.f);
                _Float16 hh = (_Float16)v;
                hv[j] = hh;
                lv[j] = (_Float16)(v - (float)hh);
            }
            size_t oaddr = ((size_t)((n * OCTS + oct) * WO + row) * WO + xx) * 8;
            *(half8*)(oh + oaddr) = hv;
            *(half8*)(ol_ + oaddr) = lv;
        }
    }
}

// ===========================================================================
// 1x1 conv via MFMA GEMM, SPLIT input: M = 64 px/block, N = NT*16,
// K = CHUNKS*32. fp32 output (heads), no relu.
// ===========================================================================
template <int CHUNKS, int NT>
__global__ __launch_bounds__(BS) void conv1x1s_mfma_kernel(
    const _Float16* __restrict__ inh, const _Float16* __restrict__ inl,  // [8, C/8, HW, 8]
    const _Float16* __restrict__ bp,
    const float* __restrict__ bias,
    float* __restrict__ out,         // [8, Cout, HW]
    int Cout, int HW)
{
    constexpr int PL1 = 64 * LDSDW;
    constexpr int EPI = 64 * NT * 16;
    constexpr int LDS_DW = (2 * PL1 > EPI) ? 2 * PL1 : EPI;
    __shared__ unsigned int lds[LDS_DW];

    int pblks = HW / 64;
    int b = blockIdx.x;
    int pb = b % pblks;
    int n  = b / pblks;
    int sp0 = pb * 64;

    int tid = threadIdx.x;
    int lane = tid & 63, wv = tid >> 6;
    int m = lane & 15, q = lane >> 4;

    floatx4 acc[NT];
#pragma unroll
    for (int nt = 0; nt < NT; ++nt) acc[nt] = (floatx4){0.f, 0.f, 0.f, 0.f};

    const int planeW = CHUNKS * NT * 64 * 8;

    for (int chunk = 0; chunk < CHUNKS; ++chunk) {
        __syncthreads();
        {
            int px = tid & 63;
            int oct = tid >> 6;
            size_t ga = (((size_t)(n * (CHUNKS * 4) + chunk * 4 + oct)) * HW + sp0 + px) * 8;
            half8 hv = *(const half8*)(inh + ga);
            half8 lv = *(const half8*)(inl + ga);
            int base = px * LDSDW + oct * 4;
            *(half8*)((char*)lds + (size_t)base * 4) = hv;
            *(half8*)((char*)lds + ((size_t)PL1 + base) * 4) = lv;
        }
        __syncthreads();
        {
            int adw = (wv * 16 + m) * LDSDW + q * 4;
            half8 ah = *(const half8*)((const char*)lds + (size_t)adw * 4);
            half8 al = *(const half8*)((const char*)lds + ((size_t)PL1 + adw) * 4);
            const _Float16* bpp = bp + ((size_t)chunk * NT) * 64 * 8;
#pragma unroll
            for (int nt = 0; nt < NT; ++nt) {
                half8 bh = *(const half8*)(bpp + ((size_t)nt * 64 + lane) * 8);
                half8 bl = *(const half8*)(bpp + planeW + ((size_t)nt * 64 + lane) * 8);
                acc[nt] = __builtin_amdgcn_mfma_f32_16x16x32_f16(ah, bh, acc[nt], 0, 0, 0);
                acc[nt] = __builtin_amdgcn_mfma_f32_16x16x32_f16(ah, bl, acc[nt], 0, 0, 0);
                acc[nt] = __builtin_amdgcn_mfma_f32_16x16x32_f16(al, bh, acc[nt], 0, 0, 0);
            }
        }
    }

    __syncthreads();
#pragma unroll
    for (int nt = 0; nt < NT; ++nt) {
#pragma unroll
        for (int r = 0; r < 4; ++r) {
            ((float*)lds)[(nt * 16 + m) * 64 + wv * 16 + q * 4 + r] = acc[nt][r];
        }
    }
    __syncthreads();
    {
        constexpr int thPerCo = 256 / (NT * 16);
        constexpr int pxPerTh = 64 / thPerCo;
        int co = tid / thPerCo;
        int g  = tid % thPerCo;
        if (co < Cout) {
            float bb = bias[co];
            const float* lp = (const float*)lds + co * 64 + g * pxPerTh;
            float* op = out + ((size_t)(n * Cout + co)) * HW + sp0 + g * pxPerTh;
#pragma unroll
            for (int u = 0; u < pxPerTh; u += 4) {
                float4 vv = *(const float4*)(lp + u);
                vv.x += bb; vv.y += bb; vv.z += bb; vv.w += bb;
                *(float4*)(op + u) = vv;
            }
        }
    }
}

// ===========================================================================
// u1 = relu(conv3x3(concat(up2(bn), d2))) via MFMA, 8 rows x 48 px @192. (R17)
// ===========================================================================
__global__ __launch_bounds__(BSW) void u1_mfma_kernel(
    const _Float16* __restrict__ bnh, const _Float16* __restrict__ bnl,  // [8,16,96,96,8]
    const _Float16* __restrict__ d2h, const _Float16* __restrict__ d2l,  // [8,8,192,192,8]
    const _Float16* __restrict__ bp,
    const float* __restrict__ b_u1,  // [64]
    _Float16* __restrict__ oh, _Float16* __restrict__ ol_)               // [8,8,192,192,8]
{
    __shared__ unsigned int lds[2 * PLT8];
    const int Ho = 192, Wo = 192;
    int b = blockIdx.x;
    int xb = b % 4; b /= 4;
    int yb = b % 24;
    int n  = b / 24;
    int y0 = yb * 8;
    int x0 = xb * 48;

    int tid = threadIdx.x;
    int lane = tid & 63, wv = tid >> 6;
    int m = lane & 15, q = lane >> 4;
    int yr = y0 + wv;

    floatx4 acc[3][4];
#pragma unroll
    for (int mt = 0; mt < 3; ++mt)
#pragma unroll
        for (int nt = 0; nt < 4; ++nt) acc[mt][nt] = (floatx4){0.f, 0.f, 0.f, 0.f};

    const int hh0 = (y0 - 1) >> 1;
    const int hx0 = (x0 - 1) >> 1;

    for (int chunk = 0; chunk < 6; ++chunk) {
        __syncthreads();
        if (chunk < 4) {
            for (int e = tid; e < 6 * 26 * 4; e += BSW) {
                int xi = e % 26;
                int rest = e / 26;
                int oct = rest & 3;
                int row = rest >> 2;
                int hy = hh0 + row, hx = hx0 + xi;
                half8 hv = {}, lv = {};
                if (hy >= 0 && hy < 96 && hx >= 0 && hx < 96) {
                    size_t ga = ((size_t)((n * 16 + chunk * 4 + oct) * 96 + hy) * 96 + hx) * 8;
                    hv = *(const half8*)(bnh + ga);
                    lv = *(const half8*)(bnl + ga);
                }
                int base = (row * 50 + xi) * LDSDW + oct * 4;
                *(half8*)((char*)lds + (size_t)base * 4) = hv;
                *(half8*)((char*)lds + ((size_t)PLT8 + base) * 4) = lv;
            }
        } else {
            for (int e = tid; e < 10 * 50 * 4; e += BSW) {
                int xi = e % 50;
                int rest = e / 50;
                int oct = rest & 3;
                int row = rest >> 2;
                int iy = y0 - 1 + row, gx = x0 - 1 + xi;
                half8 hv = {}, lv = {};
                if (iy >= 0 && iy < Ho && gx >= 0 && gx < Wo) {
                    size_t ga = ((size_t)((n * 8 + (chunk - 4) * 4 + oct) * Ho + iy) * Wo + gx) * 8;
                    hv = *(const half8*)(d2h + ga);
                    lv = *(const half8*)(d2l + ga);
                }
                int base = (row * 50 + xi) * LDSDW + oct * 4;
                *(half8*)((char*)lds + (size_t)base * 4) = hv;
                *(half8*)((char*)lds + ((size_t)PLT8 + base) * 4) = lv;
            }
        }
        __syncthreads();
#pragma unroll
        for (int ky = 0; ky < 3; ++ky) {
#pragma unroll
            for (int kx = 0; kx < 3; ++kx) {
                int tap = ky * 3 + kx;
                const _Float16* bpp = bp + ((size_t)(chunk * 9 + tap) * 4) * 64 * 8;
                half8 bh[4], bl[4];
#pragma unroll
                for (int nt = 0; nt < 4; ++nt) {
                    bh[nt] = *(const half8*)(bpp + ((size_t)nt * 64 + lane) * 8);
                    bl[nt] = *(const half8*)(bpp + 110592 + ((size_t)nt * 64 + lane) * 8);
                }
                int row;
                if (chunk < 4) row = ((yr + ky - 1) >> 1) - hh0;
                else           row = wv + ky;
#pragma unroll
                for (int mt = 0; mt < 3; ++mt) {
                    int px = 16 * mt + m;
                    int xi = (chunk < 4) ? (((x0 + px + kx - 1) >> 1) - hx0)
                                         : (px + kx);
                    int adw = (row * 50 + xi) * LDSDW + q * 4;
                    half8 ah = *(const half8*)((const char*)lds + (size_t)adw * 4);
                    half8 al = *(const half8*)((const char*)lds + ((size_t)PLT8 + adw) * 4);
#pragma unroll
                    for (int nt = 0; nt < 4; ++nt) {
                        acc[mt][nt] = __builtin_amdgcn_mfma_f32_16x16x32_f16(ah, bh[nt], acc[mt][nt], 0, 0, 0);
                        acc[mt][nt] = __builtin_amdgcn_mfma_f32_16x16x32_f16(ah, bl[nt], acc[mt][nt], 0, 0, 0);
                        acc[mt][nt] = __builtin_amdgcn_mfma_f32_16x16x32_f16(al, bh[nt], acc[mt][nt], 0, 0, 0);
                    }
                }
            }
        }
    }

#pragma unroll
    for (int h = 0; h < 2; ++h) {
        __syncthreads();
#pragma unroll
        for (int ntl = 0; ntl < 2; ++ntl) {
#pragma unroll
            for (int mt = 0; mt < 3; ++mt) {
#pragma unroll
                for (int r = 0; r < 4; ++r) {
                    ((float*)lds)[(ntl * 16 + m) * ESTR + wv * 48 + 16 * mt + q * 4 + r]
                        = acc[mt][h * 2 + ntl][r];
                }
            }
        }
        __syncthreads();
        for (int it = tid; it < 4 * 384; it += BSW) {
            int px = it % 384;
            int ol = it / 384;
            int row = y0 + px / 48, xx = x0 + px % 48;
            half8 hv, lv;
#pragma unroll
            for (int j = 0; j < 8; ++j) {
                int col = ol * 8 + j;
                float v = fmaxf(((float*)lds)[col * ESTR + px] + b_u1[h * 32 + col], 0.f);
                _Float16 hh = (_Float16)v;
                hv[j] = hh;
                lv[j] = (_Float16)(v - (float)hh);
            }
            size_t oaddr = ((size_t)((n * 8 + h * 4 + ol) * Ho + row) * Wo + xx) * 8;
            *(half8*)(oh + oaddr) = hv;
            *(half8*)(ol_ + oaddr) = lv;
        }
    }
}

// ===========================================================================
// seg via fused MFMA u2+seg, 8 rows x 48 px @384; shfl_xor co-reduce. (R17)
// ===========================================================================
__global__ __launch_bounds__(BSW) void u2seg_mfma_kernel(
    const _Float16* __restrict__ u1h, const _Float16* __restrict__ u1l,  // [8,8,192,192,8]
    const _Float16* __restrict__ d1h, const _Float16* __restrict__ d1l,  // [8,4,384,384,8]
    const _Float16* __restrict__ bp,
    const float* __restrict__ b_u2,  // [32]
    const float* __restrict__ w_seg, // [32]
    const float* __restrict__ b_seg, // [1]
    float* __restrict__ seg)         // [8,1,384,384]
{
    __shared__ unsigned int lds[2 * PLT8];
    const int Ho = 384, Wo = 384;
    int b = blockIdx.x;
    int xb = b % 8; b /= 8;
    int yb = b % 48;
    int n  = b / 48;
    int y0 = yb * 8;
    int x0 = xb * 48;

    int tid = threadIdx.x;
    int lane = tid & 63, wv = tid >> 6;
    int m = lane & 15, q = lane >> 4;
    int yr = y0 + wv;

    floatx4 acc[3][2];
#pragma unroll
    for (int mt = 0; mt < 3; ++mt) {
        acc[mt][0] = (floatx4){0.f, 0.f, 0.f, 0.f};
        acc[mt][1] = (floatx4){0.f, 0.f, 0.f, 0.f};
    }

    const int hh0 = (y0 - 1) >> 1;
    const int hx0 = (x0 - 1) >> 1;

    for (int chunk = 0; chunk < 3; ++chunk) {
        __syncthreads();
        if (chunk < 2) {
            for (int e = tid; e < 6 * 26 * 4; e += BSW) {
                int xi = e % 26;
                int rest = e / 26;
                int oct = rest & 3;
                int row = rest >> 2;
                int hy = hh0 + row, hx = hx0 + xi;
                half8 hv = {}, lv = {};
                if (hy >= 0 && hy < 192 && hx >= 0 && hx < 192) {
                    size_t ga = ((size_t)((n * 8 + chunk * 4 + oct) * 192 + hy) * 192 + hx) * 8;
                    hv = *(const half8*)(u1h + ga);
                    lv = *(const half8*)(u1l + ga);
                }
                int base = (row * 50 + xi) * LDSDW + oct * 4;
                *(half8*)((char*)lds + (size_t)base * 4) = hv;
                *(half8*)((char*)lds + ((size_t)PLT8 + base) * 4) = lv;
            }
        } else {
            for (int e = tid; e < 10 * 50 * 4; e += BSW) {
                int xi = e % 50;
                int rest = e / 50;
                int oct = rest & 3;
                int row = rest >> 2;
                int iy = y0 - 1 + row, gx = x0 - 1 + xi;
                half8 hv = {}, lv = {};
                if (iy >= 0 && iy < Ho && gx >= 0 && gx < Wo) {
                    size_t ga = ((size_t)((n * 4 + oct) * Ho + iy) * Wo + gx) * 8;
                    hv = *(const half8*)(d1h + ga);
                    lv = *(const half8*)(d1l + ga);
                }
                int base = (row * 50 + xi) * LDSDW + oct * 4;
                *(half8*)((char*)lds + (size_t)base * 4) = hv;
                *(half8*)((char*)lds + ((size_t)PLT8 + base) * 4) = lv;
            }
        }
        __syncthreads();
#pragma unroll
        for (int ky = 0; ky < 3; ++ky) {
#pragma unroll
            for (int kx = 0; kx < 3; ++kx) {
                int tap = ky * 3 + kx;
                const _Float16* bpp = bp + ((size_t)(chunk * 9 + tap) * 2) * 64 * 8;
                half8 bh0 = *(const half8*)(bpp + (size_t)lane * 8);
                half8 bl0 = *(const half8*)(bpp + 27648 + (size_t)lane * 8);
                half8 bh1 = *(const half8*)(bpp + ((size_t)64 + lane) * 8);
                half8 bl1 = *(const half8*)(bpp + 27648 + ((size_t)64 + lane) * 8);
                int row;
                if (chunk < 2) row = ((yr + ky - 1) >> 1) - hh0;
                else           row = wv + ky;
#pragma unroll
                for (int mt = 0; mt < 3; ++mt) {
                    int px = 16 * mt + m;
                    int xi = (chunk < 2) ? (((x0 + px + kx - 1) >> 1) - hx0)
                                         : (px + kx);
                    int adw = (row * 50 + xi) * LDSDW + q * 4;
                    half8 ah = *(const half8*)((const char*)lds + (size_t)adw * 4);
                    half8 al = *(const half8*)((const char*)lds + ((size_t)PLT8 + adw) * 4);
                    acc[mt][0] = __builtin_amdgcn_mfma_f32_16x16x32_f16(ah, bh0, acc[mt][0], 0, 0, 0);
                    acc[mt][0] = __builtin_amdgcn_mfma_f32_16x16x32_f16(ah, bl0, acc[mt][0], 0, 0, 0);
                    acc[mt][0] = __builtin_amdgcn_mfma_f32_16x16x32_f16(al, bh0, acc[mt][0], 0, 0, 0);
                    acc[mt][1] = __builtin_amdgcn_mfma_f32_16x16x32_f16(ah, bh1, acc[mt][1], 0, 0, 0);
                    acc[mt][1] = __builtin_amdgcn_mfma_f32_16x16x32_f16(ah, bl1, acc[mt][1], 0, 0, 0);
                    acc[mt][1] = __builtin_amdgcn_mfma_f32_16x16x32_f16(al, bh1, acc[mt][1], 0, 0, 0);
                }
            }
        }
    }

    float bb0 = b_u2[m], bb1 = b_u2[16 + m];
    float ws0 = w_seg[m], ws1 = w_seg[16 + m];
    float bseg = b_seg[0];
#pragma unroll
    for (int mt = 0; mt < 3; ++mt) {
        float sr[4];
#pragma unroll
        for (int r = 0; r < 4; ++r) {
            float p = ws0 * fmaxf(acc[mt][0][r] + bb0, 0.f)
                    + ws1 * fmaxf(acc[mt][1][r] + bb1, 0.f);
            p += __shfl_xor(p, 1);
            p += __shfl_xor(p, 2);
            p += __shfl_xor(p, 4);
            p += __shfl_xor(p, 8);
            sr[r] = p + bseg;
        }
        if (m == 0) {
            float4 o; o.x = sr[0]; o.y = sr[1]; o.z = sr[2]; o.w = sr[3];
            *(float4*)(seg + ((size_t)n * Ho + yr) * Wo + x0 + 16 * mt + q * 4) = o;
        }
    }
}

// ===========================================================================
// Vector kernels.
// ===========================================================================

template <int UPA, int TCO, int SPLIT>
__global__ __launch_bounds__(BS, 2) void conv3x3_x8_kernel(
    const float* __restrict__ inA, int Ca,
    const float* __restrict__ inB, int Cb,
    const float* __restrict__ w, const float* __restrict__ b,
    float* __restrict__ out,
    int N, int H, int W, int Cout, int do_relu,
    _Float16* __restrict__ osph, _Float16* __restrict__ ospl)
{
    const int W8 = W >> 3;
    int idx = blockIdx.x * BS + threadIdx.x;
    int total = N * H * W8;
    if (idx >= total) return;
    int x8 = idx % W8;
    int t  = idx / W8;
    int y  = t % H;
    int n  = t / H;
    int x0 = x8 << 3;
    const int co0 = blockIdx.y * TCO;
    const bool left_ok  = (x0 > 0);
    const bool right_ok = (x0 + 8 < W);
    const int Cin = Ca + Cb;

    float acc[TCO][8];
#pragma unroll
    for (int j = 0; j < TCO; ++j) {
        float bv = b[co0 + j];
#pragma unroll
        for (int p = 0; p < 8; ++p) acc[j][p] = bv;
    }

    for (int ci = 0; ci < Cin; ++ci) {
        float v[3][10];
#pragma unroll
        for (int ky = 0; ky < 3; ++ky) {
            int iy = y + ky - 1;
            if (iy < 0 || iy >= H) {
#pragma unroll
                for (int p = 0; p < 10; ++p) v[ky][p] = 0.f;
                continue;
            }
            if (UPA == 2 && ci < Ca) {
                const float* r = inA + ((size_t)(n * Ca + ci) * (H >> 1) + (iy >> 1)) * (W >> 1);
                int xh = x0 >> 1;
                float sm = left_ok  ? r[xh - 1] : 0.f;
                float4 qq = *(const float4*)(r + xh);
                float s4 = right_ok ? r[xh + 4] : 0.f;
                v[ky][0] = sm;
                v[ky][1] = qq.x; v[ky][2] = qq.x;
                v[ky][3] = qq.y; v[ky][4] = qq.y;
                v[ky][5] = qq.z; v[ky][6] = qq.z;
                v[ky][7] = qq.w; v[ky][8] = qq.w;
                v[ky][9] = s4;
            } else {
                const float* r = (ci < Ca)
                    ? inA + ((size_t)(n * Ca + ci) * H + iy) * W
                    : inB + ((size_t)(n * Cb + (ci - Ca)) * H + iy) * W;
                v[ky][0] = left_ok ? r[x0 - 1] : 0.f;
                float4 q0 = *(const float4*)(r + x0);
                float4 q1 = *(const float4*)(r + x0 + 4);
                v[ky][1] = q0.x; v[ky][2] = q0.y; v[ky][3] = q0.z; v[ky][4] = q0.w;
                v[ky][5] = q1.x; v[ky][6] = q1.y; v[ky][7] = q1.z; v[ky][8] = q1.w;
                v[ky][9] = right_ok ? r[x0 + 8] : 0.f;
            }
        }
#pragma unroll
        for (int j = 0; j < TCO; ++j) {
            const float* wp = w + ((size_t)(co0 + j) * Cin + ci) * 9;
#pragma unroll
            for (int ky = 0; ky < 3; ++ky) {
                float w0 = wp[ky * 3 + 0], w1 = wp[ky * 3 + 1], w2 = wp[ky * 3 + 2];
#pragma unroll
                for (int p = 0; p < 8; ++p)
                    acc[j][p] += w0 * v[ky][p] + w1 * v[ky][p + 1] + w2 * v[ky][p + 2];
            }
        }
    }

    if (SPLIT) {
#pragma unroll
        for (int p = 0; p < 8; ++p) {
            half8 hv, lv;
#pragma unroll
            for (int j = 0; j < 8; ++j) {
                float v = acc[j][p];
                if (do_relu) v = fmaxf(v, 0.f);
                _Float16 hh = (_Float16)v;
                hv[j] = hh;
                lv[j] = (_Float16)(v - (float)hh);
            }
            size_t oaddr = ((size_t)((n * (Cout >> 3) + (co0 >> 3)) * H + y) * W + x0 + p) * 8;
            *(half8*)(osph + oaddr) = hv;
            *(half8*)(ospl + oaddr) = lv;
        }
    } else {
#pragma unroll
        for (int j = 0; j < TCO; ++j) {
#pragma unroll
            for (int p = 0; p < 8; ++p)
                if (do_relu) acc[j][p] = fmaxf(acc[j][p], 0.f);
            float* o = out + ((size_t)(n * Cout + co0 + j) * H + y) * W + x0;
            float4 q0; q0.x = acc[j][0]; q0.y = acc[j][1]; q0.z = acc[j][2]; q0.w = acc[j][3];
            float4 q1; q1.x = acc[j][4]; q1.y = acc[j][5]; q1.z = acc[j][6]; q1.w = acc[j][7];
            *(float4*)o = q0;
            *(float4*)(o + 4) = q1;
        }
    }
}

// p1: stride-2 vector conv with SPLIT output ([C/8][Ho][Wo][8]).
template <int TCO, int SPLIT>
__global__ __launch_bounds__(BS) void conv3x3_s2_co_kernel(
    const float* __restrict__ inA, int Ca,
    const float* __restrict__ inB, int Cb,
    const float* __restrict__ w, const float* __restrict__ b,
    float* __restrict__ out,
    int N, int Hi, int Wi, int Cout, int do_relu,
    _Float16* __restrict__ osph, _Float16* __restrict__ ospl)
{
    const int Ho = Hi >> 1, Wo = Wi >> 1, Woq = Wo >> 2;
    int idx = blockIdx.x * BS + threadIdx.x;
    int total = N * Ho * Woq;
    if (idx >= total) return;
    int q  = idx % Woq;
    int t  = idx / Woq;
    int oy = t % Ho;
    int n  = t / Ho;
    int ox0 = q << 2;
    int ix0 = ox0 << 1;
    const int co0 = blockIdx.y * TCO;
    const bool right_ok = (ix0 + 8 < Wi);
    const int Cin = Ca + Cb;

    float acc[TCO][4];
#pragma unroll
    for (int j = 0; j < TCO; ++j) {
        float bv = b[co0 + j];
        acc[j][0] = bv; acc[j][1] = bv; acc[j][2] = bv; acc[j][3] = bv;
    }

    for (int ci = 0; ci < Cin; ++ci) {
        const float* base = (ci < Ca)
            ? inA + (size_t)(n * Ca + ci) * Hi * Wi
            : inB + (size_t)(n * Cb + (ci - Ca)) * Hi * Wi;
        float v[3][9];
#pragma unroll
        for (int ky = 0; ky < 3; ++ky) {
            int iy = 2 * oy + ky;
            if (iy >= Hi) {
#pragma unroll
                for (int p = 0; p < 9; ++p) v[ky][p] = 0.f;
                continue;
            }
            const float* r = base + (size_t)iy * Wi + ix0;
            float4 a = *(const float4*)r;
            float4 c = *(const float4*)(r + 4);
            v[ky][0] = a.x; v[ky][1] = a.y; v[ky][2] = a.z; v[ky][3] = a.w;
            v[ky][4] = c.x; v[ky][5] = c.y; v[ky][6] = c.z; v[ky][7] = c.w;
            v[ky][8] = right_ok ? r[8] : 0.f;
        }
#pragma unroll
        for (int j = 0; j < TCO; ++j) {
            const float* wp = w + ((size_t)(co0 + j) * Cin + ci) * 9;
#pragma unroll
            for (int ky = 0; ky < 3; ++ky) {
                float w0 = wp[ky * 3 + 0], w1 = wp[ky * 3 + 1], w2 = wp[ky * 3 + 2];
#pragma unroll
                for (int p = 0; p < 4; ++p)
                    acc[j][p] += w0 * v[ky][2 * p] + w1 * v[ky][2 * p + 1] + w2 * v[ky][2 * p + 2];
            }
        }
    }

    if (SPLIT) {
#pragma unroll
        for (int p = 0; p < 4; ++p) {
            half8 hv, lv;
#pragma unroll
            for (int j = 0; j < 8; ++j) {
                float v = acc[j][p];
                if (do_relu) v = fmaxf(v, 0.f);
                _Float16 hh = (_Float16)v;
                hv[j] = hh;
                lv[j] = (_Float16)(v - (float)hh);
            }
            size_t oaddr = ((size_t)((n * (Cout >> 3) + (co0 >> 3)) * Ho + oy) * Wo + ox0 + p) * 8;
            *(half8*)(osph + oaddr) = hv;
            *(half8*)(ospl + oaddr) = lv;
        }
    } else {
#pragma unroll
        for (int j = 0; j < TCO; ++j) {
            float4 o;
            o.x = acc[j][0]; o.y = acc[j][1]; o.z = acc[j][2]; o.w = acc[j][3];
            if (do_relu) {
                o.x = fmaxf(o.x, 0.f); o.y = fmaxf(o.y, 0.f);
                o.z = fmaxf(o.z, 0.f); o.w = fmaxf(o.w, 0.f);
            }
            *(float4*)(out + ((size_t)(n * Cout + co0 + j) * Ho + oy) * Wo + ox0) = o;
        }
    }
}

__global__ __launch_bounds__(BS) void peaks_kernel(
    const float* __restrict__ hm, float* __restrict__ out,
    int NC, int H, int W, float thresh)
{
    int idx = blockIdx.x * BS + threadIdx.x;
    int total = NC * H * W;
    if (idx >= total) return;
    int x = idx % W;
    int t = idx / W;
    int y = t % H;
    int c = t / H;
    float r = 0.f;
    if (x >= 1 && x < W - 1 && y >= 1 && y < H - 1) {
        const float* base = hm + (size_t)c * H * W;
        float cv = base[y * W + x];
        if (cv > thresh &&
            cv >= base[(y - 1) * W + x] &&
            cv >= base[(y + 1) * W + x] &&
            cv >= base[y * W + (x - 1)] &&
            cv >= base[y * W + (x + 1)])
            r = 1.f;
    }
    out[idx] = r;
}

static inline int nblk(long n) { return (int)((n + BS - 1) / BS); }

extern "C" void kernel_launch(void* const* d_in, const int* in_sizes, int n_in,
                              void* d_out, int out_size, void* d_ws, size_t ws_size,
                              hipStream_t stream)
{
    const float* x     = (const float*)d_in[0];
    const float* w_d1  = (const float*)d_in[1];  const float* b_d1  = (const float*)d_in[2];
    const float* w_d2  = (const float*)d_in[3];  const float* b_d2  = (const float*)d_in[4];
    const float* w_bn  = (const float*)d_in[5];  const float* b_bn  = (const float*)d_in[6];
    const float* w_u1  = (const float*)d_in[7];  const float* b_u1  = (const float*)d_in[8];
    const float* w_u2  = (const float*)d_in[9];  const float* b_u2  = (const float*)d_in[10];
    const float* w_seg = (const float*)d_in[11]; const float* b_seg = (const float*)d_in[12];
    const float* w_p1  = (const float*)d_in[13]; const float* b_p1  = (const float*)d_in[14];
    const float* w_p2  = (const float*)d_in[15]; const float* b_p2  = (const float*)d_in[16];
    const float* w_hm  = (const float*)d_in[17]; const float* b_hm  = (const float*)d_in[18];
    const float* w_paf = (const float*)d_in[19]; const float* b_paf = (const float*)d_in[20];

    const int N = 8, H = 384, W = 384;
    const int H2 = 192, W2 = 192, H4 = 96, W4 = 96;

    float* ws = (float*)d_ws;
    // Lifetime map in header comment. All offsets in floats.
    float* d1   = ws + 18874368;                       // fp32, s1->s2
    _Float16* pd1sp_h = (_Float16*)(ws);               // s2->s3
    _Float16* pd1sp_l = (_Float16*)(ws + 4718592);
    float* d2f  = ws + 9437184;                        // fp32 for maxpool, s3->s4
    _Float16* d2sp_h = (_Float16*)(ws + 28311552);     // s3->s6
    _Float16* d2sp_l = (_Float16*)(ws + 37748736);
    _Float16* pd2sp_h = (_Float16*)(ws + 47185920);    // s4->s5
    _Float16* pd2sp_l = (_Float16*)(ws + 49545216);
    _Float16* bnsp_h = (_Float16*)(ws + 18874368);     // s5->s6
    _Float16* bnsp_l = (_Float16*)(ws + 23592960);
    _Float16* u1sp_h = (_Float16*)(ws);                // s6->s8
    _Float16* u1sp_l = (_Float16*)(ws + 9437184);
    _Float16* d1sp_h = (_Float16*)(ws + 18874368);     // s7->s8
    _Float16* d1sp_l = (_Float16*)(ws + 37748736);
    _Float16* p1sp_h = (_Float16*)(ws);                // s9->s10
    _Float16* p1sp_l = (_Float16*)(ws + 9437184);
    _Float16* p2sp_h = (_Float16*)(ws + 18874368);     // s10->s12
    _Float16* p2sp_l = (_Float16*)(ws + 23592960);

    float* out_seg   = (float*)d_out;                 // 1179648
    float* out_hm    = out_seg + 1179648;             // 1253376
    float* out_paf   = out_hm + 1253376;              // 2359296
    float* out_peaks = out_paf + 2359296;             // 1253376
    // packed weights in the peaks region [4792320, 6045696), all consumed
    // before step 13 overwrites them. 16B-aligned.
    _Float16* bp_u1  = (_Float16*)(out_seg + 4792320); // 110592 fl
    _Float16* bp_u2  = (_Float16*)(out_seg + 4902912); // 27648 fl
    _Float16* bp_d2  = (_Float16*)(out_seg + 4930560); // 18432 fl
    _Float16* bp_bn  = (_Float16*)(out_seg + 4948992); // 73728 fl
    _Float16* bp_p2  = (_Float16*)(out_seg + 5022720); // 73728 fl
    _Float16* bp_hm  = (_Float16*)(out_seg + 5096448); // 4096 fl
    _Float16* bp_paf = (_Float16*)(out_seg + 5100544); // 4096 fl -> ends 5104640

    // 0. pack weights
    packw_gen_kernel<<<nblk(13824), BS, 0, stream>>>(w_u1, bp_u1, 192, 64);
    packw_gen_kernel<<<nblk(3456),  BS, 0, stream>>>(w_u2, bp_u2, 96, 32);
    packw_gen_kernel<<<nblk(2304),  BS, 0, stream>>>(w_d2, bp_d2, 32, 64);
    packw_gen_kernel<<<nblk(9216),  BS, 0, stream>>>(w_bn, bp_bn, 64, 128);
    packw_gen_kernel<<<nblk(9216),  BS, 0, stream>>>(w_p2, bp_p2, 64, 128);
    packw_1x1_kernel<<<nblk(512),   BS, 0, stream>>>(w_hm, bp_hm, 128, 2, 17);
    packw_1x1_kernel<<<nblk(512),   BS, 0, stream>>>(w_paf, bp_paf, 128, 2, 32);
    // 1. d1 = relu(conv3x3(x; 3->32)) @384  [fp32, feeds maxpool]
    {
        dim3 g(nblk((long)N * H * (W / 8)), 32 / 8);
        conv3x3_x8_kernel<1, 8, 0><<<g, BS, 0, stream>>>(
            x, 3, nullptr, 0, w_d1, b_d1, d1, N, H, W, 32, 1, nullptr, nullptr);
    }
    // 2. pd1sp = maxpool_split(d1) @192
    maxpool2_split_kernel<<<nblk((long)8 * 4 * 192 * 48), BS, 0, stream>>>(
        d1, pd1sp_h, pd1sp_l, N, 4, H, W);
    // 3. d2 = relu(conv3x3(pd1; 32->64)) @192  [MFMA split-in; fp32 + split out]
    conv3x3s_mfma_kernel<1, 4, 192, 192, 2><<<8 * 96 * 6, BS, 0, stream>>>(
        pd1sp_h, pd1sp_l, bp_d2, b_d2, d2f, d2sp_h, d2sp_l);
    // 4. pd2sp = maxpool_split(d2) @96
    maxpool2_split_kernel<<<nblk((long)8 * 8 * 96 * 24), BS, 0, stream>>>(
        d2f, pd2sp_h, pd2sp_l, N, 8, H2, W2);
    // 5. bn = relu(conv3x3(pd2; 64->128)) @96  [MFMA split-in; split-only out]
    conv3x3s_mfma_kernel<2, 8, 96, 96, 1><<<8 * 48 * 3, BS, 0, stream>>>(
        pd2sp_h, pd2sp_l, bp_bn, b_bn, nullptr, bnsp_h, bnsp_l);
    // 6. u1 = relu(conv3x3(concat(up2(bn), d2); 192->64)) @192  [MFMA 8x48]
    u1_mfma_kernel<<<8 * 24 * 4, BSW, 0, stream>>>(
        bnsp_h, bnsp_l, d2sp_h, d2sp_l, bp_u1, b_u1, u1sp_h, u1sp_l);
    // 7. d1' = relu(conv3x3(x; 3->32)) @384  (recompute, split-only out)
    {
        dim3 g(nblk((long)N * H * (W / 8)), 32 / 8);
        conv3x3_x8_kernel<1, 8, 1><<<g, BS, 0, stream>>>(
            x, 3, nullptr, 0, w_d1, b_d1, nullptr, N, H, W, 32, 1, d1sp_h, d1sp_l);
    }
    // 8. seg via fused MFMA u2+seg @384  [MFMA 8x48]
    u2seg_mfma_kernel<<<8 * 48 * 8, BSW, 0, stream>>>(
        u1sp_h, u1sp_l, d1sp_h, d1sp_l, bp_u2, b_u2, w_seg, b_seg, out_seg);
    // 9. p1 = relu(conv3x3_s2(concat(x, seg); 4->64)) @384->192  [vector, split out]
    {
        dim3 g(nblk((long)N * H2 * (W2 / 4)), 64 / 8);
        conv3x3_s2_co_kernel<8, 1><<<g, BS, 0, stream>>>(
            x, 3, out_seg, 1, w_p1, b_p1, nullptr, N, H, W, 64, 1, p1sp_h, p1sp_l);
    }
    // 10. p2 = relu(conv3x3_s2(p1; 64->128)) @192->96  [MFMA s2 split I/O]
    conv3x3s2s_mfma_kernel<2, 8, 192><<<8 * 48 * 3, BS, 0, stream>>>(
        p1sp_h, p1sp_l, bp_p2, b_p2, p2sp_h, p2sp_l);
    // 11. hm = conv1x1(p2; 128->17) @96  [MFMA 1x1 split-in]
    conv1x1s_mfma_kernel<4, 2><<<8 * 144, BS, 0, stream>>>(
        p2sp_h, p2sp_l, bp_hm, b_hm, out_hm, 17, H4 * W4);
    // 12. paf = conv1x1(p2; 128->32) @96  [MFMA 1x1 split-in]
    conv1x1s_mfma_kernel<4, 2><<<8 * 144, BS, 0, stream>>>(
        p2sp_h, p2sp_l, bp_paf, b_paf, out_paf, 32, H4 * W4);
    // 13. peaks @96  (overwrites packed-weight region - already consumed)
    peaks_kernel<<<nblk((long)N * 17 * H4 * W4), BS, 0, stream>>>(
        out_hm, out_peaks, N * 17, H4, W4, 0.1f);
}